// Round 4
// baseline (2587.328 us; speedup 1.0000x reference)
//
#include <hip/hip_runtime.h>
#include <hip/hip_bf16.h>

// BiDirectionalFusionModule on MI355X.
// All heavy convs = implicit GEMM, bf16 MFMA 16x16x32, f32 accumulate.
// Activations staged as zero-padded NHWC bf16. ~220MB workspace.
// R2: global_load_lds(16B) GEMM staging; coalesced weight preps.
// R3: fixed dotconv weight staging.
// R4: attn_k rewrite — no V in LDS (L2-resident, f32 global reads), q+scores in
//     registers, per-wave softmax without barriers. LDS 96->36KB (occ 11%->~40%).

typedef __bf16 bf16x8 __attribute__((ext_vector_type(8)));
typedef float f32x4 __attribute__((ext_vector_type(4)));

#define DEVI __device__ __forceinline__

DEVI float bf2f(unsigned short u){
  union { unsigned int i; float f; } v; v.i = ((unsigned int)u) << 16; return v.f;
}
DEVI unsigned short f2bf(float f){
  union { float f; unsigned int i; } v; v.f = f;
  unsigned int x = v.i;
  unsigned int r = (x + 0x7fffu + ((x >> 16) & 1u)) >> 16;
  return (unsigned short)r;
}

// ---------------------------------------------------------------- BN prep
__global__ void bnprep_k(const float* __restrict__ g1, const float* __restrict__ be1,
                         const float* __restrict__ m1, const float* __restrict__ v1,
                         const float* __restrict__ b1,
                         const float* __restrict__ gf, const float* __restrict__ bef,
                         const float* __restrict__ mf, const float* __restrict__ vf,
                         const float* __restrict__ bf,
                         float* __restrict__ sc1, float* __restrict__ sh1,
                         float* __restrict__ scf, float* __restrict__ shf)
{
  int c = threadIdx.x;
  float s = g1[c] * rsqrtf(v1[c] + 1e-5f);
  sc1[c] = s; sh1[c] = (b1[c] - m1[c]) * s + be1[c];
  s = gf[c] * rsqrtf(vf[c] + 1e-5f);
  scf[c] = s; shf[c] = (bf[c] - mf[c]) * s + bef[c];
}

// ------------------------------------------------- NCHW f32 -> padded NHWC bf16
// Xpad layout: [8][90][90][512], ch 0..255 = rgb, 256..511 = depth. Borders pre-zeroed.
__global__ __launch_bounds__(256)
void prep_xpad_k(const float* __restrict__ rgb, const float* __restrict__ dep,
                 unsigned short* __restrict__ Xpad)
{
  __shared__ unsigned short tile[64][65];
  int bi = blockIdx.x;
  int b = bi / 968;
  int rem = bi - b * 968;
  int cblk = rem / 121;
  int pblk = rem - cblk * 121;
  int t = threadIdx.x;
  int pl = t & 63;
  #pragma unroll
  for (int pass = 0; pass < 16; ++pass){
    int cl = pass * 4 + (t >> 6);
    int c = cblk * 64 + cl;
    const float* sp = (c < 256) ? (rgb + ((size_t)b * 256 + c) * 7744)
                                : (dep + ((size_t)b * 256 + (c - 256)) * 7744);
    tile[cl][pl] = f2bf(sp[pblk * 64 + pl]);
  }
  __syncthreads();
  int cl2 = t & 63;
  for (int pass = 0; pass < 16; ++pass){
    int pl2 = pass * 4 + (t >> 6);
    int pixg = pblk * 64 + pl2;
    int y = pixg / 88, x = pixg - y * 88;
    Xpad[(((size_t)b * 90 + y + 1) * 90 + (x + 1)) * 512 + cblk * 64 + cl2] = tile[cl2][pl2];
  }
}

// ---------------------------------------------------------------- weight reshuffles
// o: [9tap][256co][512ci] bf16 from sm_w1 (256,512,3,3). One block per co; coalesced.
__global__ __launch_bounds__(256)
void prep_w1t_k(const float* __restrict__ w, unsigned short* __restrict__ o)
{
  int co = blockIdx.x, t = threadIdx.x;
  const float* src = w + (size_t)co * 4608 + t * 18;   // ci=2t..2t+1, taps 0..8
  unsigned int* op = (unsigned int*)o;
  #pragma unroll
  for (int k = 0; k < 9; ++k){
    unsigned short lo = f2bf(src[k]);
    unsigned short hi = f2bf(src[9 + k]);
    op[((size_t)k * 256 + co) * 256 + t] = lo | ((unsigned int)hi << 16);
  }
}
// o: [9tap][256co][576ci] from fus_w (256,513,3,3); ci>=513 zero-padded.
__global__ __launch_bounds__(256)
void prep_wfus_k(const float* __restrict__ w, unsigned short* __restrict__ o)
{
  int co = blockIdx.x, t = threadIdx.x;
  const float* src = w + (size_t)co * 4617 + t * 18;   // ci<512 part
  unsigned int* op = (unsigned int*)o;
  #pragma unroll
  for (int k = 0; k < 9; ++k){
    unsigned short lo = f2bf(src[k]);
    unsigned short hi = f2bf(src[9 + k]);
    op[((size_t)k * 256 + co) * 288 + t] = lo | ((unsigned int)hi << 16);
  }
  if (t < 32){
    #pragma unroll
    for (int k = 0; k < 9; ++k){
      unsigned int val = 0;
      if (t == 0) val = (unsigned int)f2bf(w[(size_t)co * 4617 + 512 * 9 + k]); // ci=512
      op[((size_t)k * 256 + co) * 288 + 256 + t] = val;
    }
  }
}
// o: [64tap][256co][256ci] from sr_w (256,256,8,8). One block per co; LDS transpose.
__global__ __launch_bounds__(256)
void prep_wsr_k(const float* __restrict__ w, unsigned short* __restrict__ o)
{
  __shared__ float ld[64][65];
  int co = blockIdx.x;
  int t = threadIdx.x;
  for (int cib = 0; cib < 256; cib += 64){
    int cil = t >> 2, tq = t & 3;
    const float* src = w + ((size_t)co * 256 + cib + cil) * 64 + tq * 16;
    float v[16];
    #pragma unroll
    for (int k = 0; k < 16; ++k) v[k] = src[k];
    __syncthreads();
    #pragma unroll
    for (int k = 0; k < 16; ++k) ld[cil][tq * 16 + k] = v[k];
    __syncthreads();
    #pragma unroll
    for (int tp = 0; tp < 16; ++tp){
      int tap = tp * 4 + (t >> 6);
      int ci = t & 63;
      o[((size_t)tap * 256 + co) * 256 + cib + ci] = f2bf(ld[ci][tap]);
    }
  }
}
// generic (R,C) f32 -> [C][R] bf16 transpose (R,C multiples of 32)
__global__ __launch_bounds__(256)
void tranw_k(const float* __restrict__ in, unsigned short* __restrict__ out, int R, int C)
{
  __shared__ float tl[32][33];
  int tiles_c = C >> 5;
  int tr = (blockIdx.x / tiles_c) << 5, tc = (blockIdx.x % tiles_c) << 5;
  int t = threadIdx.x; int r = t >> 5, c = t & 31;
  #pragma unroll
  for (int p = 0; p < 4; ++p)
    tl[r + p * 8][c] = in[(size_t)(tr + r + p * 8) * C + tc + c];
  __syncthreads();
  #pragma unroll
  for (int p = 0; p < 4; ++p)
    out[(size_t)(tc + r + p * 8) * R + tr + c] = f2bf(tl[c][r + p * 8]);
}

// ---------------------------------------------------------------- implicit GEMM
struct GemmP {
  const unsigned short* A;
  const unsigned short* W;
  const float* ep_scale;
  const float* ep_shift;
  void* out;
  int img_px, row_px, px_el, ch_off, y0, x0;
  int tapw, stridepix, out_w, out_imgpx;
  int Cin, Mtot, Mtiles, Ntiles, k_per;
};

template<int EPI>   // 0: BN+ReLU -> bf16 NHWC[.][256]   1: BN+ReLU -> f32 NCHW   2: f32 partial [slot][968][256]
__global__ __launch_bounds__(256)
void gemm_k(GemmP p)
{
  __shared__ __bf16 As[128 * 64];
  __shared__ __bf16 Bs[128 * 64];
  const int t = threadIdx.x;
  const int lane = t & 63;
  const int wid = t >> 6;
  const int wr = wid >> 1, wc = wid & 1;

  int pid = blockIdx.x;
  int mt = pid % p.Mtiles;
  int nt = (pid / p.Mtiles) % p.Ntiles;
  int slot = pid / (p.Mtiles * p.Ntiles);
  int kb = slot * p.k_per;
  int tap0 = kb / p.Cin;        // host guarantees k_per % Cin == 0, kb % Cin == 0
  int ntap = p.k_per / p.Cin;

  long long apix[4]; int cbg8[4]; int wrow[4];
  #pragma unroll
  for (int i = 0; i < 4; ++i){
    int r = i * 32 + (t >> 3);
    cbg8[i] = ((t & 7) ^ (r & 7)) * 8;
    int n = mt * 128 + r;
    int nc = n < p.Mtot ? n : 0;
    int b = nc / p.out_imgpx; int rr = nc - b * p.out_imgpx;
    int yo = rr / p.out_w;    int xo = rr - yo * p.out_w;
    apix[i] = (long long)b * p.img_px + (long long)(yo * p.stridepix + p.y0) * p.row_px
            + (xo * p.stridepix + p.x0);
    wrow[i] = (nt * 128 + r) * p.Cin + cbg8[i];
  }

  f32x4 acc[4][4];
  #pragma unroll
  for (int i = 0; i < 4; ++i)
    #pragma unroll
    for (int j = 0; j < 4; ++j)
      acc[i][j] = f32x4{0.f, 0.f, 0.f, 0.f};

  const long long wstap = 256LL * p.Cin;

  for (int tp = 0; tp < ntap; ++tp){
    int tap = tap0 + tp;
    int dy = tap / p.tapw, dx = tap - dy * p.tapw;
    const unsigned short* wb = p.W + (long long)tap * wstap;
    long long abase[4];
    #pragma unroll
    for (int i = 0; i < 4; ++i)
      abase[i] = (apix[i] + (long long)dy * p.row_px + dx) * p.px_el + p.ch_off + cbg8[i];

    for (int cib = 0; cib < p.Cin; cib += 64){
      __syncthreads();
      #pragma unroll
      for (int i = 0; i < 4; ++i){
        __builtin_amdgcn_global_load_lds(
            (__attribute__((address_space(1))) void*)(p.A + abase[i] + cib),
            (__attribute__((address_space(3))) void*)(&As[i * 2048 + wid * 512]),
            16, 0, 0);
        __builtin_amdgcn_global_load_lds(
            (__attribute__((address_space(1))) void*)(wb + wrow[i] + cib),
            (__attribute__((address_space(3))) void*)(&Bs[i * 2048 + wid * 512]),
            16, 0, 0);
      }
      __syncthreads();
      #pragma unroll
      for (int ks = 0; ks < 2; ++ks){
        bf16x8 av[4], bv[4];
        #pragma unroll
        for (int mi = 0; mi < 4; ++mi){
          int ar = wr * 64 + mi * 16 + (lane & 15);
          int cb = (ks * 4 + (lane >> 4)) ^ (ar & 7);
          av[mi] = *reinterpret_cast<const bf16x8*>(&As[ar * 64 + cb * 8]);
        }
        #pragma unroll
        for (int ni = 0; ni < 4; ++ni){
          int br = wc * 64 + ni * 16 + (lane & 15);
          int cb = (ks * 4 + (lane >> 4)) ^ (br & 7);
          bv[ni] = *reinterpret_cast<const bf16x8*>(&Bs[br * 64 + cb * 8]);
        }
        #pragma unroll
        for (int mi = 0; mi < 4; ++mi)
          #pragma unroll
          for (int ni = 0; ni < 4; ++ni)
            acc[mi][ni] = __builtin_amdgcn_mfma_f32_16x16x32_bf16(av[mi], bv[ni], acc[mi][ni], 0, 0, 0);
      }
    }
  }

  const int r0 = (lane >> 4) * 4;
  const int c0 = lane & 15;
  #pragma unroll
  for (int mi = 0; mi < 4; ++mi){
    int nbase = mt * 128 + wr * 64 + mi * 16 + r0;
    #pragma unroll
    for (int ni = 0; ni < 4; ++ni){
      int co = nt * 128 + wc * 64 + ni * 16 + c0;
      f32x4 a = acc[mi][ni];
      if constexpr (EPI == 0){
        float sc = p.ep_scale[co], sh = p.ep_shift[co];
        unsigned short* o = (unsigned short*)p.out;
        #pragma unroll
        for (int r = 0; r < 4; ++r){
          float v = fmaf(a[r], sc, sh); v = v > 0.f ? v : 0.f;
          o[(size_t)(nbase + r) * 256 + co] = f2bf(v);
        }
      } else if constexpr (EPI == 1){
        float sc = p.ep_scale[co], sh = p.ep_shift[co];
        float* o = (float*)p.out;
        int b = nbase / 7744; int s = nbase - b * 7744;
        float4 v;
        v.x = fmaxf(fmaf(a[0], sc, sh), 0.f);
        v.y = fmaxf(fmaf(a[1], sc, sh), 0.f);
        v.z = fmaxf(fmaf(a[2], sc, sh), 0.f);
        v.w = fmaxf(fmaf(a[3], sc, sh), 0.f);
        *reinterpret_cast<float4*>(o + ((size_t)(b * 256 + co)) * 7744 + s) = v;
      } else {
        float* o = (float*)p.out + (size_t)slot * 968 * 256;
        #pragma unroll
        for (int r = 0; r < 4; ++r){
          int n = nbase + r;
          if (n < p.Mtot) o[(size_t)n * 256 + co] = a[r];
        }
      }
    }
  }
}

// ---------------------------------------------------------------- spatial mask
__global__ __launch_bounds__(256)
void mask_k(const unsigned short* __restrict__ h1, const float* __restrict__ w2,
            const float* __restrict__ b2, float* __restrict__ mask,
            unsigned short* __restrict__ FusPad)
{
  __shared__ float w[256];
  int t = threadIdx.x;
  w[t] = w2[t];
  __syncthreads();
  int n = blockIdx.x * 256 + t;
  const unsigned short* row = h1 + (size_t)n * 256;
  float s = b2[0];
  for (int c = 0; c < 256; c += 8){
    union { uint4 v; unsigned short s_[8]; } u;
    u.v = *reinterpret_cast<const uint4*>(row + c);
    #pragma unroll
    for (int j = 0; j < 8; ++j) s = fmaf(bf2f(u.s_[j]), w[c + j], s);
  }
  float m = 1.f / (1.f + __expf(-s));
  mask[n] = m;
  int b = n / 7744, sr = n - b * 7744;
  int y = sr / 88, x = sr - y * 88;
  FusPad[(((size_t)b * 90 + y + 1) * 90 + (x + 1)) * 576 + 512] = f2bf(m);
}

// ---------------------------------------------------------------- f_depth * mask -> NHWC bf16 [61952][256]
__global__ __launch_bounds__(256)
void fdm_k(const unsigned short* __restrict__ Xpad, const float* __restrict__ mask,
           unsigned short* __restrict__ fdm)
{
  int idx = blockIdx.x * 256 + threadIdx.x;   // 61952*32
  int n = idx >> 5, cb = idx & 31;
  int b = n / 7744, s = n - b * 7744;
  int y = s / 88, x = s - y * 88;
  size_t pix = ((size_t)(b * 90 + y + 1)) * 90 + x + 1;
  union { uint4 v; unsigned short s_[8]; } u, w;
  u.v = *reinterpret_cast<const uint4*>(Xpad + pix * 512 + 256 + cb * 8);
  float m = mask[n];
  #pragma unroll
  for (int j = 0; j < 8; ++j) w.s_[j] = f2bf(bf2f(u.s_[j]) * m);
  *reinterpret_cast<uint4*>(fdm + (size_t)n * 256 + cb * 8) = w.v;
}

// ---------------------------------------------------------------- sum split-K partials + channel LN -> kvr bf16
__global__ __launch_bounds__(256)
void lnkvr_k(const float* __restrict__ part, const float* __restrict__ srb,
             const float* __restrict__ lng, const float* __restrict__ lnb,
             unsigned short* __restrict__ kvr)
{
  int n = blockIdx.x, t = threadIdx.x;
  float v = srb[t];
  for (int s = 0; s < 16; ++s) v += part[((size_t)s * 968 + n) * 256 + t];
  float s1 = v, s2 = v * v;
  #pragma unroll
  for (int o = 1; o < 64; o <<= 1){ s1 += __shfl_xor(s1, o, 64); s2 += __shfl_xor(s2, o, 64); }
  __shared__ float a1[4], a2[4];
  if ((t & 63) == 0){ a1[t >> 6] = s1; a2[t >> 6] = s2; }
  __syncthreads();
  float t1 = a1[0] + a1[1] + a1[2] + a1[3];
  float t2 = a2[0] + a2[1] + a2[2] + a2[3];
  float mean = t1 * (1.f / 256.f);
  float var = t2 * (1.f / 256.f) - mean * mean;
  float rstd = rsqrtf(var + 1e-5f);
  kvr[(size_t)n * 256 + t] = f2bf((v - mean) * rstd * lng[t] + lnb[t]);
}

// ---------------------------------------------------------------- 1x1 conv 256->32 (Q and K)
__global__ __launch_bounds__(256)
void dotconv_k(const unsigned short* __restrict__ src, int mode,
               const unsigned short* __restrict__ wt, const float* __restrict__ bias,
               float* __restrict__ out)
{
  __shared__ unsigned short wl[256 * 32];
  const int t = threadIdx.x;
  {
    uint4* d = (uint4*)wl; const uint4* s = (const uint4*)wt;
    #pragma unroll
    for (int k = 0; k < 4; ++k) d[t + 256 * k] = s[t + 256 * k];   // 1024 uint4 = all of wl
  }
  __syncthreads();
  const int n = blockIdx.x * 8 + (t >> 5);
  const int co = t & 31;
  const unsigned short* row;
  if (mode == 1){
    int b = n / 7744, s2 = n - b * 7744;
    int y = s2 / 88, x = s2 - y * 88;
    row = src + (((size_t)(b * 90 + y + 1)) * 90 + (x + 1)) * 512;
  } else {
    row = src + (size_t)n * 256;
  }
  float sum = bias[co];
  for (int c = 0; c < 256; c += 8){
    union { uint4 v; unsigned short s_[8]; } u;
    u.v = *reinterpret_cast<const uint4*>(row + c);
    #pragma unroll
    for (int j = 0; j < 8; ++j)
      sum = fmaf(bf2f(u.s_[j]), bf2f(wl[(c + j) * 32 + co]), sum);
  }
  out[(size_t)n * 32 + co] = sum;
}

// ---------------------------------------------------------------- 1x1 conv 256->256 (V) -> f32
__global__ __launch_bounds__(256)
void vconv_k(const unsigned short* __restrict__ kvr, const unsigned short* __restrict__ vwt,
             const float* __restrict__ vb, float* __restrict__ V)
{
  __shared__ float rowf[256];
  const int n = blockIdx.x, t = threadIdx.x;
  rowf[t] = bf2f(kvr[(size_t)n * 256 + t]);
  __syncthreads();
  float sum = vb[t];
  #pragma unroll 8
  for (int c = 0; c < 256; ++c)
    sum = fmaf(rowf[c], bf2f(vwt[(size_t)c * 256 + t]), sum);
  V[(size_t)n * 256 + t] = sum;
}

// ---------------------------------------------------------------- fused attention + LN + residual
// Per block: 32 query rows of one image; KV = 121 positions.
// Q,K in LDS; scores in registers; V (f32) read from global (L2-resident, reused 242x).
// Each row's softmax is wave-local: lanes 8n..8n+7 own row n; no cross-wave barriers.
__global__ __launch_bounds__(256)
void attn_k(const float* __restrict__ Qbuf, const float* __restrict__ Kbuf,
            const float* __restrict__ Vbuf,
            const unsigned short* __restrict__ Xpad, int resChOff,
            unsigned short* __restrict__ FusPad, int outChOff,
            const float* __restrict__ ng, const float* __restrict__ nbv,
            const float* __restrict__ gammap)
{
  __shared__ float Qt[32 * 33];
  __shared__ float Kt[121 * 33];
  __shared__ float Sl[32 * 124];
  const int t = threadIdx.x;
  const int nb0 = blockIdx.x * 32;
  const int b = nb0 / 7744;
  const int mbase = b * 121;

  {
    const float4* src = reinterpret_cast<const float4*>(Qbuf + (size_t)nb0 * 32);
    float4 v = src[t];
    int i = t >> 3, c = (t & 7) * 4;
    float* q = &Qt[i * 33 + c];
    q[0] = v.x; q[1] = v.y; q[2] = v.z; q[3] = v.w;
  }
  for (int idx = t; idx < 121 * 32; idx += 256){
    int m = idx >> 5, c = idx & 31;
    Kt[m * 33 + c] = Kbuf[(size_t)mbase * 32 + idx];
  }
  __syncthreads();

  const int n2 = t >> 3, sub = t & 7;
  const float scale = 0.17677669529663687f;  // 32^-0.5

  // ---- QK^T: q row in registers, 16 scores per thread (m = sub + 8k) ----
  float q[32];
  #pragma unroll
  for (int c = 0; c < 32; ++c) q[c] = Qt[n2 * 33 + c];
  float s[16];
  #pragma unroll
  for (int k = 0; k < 16; ++k){
    int m = sub + 8 * k;
    if (m < 121){
      const float* kp = &Kt[m * 33];
      float a = 0.f;
      #pragma unroll
      for (int c = 0; c < 32; ++c) a = fmaf(q[c], kp[c], a);
      s[k] = a * scale;
    } else s[k] = -1e30f;
  }
  // ---- softmax over the 8-lane row group ----
  float mx = s[0];
  #pragma unroll
  for (int k = 1; k < 16; ++k) mx = fmaxf(mx, s[k]);
  #pragma unroll
  for (int o = 1; o < 8; o <<= 1) mx = fmaxf(mx, __shfl_xor(mx, o, 64));
  float sum = 0.f;
  #pragma unroll
  for (int k = 0; k < 16; ++k){
    int m = sub + 8 * k;
    if (m < 121){
      float pv = __expf(s[k] - mx);
      Sl[n2 * 124 + m] = pv;       // written & read by the same wave: no barrier
      sum += pv;
    }
  }
  #pragma unroll
  for (int o = 1; o < 8; o <<= 1) sum += __shfl_xor(sum, o, 64);
  const float rden = 1.f / sum;

  // ---- PV: V f32 from global (L1/L2-served, 8-lane broadcast) ----
  const int ck = sub;
  const float* prow = &Sl[n2 * 124];
  const float* vbase = Vbuf + (size_t)mbase * 256 + ck * 32;
  float oacc[32];
  #pragma unroll
  for (int j = 0; j < 32; ++j) oacc[j] = 0.f;
  for (int m = 0; m < 121; ++m){
    float pv = prow[m];
    const float4* vr = reinterpret_cast<const float4*>(vbase + (size_t)m * 256);
    #pragma unroll
    for (int qq = 0; qq < 8; ++qq){
      float4 v4 = vr[qq];
      oacc[qq * 4 + 0] = fmaf(pv, v4.x, oacc[qq * 4 + 0]);
      oacc[qq * 4 + 1] = fmaf(pv, v4.y, oacc[qq * 4 + 1]);
      oacc[qq * 4 + 2] = fmaf(pv, v4.z, oacc[qq * 4 + 2]);
      oacc[qq * 4 + 3] = fmaf(pv, v4.w, oacc[qq * 4 + 3]);
    }
  }

  float s1 = 0.f, s2 = 0.f;
  #pragma unroll
  for (int j = 0; j < 32; ++j){ oacc[j] *= rden; s1 += oacc[j]; s2 += oacc[j] * oacc[j]; }
  #pragma unroll
  for (int ofs = 1; ofs < 8; ofs <<= 1){ s1 += __shfl_xor(s1, ofs, 64); s2 += __shfl_xor(s2, ofs, 64); }
  const float mean = s1 * (1.f / 256.f);
  const float var = s2 * (1.f / 256.f) - mean * mean;
  const float rstd = rsqrtf(var + 1e-5f);
  float g = gammap[0]; g = fminf(fmaxf(g, 0.f), 1.f);

  int nglob = nb0 + n2;
  int srem = nglob - b * 7744;
  int y = srem / 88, x = srem - y * 88;
  size_t pix = ((size_t)(b * 90 + y + 1)) * 90 + (x + 1);
  const unsigned short* res = Xpad + pix * 512 + resChOff + ck * 32;
  unsigned short* outp = FusPad + pix * 576 + outChOff + ck * 32;
  #pragma unroll
  for (int qv = 0; qv < 4; ++qv){
    union { uint4 v; unsigned short s_[8]; } ru, wu;
    ru.v = *reinterpret_cast<const uint4*>(res + qv * 8);
    #pragma unroll
    for (int j = 0; j < 8; ++j){
      int c = ck * 32 + qv * 8 + j;
      float yv = (oacc[qv * 8 + j] - mean) * rstd * ng[c] + nbv[c];
      wu.s_[j] = f2bf(bf2f(ru.s_[j]) + g * yv);
    }
    *reinterpret_cast<uint4*>(outp + qv * 8) = wu.v;
  }
}

// ================================================================ host
extern "C" void kernel_launch(void* const* d_in, const int* in_sizes, int n_in,
                              void* d_out, int out_size, void* d_ws, size_t ws_size,
                              hipStream_t stream)
{
  const float* P[42];
  for (int i = 0; i < 42; ++i) P[i] = (const float*)d_in[i];

  char* ws = (char*)d_ws;
  size_t off = 0;
  auto take = [&](size_t bytes) -> char* {
    char* p = ws + off; off += (bytes + 255) & ~(size_t)255; return p;
  };
  unsigned short* XPAD = (unsigned short*)take(8ull * 8100 * 512 * 2);   // 66.4 MB
  unsigned short* FUSP = (unsigned short*)take(8ull * 8100 * 576 * 2);   // 74.6 MB
  unsigned short* H1   = (unsigned short*)take(61952ull * 256 * 2);      // 31.7 MB
  unsigned short* FDM  = H1;  // alias: h1 dead after mask_k
  unsigned short* W1T  = (unsigned short*)take(9ull * 256 * 512 * 2);
  unsigned short* WFT  = (unsigned short*)take(9ull * 256 * 576 * 2);
  unsigned short* WSRA = (unsigned short*)take(64ull * 256 * 256 * 2);
  unsigned short* WSRB = (unsigned short*)take(64ull * 256 * 256 * 2);
  float* PART = (float*)take(16ull * 968 * 256 * 4);                      // 15.9 MB
  float* QB   = (float*)take(61952ull * 32 * 4);
  unsigned short* KVR = (unsigned short*)take(968ull * 256 * 2);
  float* KB   = (float*)take(968ull * 32 * 4);
  float* VB   = (float*)take(968ull * 256 * 4);                           // f32 now
  float* MASK = (float*)take(61952ull * 4);
  float* SC1 = (float*)take(256 * 4);
  float* SH1 = (float*)take(256 * 4);
  float* SCF = (float*)take(256 * 4);
  float* SHF = (float*)take(256 * 4);
  unsigned short* QWTA = (unsigned short*)take(256ull * 32 * 2);
  unsigned short* KWTA = (unsigned short*)take(256ull * 32 * 2);
  unsigned short* VWTA = (unsigned short*)take(256ull * 256 * 2);
  unsigned short* QWTB = (unsigned short*)take(256ull * 32 * 2);
  unsigned short* KWTB = (unsigned short*)take(256ull * 32 * 2);
  unsigned short* VWTB = (unsigned short*)take(256ull * 256 * 2);
  (void)ws_size; (void)in_sizes; (void)n_in; (void)out_size;

  hipMemsetAsync(XPAD, 0, 8ull * 8100 * 512 * 2, stream);
  hipMemsetAsync(FUSP, 0, 8ull * 8100 * 576 * 2, stream);

  bnprep_k<<<1, 256, 0, stream>>>(P[4], P[5], P[6], P[7], P[3],
                                  P[38], P[39], P[40], P[41], P[37],
                                  SC1, SH1, SCF, SHF);
  prep_xpad_k<<<7744, 256, 0, stream>>>(P[0], P[1], XPAD);
  prep_w1t_k<<<256, 256, 0, stream>>>(P[2], W1T);
  prep_wfus_k<<<256, 256, 0, stream>>>(P[36], WFT);
  prep_wsr_k<<<256, 256, 0, stream>>>(P[16], WSRA);
  prep_wsr_k<<<256, 256, 0, stream>>>(P[28], WSRB);
  tranw_k<<<8, 256, 0, stream>>>(P[10], QWTA, 32, 256);
  tranw_k<<<8, 256, 0, stream>>>(P[12], KWTA, 32, 256);
  tranw_k<<<64, 256, 0, stream>>>(P[14], VWTA, 256, 256);
  tranw_k<<<8, 256, 0, stream>>>(P[22], QWTB, 32, 256);
  tranw_k<<<8, 256, 0, stream>>>(P[24], KWTB, 32, 256);
  tranw_k<<<64, 256, 0, stream>>>(P[26], VWTB, 256, 256);

  // conv1 3x3 (512->256) + BN + ReLU -> h1 NHWC bf16
  GemmP g1{};
  g1.A = XPAD; g1.W = W1T; g1.ep_scale = SC1; g1.ep_shift = SH1; g1.out = H1;
  g1.img_px = 8100; g1.row_px = 90; g1.px_el = 512; g1.ch_off = 0; g1.y0 = 0; g1.x0 = 0;
  g1.tapw = 3; g1.stridepix = 1; g1.out_w = 88; g1.out_imgpx = 7744;
  g1.Cin = 512; g1.Mtot = 61952; g1.Mtiles = 484; g1.Ntiles = 2; g1.k_per = 4608;
  gemm_k<0><<<968, 256, 0, stream>>>(g1);

  mask_k<<<242, 256, 0, stream>>>(H1, P[8], P[9], MASK, FUSP);
  fdm_k<<<7744, 256, 0, stream>>>(XPAD, MASK, FDM);

  // ---------------- d2r: Q from f_rgb, KV from f_depth_masked ----------------
  GemmP gs{};
  gs.A = FDM; gs.W = WSRA; gs.out = PART;
  gs.img_px = 7744; gs.row_px = 88; gs.px_el = 256; gs.ch_off = 0; gs.y0 = 0; gs.x0 = 0;
  gs.tapw = 8; gs.stridepix = 8; gs.out_w = 11; gs.out_imgpx = 121;
  gs.Cin = 256; gs.Mtot = 968; gs.Mtiles = 8; gs.Ntiles = 2; gs.k_per = 1024;
  gemm_k<2><<<256, 256, 0, stream>>>(gs);
  lnkvr_k<<<968, 256, 0, stream>>>(PART, P[17], P[18], P[19], KVR);
  dotconv_k<<<7744, 256, 0, stream>>>(XPAD, 1, QWTA, P[11], QB);
  dotconv_k<<<121, 256, 0, stream>>>(KVR, 0, KWTA, P[13], KB);
  vconv_k<<<968, 256, 0, stream>>>(KVR, VWTA, P[15], VB);
  attn_k<<<1936, 256, 0, stream>>>(QB, KB, VB, XPAD, 0, FUSP, 0, P[20], P[21], P[34]);

  // ---------------- r2d: Q from f_depth_masked, KV from f_rgb ----------------
  gs.A = XPAD; gs.W = WSRB;
  gs.img_px = 8100; gs.row_px = 90; gs.px_el = 512; gs.y0 = 1; gs.x0 = 1;
  gemm_k<2><<<256, 256, 0, stream>>>(gs);
  lnkvr_k<<<968, 256, 0, stream>>>(PART, P[29], P[30], P[31], KVR);
  dotconv_k<<<7744, 256, 0, stream>>>(FDM, 0, QWTB, P[23], QB);
  dotconv_k<<<121, 256, 0, stream>>>(KVR, 0, KWTB, P[25], KB);
  vconv_k<<<968, 256, 0, stream>>>(KVR, VWTB, P[27], VB);
  attn_k<<<1936, 256, 0, stream>>>(QB, KB, VB, XPAD, 256, FUSP, 256, P[32], P[33], P[35]);

  // final fused conv 3x3 (576->256) + BN + ReLU -> d_out f32 NCHW
  GemmP gf{};
  gf.A = FUSP; gf.W = WFT; gf.ep_scale = SCF; gf.ep_shift = SHF; gf.out = d_out;
  gf.img_px = 8100; gf.row_px = 90; gf.px_el = 576; gf.ch_off = 0; gf.y0 = 0; gf.x0 = 0;
  gf.tapw = 3; gf.stridepix = 1; gf.out_w = 88; gf.out_imgpx = 7744;
  gf.Cin = 576; gf.Mtot = 61952; gf.Mtiles = 484; gf.Ntiles = 2; gf.k_per = 5184;
  gemm_k<1><<<968, 256, 0, stream>>>(gf);
}

// Round 5
// 765.093 us; speedup vs baseline: 3.3817x; 3.3817x over previous
//
#include <hip/hip_runtime.h>
#include <hip/hip_bf16.h>

// BiDirectionalFusionModule on MI355X.
// All heavy convs = implicit GEMM, bf16 MFMA 16x16x32, f32 accumulate.
// Activations staged as zero-padded NHWC bf16. ~220MB workspace.
// R2: global_load_lds(16B) GEMM staging; coalesced weight preps.
// R3: fixed dotconv weight staging.
// R5: MFMA attention: 512 thr / 128 rows / 8 waves; QK^T+softmax+PV+LN all
//     wave-local; m97-style XOR-swizzled LDS (measured 0-conflict pattern);
//     V pre-transposed to VBt[c][m] and staged via global_load_lds.

typedef __bf16 bf16x8 __attribute__((ext_vector_type(8)));
typedef float f32x4 __attribute__((ext_vector_type(4)));

#define AS1 __attribute__((address_space(1)))
#define AS3 __attribute__((address_space(3)))
#define DEVI __device__ __forceinline__

DEVI float bf2f(unsigned short u){
  union { unsigned int i; float f; } v; v.i = ((unsigned int)u) << 16; return v.f;
}
DEVI unsigned short f2bf(float f){
  union { float f; unsigned int i; } v; v.f = f;
  unsigned int x = v.i;
  unsigned int r = (x + 0x7fffu + ((x >> 16) & 1u)) >> 16;
  return (unsigned short)r;
}

// ---------------------------------------------------------------- BN prep
__global__ void bnprep_k(const float* __restrict__ g1, const float* __restrict__ be1,
                         const float* __restrict__ m1, const float* __restrict__ v1,
                         const float* __restrict__ b1,
                         const float* __restrict__ gf, const float* __restrict__ bef,
                         const float* __restrict__ mf, const float* __restrict__ vf,
                         const float* __restrict__ bf,
                         float* __restrict__ sc1, float* __restrict__ sh1,
                         float* __restrict__ scf, float* __restrict__ shf)
{
  int c = threadIdx.x;
  float s = g1[c] * rsqrtf(v1[c] + 1e-5f);
  sc1[c] = s; sh1[c] = (b1[c] - m1[c]) * s + be1[c];
  s = gf[c] * rsqrtf(vf[c] + 1e-5f);
  scf[c] = s; shf[c] = (bf[c] - mf[c]) * s + bef[c];
}

// ------------------------------------------------- NCHW f32 -> padded NHWC bf16
__global__ __launch_bounds__(256)
void prep_xpad_k(const float* __restrict__ rgb, const float* __restrict__ dep,
                 unsigned short* __restrict__ Xpad)
{
  __shared__ unsigned short tile[64][65];
  int bi = blockIdx.x;
  int b = bi / 968;
  int rem = bi - b * 968;
  int cblk = rem / 121;
  int pblk = rem - cblk * 121;
  int t = threadIdx.x;
  int pl = t & 63;
  #pragma unroll
  for (int pass = 0; pass < 16; ++pass){
    int cl = pass * 4 + (t >> 6);
    int c = cblk * 64 + cl;
    const float* sp = (c < 256) ? (rgb + ((size_t)b * 256 + c) * 7744)
                                : (dep + ((size_t)b * 256 + (c - 256)) * 7744);
    tile[cl][pl] = f2bf(sp[pblk * 64 + pl]);
  }
  __syncthreads();
  int cl2 = t & 63;
  for (int pass = 0; pass < 16; ++pass){
    int pl2 = pass * 4 + (t >> 6);
    int pixg = pblk * 64 + pl2;
    int y = pixg / 88, x = pixg - y * 88;
    Xpad[(((size_t)b * 90 + y + 1) * 90 + (x + 1)) * 512 + cblk * 64 + cl2] = tile[cl2][pl2];
  }
}

// ---------------------------------------------------------------- weight reshuffles
__global__ __launch_bounds__(256)
void prep_w1t_k(const float* __restrict__ w, unsigned short* __restrict__ o)
{
  int co = blockIdx.x, t = threadIdx.x;
  const float* src = w + (size_t)co * 4608 + t * 18;
  unsigned int* op = (unsigned int*)o;
  #pragma unroll
  for (int k = 0; k < 9; ++k){
    unsigned short lo = f2bf(src[k]);
    unsigned short hi = f2bf(src[9 + k]);
    op[((size_t)k * 256 + co) * 256 + t] = lo | ((unsigned int)hi << 16);
  }
}
__global__ __launch_bounds__(256)
void prep_wfus_k(const float* __restrict__ w, unsigned short* __restrict__ o)
{
  int co = blockIdx.x, t = threadIdx.x;
  const float* src = w + (size_t)co * 4617 + t * 18;
  unsigned int* op = (unsigned int*)o;
  #pragma unroll
  for (int k = 0; k < 9; ++k){
    unsigned short lo = f2bf(src[k]);
    unsigned short hi = f2bf(src[9 + k]);
    op[((size_t)k * 256 + co) * 288 + t] = lo | ((unsigned int)hi << 16);
  }
  if (t < 32){
    #pragma unroll
    for (int k = 0; k < 9; ++k){
      unsigned int val = 0;
      if (t == 0) val = (unsigned int)f2bf(w[(size_t)co * 4617 + 512 * 9 + k]);
      op[((size_t)k * 256 + co) * 288 + 256 + t] = val;
    }
  }
}
__global__ __launch_bounds__(256)
void prep_wsr_k(const float* __restrict__ w, unsigned short* __restrict__ o)
{
  __shared__ float ld[64][65];
  int co = blockIdx.x;
  int t = threadIdx.x;
  for (int cib = 0; cib < 256; cib += 64){
    int cil = t >> 2, tq = t & 3;
    const float* src = w + ((size_t)co * 256 + cib + cil) * 64 + tq * 16;
    float v[16];
    #pragma unroll
    for (int k = 0; k < 16; ++k) v[k] = src[k];
    __syncthreads();
    #pragma unroll
    for (int k = 0; k < 16; ++k) ld[cil][tq * 16 + k] = v[k];
    __syncthreads();
    #pragma unroll
    for (int tp = 0; tp < 16; ++tp){
      int tap = tp * 4 + (t >> 6);
      int ci = t & 63;
      o[((size_t)tap * 256 + co) * 256 + cib + ci] = f2bf(ld[ci][tap]);
    }
  }
}
__global__ __launch_bounds__(256)
void tranw_k(const float* __restrict__ in, unsigned short* __restrict__ out, int R, int C)
{
  __shared__ float tl[32][33];
  int tiles_c = C >> 5;
  int tr = (blockIdx.x / tiles_c) << 5, tc = (blockIdx.x % tiles_c) << 5;
  int t = threadIdx.x; int r = t >> 5, c = t & 31;
  #pragma unroll
  for (int p = 0; p < 4; ++p)
    tl[r + p * 8][c] = in[(size_t)(tr + r + p * 8) * C + tc + c];
  __syncthreads();
  #pragma unroll
  for (int p = 0; p < 4; ++p)
    out[(size_t)(tc + r + p * 8) * R + tr + c] = f2bf(tl[c][r + p * 8]);
}

// ---------------------------------------------------------------- implicit GEMM
struct GemmP {
  const unsigned short* A;
  const unsigned short* W;
  const float* ep_scale;
  const float* ep_shift;
  void* out;
  int img_px, row_px, px_el, ch_off, y0, x0;
  int tapw, stridepix, out_w, out_imgpx;
  int Cin, Mtot, Mtiles, Ntiles, k_per;
};

template<int EPI>
__global__ __launch_bounds__(256)
void gemm_k(GemmP p)
{
  __shared__ __bf16 As[128 * 64];
  __shared__ __bf16 Bs[128 * 64];
  const int t = threadIdx.x;
  const int lane = t & 63;
  const int wid = t >> 6;
  const int wr = wid >> 1, wc = wid & 1;

  int pid = blockIdx.x;
  int mt = pid % p.Mtiles;
  int nt = (pid / p.Mtiles) % p.Ntiles;
  int slot = pid / (p.Mtiles * p.Ntiles);
  int kb = slot * p.k_per;
  int tap0 = kb / p.Cin;
  int ntap = p.k_per / p.Cin;

  long long apix[4]; int cbg8[4]; int wrow[4];
  #pragma unroll
  for (int i = 0; i < 4; ++i){
    int r = i * 32 + (t >> 3);
    cbg8[i] = ((t & 7) ^ (r & 7)) * 8;
    int n = mt * 128 + r;
    int nc = n < p.Mtot ? n : 0;
    int b = nc / p.out_imgpx; int rr = nc - b * p.out_imgpx;
    int yo = rr / p.out_w;    int xo = rr - yo * p.out_w;
    apix[i] = (long long)b * p.img_px + (long long)(yo * p.stridepix + p.y0) * p.row_px
            + (xo * p.stridepix + p.x0);
    wrow[i] = (nt * 128 + r) * p.Cin + cbg8[i];
  }

  f32x4 acc[4][4];
  #pragma unroll
  for (int i = 0; i < 4; ++i)
    #pragma unroll
    for (int j = 0; j < 4; ++j)
      acc[i][j] = f32x4{0.f, 0.f, 0.f, 0.f};

  const long long wstap = 256LL * p.Cin;

  for (int tp = 0; tp < ntap; ++tp){
    int tap = tap0 + tp;
    int dy = tap / p.tapw, dx = tap - dy * p.tapw;
    const unsigned short* wb = p.W + (long long)tap * wstap;
    long long abase[4];
    #pragma unroll
    for (int i = 0; i < 4; ++i)
      abase[i] = (apix[i] + (long long)dy * p.row_px + dx) * p.px_el + p.ch_off + cbg8[i];

    for (int cib = 0; cib < p.Cin; cib += 64){
      __syncthreads();
      #pragma unroll
      for (int i = 0; i < 4; ++i){
        __builtin_amdgcn_global_load_lds(
            (AS1 void*)(p.A + abase[i] + cib),
            (AS3 void*)(&As[i * 2048 + wid * 512]),
            16, 0, 0);
        __builtin_amdgcn_global_load_lds(
            (AS1 void*)(wb + wrow[i] + cib),
            (AS3 void*)(&Bs[i * 2048 + wid * 512]),
            16, 0, 0);
      }
      __syncthreads();
      #pragma unroll
      for (int ks = 0; ks < 2; ++ks){
        bf16x8 av[4], bv[4];
        #pragma unroll
        for (int mi = 0; mi < 4; ++mi){
          int ar = wr * 64 + mi * 16 + (lane & 15);
          int cb = (ks * 4 + (lane >> 4)) ^ (ar & 7);
          av[mi] = *reinterpret_cast<const bf16x8*>(&As[ar * 64 + cb * 8]);
        }
        #pragma unroll
        for (int ni = 0; ni < 4; ++ni){
          int br = wc * 64 + ni * 16 + (lane & 15);
          int cb = (ks * 4 + (lane >> 4)) ^ (br & 7);
          bv[ni] = *reinterpret_cast<const bf16x8*>(&Bs[br * 64 + cb * 8]);
        }
        #pragma unroll
        for (int mi = 0; mi < 4; ++mi)
          #pragma unroll
          for (int ni = 0; ni < 4; ++ni)
            acc[mi][ni] = __builtin_amdgcn_mfma_f32_16x16x32_bf16(av[mi], bv[ni], acc[mi][ni], 0, 0, 0);
      }
    }
  }

  const int r0 = (lane >> 4) * 4;
  const int c0 = lane & 15;
  #pragma unroll
  for (int mi = 0; mi < 4; ++mi){
    int nbase = mt * 128 + wr * 64 + mi * 16 + r0;
    #pragma unroll
    for (int ni = 0; ni < 4; ++ni){
      int co = nt * 128 + wc * 64 + ni * 16 + c0;
      f32x4 a = acc[mi][ni];
      if constexpr (EPI == 0){
        float sc = p.ep_scale[co], sh = p.ep_shift[co];
        unsigned short* o = (unsigned short*)p.out;
        #pragma unroll
        for (int r = 0; r < 4; ++r){
          float v = fmaf(a[r], sc, sh); v = v > 0.f ? v : 0.f;
          o[(size_t)(nbase + r) * 256 + co] = f2bf(v);
        }
      } else if constexpr (EPI == 1){
        float sc = p.ep_scale[co], sh = p.ep_shift[co];
        float* o = (float*)p.out;
        int b = nbase / 7744; int s = nbase - b * 7744;
        float4 v;
        v.x = fmaxf(fmaf(a[0], sc, sh), 0.f);
        v.y = fmaxf(fmaf(a[1], sc, sh), 0.f);
        v.z = fmaxf(fmaf(a[2], sc, sh), 0.f);
        v.w = fmaxf(fmaf(a[3], sc, sh), 0.f);
        *reinterpret_cast<float4*>(o + ((size_t)(b * 256 + co)) * 7744 + s) = v;
      } else {
        float* o = (float*)p.out + (size_t)slot * 968 * 256;
        #pragma unroll
        for (int r = 0; r < 4; ++r){
          int n = nbase + r;
          if (n < p.Mtot) o[(size_t)n * 256 + co] = a[r];
        }
      }
    }
  }
}

// ---------------------------------------------------------------- spatial mask
__global__ __launch_bounds__(256)
void mask_k(const unsigned short* __restrict__ h1, const float* __restrict__ w2,
            const float* __restrict__ b2, float* __restrict__ mask,
            unsigned short* __restrict__ FusPad)
{
  __shared__ float w[256];
  int t = threadIdx.x;
  w[t] = w2[t];
  __syncthreads();
  int n = blockIdx.x * 256 + t;
  const unsigned short* row = h1 + (size_t)n * 256;
  float s = b2[0];
  for (int c = 0; c < 256; c += 8){
    union { uint4 v; unsigned short s_[8]; } u;
    u.v = *reinterpret_cast<const uint4*>(row + c);
    #pragma unroll
    for (int j = 0; j < 8; ++j) s = fmaf(bf2f(u.s_[j]), w[c + j], s);
  }
  float m = 1.f / (1.f + __expf(-s));
  mask[n] = m;
  int b = n / 7744, sr = n - b * 7744;
  int y = sr / 88, x = sr - y * 88;
  FusPad[(((size_t)b * 90 + y + 1) * 90 + (x + 1)) * 576 + 512] = f2bf(m);
}

// ---------------------------------------------------------------- f_depth * mask -> NHWC bf16
__global__ __launch_bounds__(256)
void fdm_k(const unsigned short* __restrict__ Xpad, const float* __restrict__ mask,
           unsigned short* __restrict__ fdm)
{
  int idx = blockIdx.x * 256 + threadIdx.x;
  int n = idx >> 5, cb = idx & 31;
  int b = n / 7744, s = n - b * 7744;
  int y = s / 88, x = s - y * 88;
  size_t pix = ((size_t)(b * 90 + y + 1)) * 90 + x + 1;
  union { uint4 v; unsigned short s_[8]; } u, w;
  u.v = *reinterpret_cast<const uint4*>(Xpad + pix * 512 + 256 + cb * 8);
  float m = mask[n];
  #pragma unroll
  for (int j = 0; j < 8; ++j) w.s_[j] = f2bf(bf2f(u.s_[j]) * m);
  *reinterpret_cast<uint4*>(fdm + (size_t)n * 256 + cb * 8) = w.v;
}

// ---------------------------------------------------------------- split-K sum + channel LN
__global__ __launch_bounds__(256)
void lnkvr_k(const float* __restrict__ part, const float* __restrict__ srb,
             const float* __restrict__ lng, const float* __restrict__ lnb,
             unsigned short* __restrict__ kvr)
{
  int n = blockIdx.x, t = threadIdx.x;
  float v = srb[t];
  for (int s = 0; s < 16; ++s) v += part[((size_t)s * 968 + n) * 256 + t];
  float s1 = v, s2 = v * v;
  #pragma unroll
  for (int o = 1; o < 64; o <<= 1){ s1 += __shfl_xor(s1, o, 64); s2 += __shfl_xor(s2, o, 64); }
  __shared__ float a1[4], a2[4];
  if ((t & 63) == 0){ a1[t >> 6] = s1; a2[t >> 6] = s2; }
  __syncthreads();
  float t1 = a1[0] + a1[1] + a1[2] + a1[3];
  float t2 = a2[0] + a2[1] + a2[2] + a2[3];
  float mean = t1 * (1.f / 256.f);
  float var = t2 * (1.f / 256.f) - mean * mean;
  float rstd = rsqrtf(var + 1e-5f);
  kvr[(size_t)n * 256 + t] = f2bf((v - mean) * rstd * lng[t] + lnb[t]);
}

// ---------------------------------------------------------------- 1x1 conv 256->32 (Q and K)
__global__ __launch_bounds__(256)
void dotconv_k(const unsigned short* __restrict__ src, int mode,
               const unsigned short* __restrict__ wt, const float* __restrict__ bias,
               float* __restrict__ out)
{
  __shared__ unsigned short wl[256 * 32];
  const int t = threadIdx.x;
  {
    uint4* d = (uint4*)wl; const uint4* s = (const uint4*)wt;
    #pragma unroll
    for (int k = 0; k < 4; ++k) d[t + 256 * k] = s[t + 256 * k];
  }
  __syncthreads();
  const int n = blockIdx.x * 8 + (t >> 5);
  const int co = t & 31;
  const unsigned short* row;
  if (mode == 1){
    int b = n / 7744, s2 = n - b * 7744;
    int y = s2 / 88, x = s2 - y * 88;
    row = src + (((size_t)(b * 90 + y + 1)) * 90 + (x + 1)) * 512;
  } else {
    row = src + (size_t)n * 256;
  }
  float sum = bias[co];
  for (int c = 0; c < 256; c += 8){
    union { uint4 v; unsigned short s_[8]; } u;
    u.v = *reinterpret_cast<const uint4*>(row + c);
    #pragma unroll
    for (int j = 0; j < 8; ++j)
      sum = fmaf(bf2f(u.s_[j]), bf2f(wl[(c + j) * 32 + co]), sum);
  }
  out[(size_t)n * 32 + co] = sum;
}

// ---------------------------------------------------------------- 1x1 conv 256->256 (V) -> VBt[b][c][128m] bf16
__global__ __launch_bounds__(256)
void vconv_k(const unsigned short* __restrict__ kvr, const unsigned short* __restrict__ vwt,
             const float* __restrict__ vb, unsigned short* __restrict__ VBt)
{
  __shared__ float rowf[256];
  const int n = blockIdx.x, t = threadIdx.x;
  rowf[t] = bf2f(kvr[(size_t)n * 256 + t]);
  __syncthreads();
  float sum = vb[t];
  #pragma unroll 8
  for (int c = 0; c < 256; ++c)
    sum = fmaf(rowf[c], bf2f(vwt[(size_t)c * 256 + t]), sum);
  int b = n / 121, m = n - b * 121;
  VBt[(size_t)b * 32768 + (size_t)t * 128 + m] = f2bf(sum);
}

// ---------------------------------------------------------------- MFMA attention + LN + residual
// 512 threads = 8 waves; 128 query rows/block (wave w owns rows 16w..16w+15).
// All LDS tiles: 128-B rows, chunk (4ks+h)^(row&7) XOR swizzle (m97 0-conflict pattern).
__global__ __launch_bounds__(512, 2)
void attn_k(const float* __restrict__ Qbuf, const float* __restrict__ Kbuf,
            const unsigned short* __restrict__ VBt,
            const unsigned short* __restrict__ Xpad, int resChOff,
            unsigned short* __restrict__ FusPad, int outChOff,
            const float* __restrict__ ng, const float* __restrict__ nbv,
            const float* __restrict__ gammap)
{
  __shared__ unsigned short Vt[2][256][64];   // [kt][c][swizzled 64 bf16]  64 KB
  __shared__ unsigned short Pl[2][128][64];   // [kt][n][swizzled]          32 KB
  __shared__ unsigned short Qs[128][64];      // [n][swizzled ch]           16 KB
  __shared__ unsigned short Ks[128][64];      // [m][swizzled ch]           16 KB

  const int t = threadIdx.x;
  const int lane = t & 63;
  const int w = t >> 6;
  const int c15 = lane & 15;
  const int h = lane >> 4;

  const int bid = blockIdx.x;
  const int b = bid / 61;
  const int rb = bid - b * 61;
  const int nb0 = rb * 128;

  // ---- stage Vt via global_load_lds (wave-uniform LDS base + lane*16) ----
  const unsigned short* vsrc = VBt + (size_t)b * 32768;
  #pragma unroll
  for (int kt = 0; kt < 2; ++kt)
    #pragma unroll
    for (int i = 0; i < 4; ++i){
      int rowbase = i * 64 + w * 8;
      int c = rowbase + (lane >> 3);
      int mchunk = (lane & 7) ^ (c & 7);
      __builtin_amdgcn_global_load_lds(
        (AS1 void*)(vsrc + (size_t)c * 128 + kt * 64 + mchunk * 8),
        (AS3 void*)(&Vt[kt][rowbase][0]),
        16, 0, 0);
    }

  // ---- stage Qs (scale folded into Q) ----
  {
    const float scale = 0.17677669529663687f;  // 32^-0.5
    int n = t >> 2, part = t & 3;
    int gn = nb0 + n; if (gn > 7743) gn = 7743;
    const float* qp = Qbuf + ((size_t)b * 7744 + gn) * 32 + part * 8;
    float4 a = *reinterpret_cast<const float4*>(qp);
    float4 bb = *reinterpret_cast<const float4*>(qp + 4);
    union { uint4 v; unsigned short s_[8]; } u;
    u.s_[0] = f2bf(a.x * scale); u.s_[1] = f2bf(a.y * scale);
    u.s_[2] = f2bf(a.z * scale); u.s_[3] = f2bf(a.w * scale);
    u.s_[4] = f2bf(bb.x * scale); u.s_[5] = f2bf(bb.y * scale);
    u.s_[6] = f2bf(bb.z * scale); u.s_[7] = f2bf(bb.w * scale);
    *reinterpret_cast<uint4*>(&Qs[n][(part ^ (n & 7)) * 8]) = u.v;
  }
  // ---- stage Ks (rows m>=121 zeroed) ----
  {
    int m = t >> 2, part = t & 3;
    union { uint4 v; unsigned short s_[8]; } u;
    u.v = uint4{0, 0, 0, 0};
    if (m < 121){
      const float* kp = Kbuf + ((size_t)b * 121 + m) * 32 + part * 8;
      float4 a = *reinterpret_cast<const float4*>(kp);
      float4 bb = *reinterpret_cast<const float4*>(kp + 4);
      u.s_[0] = f2bf(a.x); u.s_[1] = f2bf(a.y); u.s_[2] = f2bf(a.z); u.s_[3] = f2bf(a.w);
      u.s_[4] = f2bf(bb.x); u.s_[5] = f2bf(bb.y); u.s_[6] = f2bf(bb.z); u.s_[7] = f2bf(bb.w);
    }
    *reinterpret_cast<uint4*>(&Ks[m][(part ^ (m & 7)) * 8]) = u.v;
  }
  __syncthreads();

  // ---- QK^T: wave w owns rows 16w..16w+15 ----
  const int nA = w * 16 + c15;
  bf16x8 aq = *reinterpret_cast<const bf16x8*>(&Qs[nA][(h ^ (nA & 7)) * 8]);
  f32x4 sv[8];
  #pragma unroll
  for (int ni = 0; ni < 8; ++ni){
    int mrow = ni * 16 + c15;
    bf16x8 bk = *reinterpret_cast<const bf16x8*>(&Ks[mrow][(h ^ (mrow & 7)) * 8]);
    sv[ni] = __builtin_amdgcn_mfma_f32_16x16x32_bf16(aq, bk, f32x4{0.f,0.f,0.f,0.f}, 0, 0, 0);
  }
  // mask m >= 121 (ni=7, col 112+c15)
  if (c15 >= 9) sv[7] = f32x4{-1e30f, -1e30f, -1e30f, -1e30f};

  // ---- softmax (wave-local: row n = 16w+4h+r, cols = c15 across ni) ----
  float rden[4];
  #pragma unroll
  for (int r = 0; r < 4; ++r){
    float mx = sv[0][r];
    #pragma unroll
    for (int ni = 1; ni < 8; ++ni) mx = fmaxf(mx, sv[ni][r]);
    #pragma unroll
    for (int o = 1; o < 16; o <<= 1) mx = fmaxf(mx, __shfl_xor(mx, o, 64));
    float sm = 0.f;
    #pragma unroll
    for (int ni = 0; ni < 8; ++ni){
      float p = __expf(sv[ni][r] - mx);
      sv[ni][r] = p;
      sm += p;
    }
    #pragma unroll
    for (int o = 1; o < 16; o <<= 1) sm += __shfl_xor(sm, o, 64);
    rden[r] = 1.f / sm;
  }
  // ---- write P (scaled) to Pl; wave-private rows, no barrier needed ----
  #pragma unroll
  for (int ni = 0; ni < 8; ++ni){
    int m = ni * 16 + c15;
    int kt = m >> 6;
    int mq = (m & 63) >> 3;
    #pragma unroll
    for (int r = 0; r < 4; ++r){
      int n = w * 16 + 4 * h + r;
      Pl[kt][n][(mq ^ (n & 7)) * 8 + (m & 7)] = f2bf(sv[ni][r] * rden[r]);
    }
  }

  // ---- PV: D[n][c] = sum_m P[n][m] * Vt[c][m] ----
  bf16x8 pa[2][2];
  #pragma unroll
  for (int kt = 0; kt < 2; ++kt)
    #pragma unroll
    for (int ks = 0; ks < 2; ++ks)
      pa[kt][ks] = *reinterpret_cast<const bf16x8*>(&Pl[kt][nA][((ks * 4 + h) ^ (nA & 7)) * 8]);

  f32x4 acc[16];
  #pragma unroll
  for (int ni = 0; ni < 16; ++ni) acc[ni] = f32x4{0.f, 0.f, 0.f, 0.f};
  #pragma unroll
  for (int ni = 0; ni < 16; ++ni){
    int crow = ni * 16 + c15;
    #pragma unroll
    for (int kt = 0; kt < 2; ++kt)
      #pragma unroll
      for (int ks = 0; ks < 2; ++ks){
        bf16x8 bv = *reinterpret_cast<const bf16x8*>(&Vt[kt][crow][((ks * 4 + h) ^ (crow & 7)) * 8]);
        acc[ni] = __builtin_amdgcn_mfma_f32_16x16x32_bf16(pa[kt][ks], bv, acc[ni], 0, 0, 0);
      }
  }

  // ---- epilogue: LN over 256 ch (wave-local) + gamma residual ----
  float ngv[16], nbb[16];
  #pragma unroll
  for (int ni = 0; ni < 16; ++ni){
    int c = ni * 16 + c15;
    ngv[ni] = ng[c]; nbb[ni] = nbv[c];
  }
  float g = gammap[0]; g = fminf(fmaxf(g, 0.f), 1.f);

  #pragma unroll
  for (int r = 0; r < 4; ++r){
    float s1 = 0.f, s2 = 0.f;
    #pragma unroll
    for (int ni = 0; ni < 16; ++ni){ float v = acc[ni][r]; s1 += v; s2 += v * v; }
    #pragma unroll
    for (int o = 1; o < 16; o <<= 1){ s1 += __shfl_xor(s1, o, 64); s2 += __shfl_xor(s2, o, 64); }
    float mean = s1 * (1.f / 256.f);
    float var = s2 * (1.f / 256.f) - mean * mean;
    float rstd = rsqrtf(var + 1e-5f);

    int nloc = w * 16 + 4 * h + r;
    int rix = nb0 + nloc;
    if (rix < 7744){
      int y = rix / 88, x = rix - y * 88;
      size_t pix = ((size_t)(b * 90) + y + 1) * 90 + (x + 1);
      const unsigned short* res = Xpad + pix * 512 + resChOff;
      unsigned short* outp = FusPad + pix * 576 + outChOff;
      #pragma unroll
      for (int ni = 0; ni < 16; ++ni){
        int c = ni * 16 + c15;
        float yv = (acc[ni][r] - mean) * rstd * ngv[ni] + nbb[ni];
        outp[c] = f2bf(bf2f(res[c]) + g * yv);
      }
    }
  }
}

// ================================================================ host
extern "C" void kernel_launch(void* const* d_in, const int* in_sizes, int n_in,
                              void* d_out, int out_size, void* d_ws, size_t ws_size,
                              hipStream_t stream)
{
  const float* P[42];
  for (int i = 0; i < 42; ++i) P[i] = (const float*)d_in[i];

  char* ws = (char*)d_ws;
  size_t off = 0;
  auto take = [&](size_t bytes) -> char* {
    char* p = ws + off; off += (bytes + 255) & ~(size_t)255; return p;
  };
  unsigned short* XPAD = (unsigned short*)take(8ull * 8100 * 512 * 2);   // 66.4 MB
  unsigned short* FUSP = (unsigned short*)take(8ull * 8100 * 576 * 2);   // 74.6 MB
  unsigned short* H1   = (unsigned short*)take(61952ull * 256 * 2);      // 31.7 MB
  unsigned short* FDM  = H1;  // alias: h1 dead after mask_k
  unsigned short* W1T  = (unsigned short*)take(9ull * 256 * 512 * 2);
  unsigned short* WFT  = (unsigned short*)take(9ull * 256 * 576 * 2);
  unsigned short* WSRA = (unsigned short*)take(64ull * 256 * 256 * 2);
  unsigned short* WSRB = (unsigned short*)take(64ull * 256 * 256 * 2);
  float* PART = (float*)take(16ull * 968 * 256 * 4);                      // 15.9 MB
  float* QB   = (float*)take(61952ull * 32 * 4);
  unsigned short* KVR = (unsigned short*)take(968ull * 256 * 2);
  float* KB   = (float*)take(968ull * 32 * 4);
  unsigned short* VBT = (unsigned short*)take(8ull * 256 * 128 * 2);      // 512 KB
  float* MASK = (float*)take(61952ull * 4);
  float* SC1 = (float*)take(256 * 4);
  float* SH1 = (float*)take(256 * 4);
  float* SCF = (float*)take(256 * 4);
  float* SHF = (float*)take(256 * 4);
  unsigned short* QWTA = (unsigned short*)take(256ull * 32 * 2);
  unsigned short* KWTA = (unsigned short*)take(256ull * 32 * 2);
  unsigned short* VWTA = (unsigned short*)take(256ull * 256 * 2);
  unsigned short* QWTB = (unsigned short*)take(256ull * 32 * 2);
  unsigned short* KWTB = (unsigned short*)take(256ull * 32 * 2);
  unsigned short* VWTB = (unsigned short*)take(256ull * 256 * 2);
  (void)ws_size; (void)in_sizes; (void)n_in; (void)out_size;

  hipMemsetAsync(XPAD, 0, 8ull * 8100 * 512 * 2, stream);
  hipMemsetAsync(FUSP, 0, 8ull * 8100 * 576 * 2, stream);
  hipMemsetAsync(VBT, 0, 8ull * 256 * 128 * 2, stream);   // zero pad rows m=121..127

  bnprep_k<<<1, 256, 0, stream>>>(P[4], P[5], P[6], P[7], P[3],
                                  P[38], P[39], P[40], P[41], P[37],
                                  SC1, SH1, SCF, SHF);
  prep_xpad_k<<<7744, 256, 0, stream>>>(P[0], P[1], XPAD);
  prep_w1t_k<<<256, 256, 0, stream>>>(P[2], W1T);
  prep_wfus_k<<<256, 256, 0, stream>>>(P[36], WFT);
  prep_wsr_k<<<256, 256, 0, stream>>>(P[16], WSRA);
  prep_wsr_k<<<256, 256, 0, stream>>>(P[28], WSRB);
  tranw_k<<<8, 256, 0, stream>>>(P[10], QWTA, 32, 256);
  tranw_k<<<8, 256, 0, stream>>>(P[12], KWTA, 32, 256);
  tranw_k<<<64, 256, 0, stream>>>(P[14], VWTA, 256, 256);
  tranw_k<<<8, 256, 0, stream>>>(P[22], QWTB, 32, 256);
  tranw_k<<<8, 256, 0, stream>>>(P[24], KWTB, 32, 256);
  tranw_k<<<64, 256, 0, stream>>>(P[26], VWTB, 256, 256);

  // conv1 3x3 (512->256) + BN + ReLU -> h1 NHWC bf16
  GemmP g1{};
  g1.A = XPAD; g1.W = W1T; g1.ep_scale = SC1; g1.ep_shift = SH1; g1.out = H1;
  g1.img_px = 8100; g1.row_px = 90; g1.px_el = 512; g1.ch_off = 0; g1.y0 = 0; g1.x0 = 0;
  g1.tapw = 3; g1.stridepix = 1; g1.out_w = 88; g1.out_imgpx = 7744;
  g1.Cin = 512; g1.Mtot = 61952; g1.Mtiles = 484; g1.Ntiles = 2; g1.k_per = 4608;
  gemm_k<0><<<968, 256, 0, stream>>>(g1);

  mask_k<<<242, 256, 0, stream>>>(H1, P[8], P[9], MASK, FUSP);
  fdm_k<<<7744, 256, 0, stream>>>(XPAD, MASK, FDM);

  // ---------------- d2r: Q from f_rgb, KV from f_depth_masked ----------------
  GemmP gs{};
  gs.A = FDM; gs.W = WSRA; gs.out = PART;
  gs.img_px = 7744; gs.row_px = 88; gs.px_el = 256; gs.ch_off = 0; gs.y0 = 0; gs.x0 = 0;
  gs.tapw = 8; gs.stridepix = 8; gs.out_w = 11; gs.out_imgpx = 121;
  gs.Cin = 256; gs.Mtot = 968; gs.Mtiles = 8; gs.Ntiles = 2; gs.k_per = 1024;
  gemm_k<2><<<256, 256, 0, stream>>>(gs);
  lnkvr_k<<<968, 256, 0, stream>>>(PART, P[17], P[18], P[19], KVR);
  dotconv_k<<<7744, 256, 0, stream>>>(XPAD, 1, QWTA, P[11], QB);
  dotconv_k<<<121, 256, 0, stream>>>(KVR, 0, KWTA, P[13], KB);
  vconv_k<<<968, 256, 0, stream>>>(KVR, VWTA, P[15], VBT);
  attn_k<<<488, 512, 0, stream>>>(QB, KB, VBT, XPAD, 0, FUSP, 0, P[20], P[21], P[34]);

  // ---------------- r2d: Q from f_depth_masked, KV from f_rgb ----------------
  gs.A = XPAD; gs.W = WSRB;
  gs.img_px = 8100; gs.row_px = 90; gs.px_el = 512; gs.y0 = 1; gs.x0 = 1;
  gemm_k<2><<<256, 256, 0, stream>>>(gs);
  lnkvr_k<<<968, 256, 0, stream>>>(PART, P[29], P[30], P[31], KVR);
  dotconv_k<<<7744, 256, 0, stream>>>(FDM, 0, QWTB, P[23], QB);
  dotconv_k<<<121, 256, 0, stream>>>(KVR, 0, KWTB, P[25], KB);
  vconv_k<<<968, 256, 0, stream>>>(KVR, VWTB, P[27], VBT);
  attn_k<<<488, 512, 0, stream>>>(QB, KB, VBT, XPAD, 256, FUSP, 256, P[32], P[33], P[35]);

  // final fused conv 3x3 (576->256) + BN + ReLU -> d_out f32 NCHW
  GemmP gf{};
  gf.A = FUSP; gf.W = WFT; gf.ep_scale = SCF; gf.ep_shift = SHF; gf.out = d_out;
  gf.img_px = 8100; gf.row_px = 90; gf.px_el = 576; gf.ch_off = 0; gf.y0 = 0; gf.x0 = 0;
  gf.tapw = 3; gf.stridepix = 1; gf.out_w = 88; gf.out_imgpx = 7744;
  gf.Cin = 576; gf.Mtot = 61952; gf.Mtiles = 484; gf.Ntiles = 2; gf.k_per = 5184;
  gemm_k<1><<<968, 256, 0, stream>>>(gf);
}

// Round 6
// 702.694 us; speedup vs baseline: 3.6820x; 1.0888x over previous
//
#include <hip/hip_runtime.h>
#include <hip/hip_bf16.h>

// BiDirectionalFusionModule on MI355X.
// All heavy convs = implicit GEMM, bf16 MFMA 16x16x32, f32 accumulate.
// Activations staged as zero-padded NHWC bf16. ~220MB workspace.
// R2: global_load_lds(16B) GEMM staging; coalesced weight preps.
// R3: fixed dotconv weight staging.
// R5: MFMA attention (8 waves, wave-local softmax/LN, swizzled LDS, V via lds-DMA).
// R6: GEMM L2-locality pass — cib-outer/tap-inner K loop (A window reused 9x at
//     1-step distance), nt-inner pid decode (N-tile pairs share A), chunked XCD
//     swizzle (contiguous pid range per XCD L2). FETCH 574MB -> target <200MB.

typedef __bf16 bf16x8 __attribute__((ext_vector_type(8)));
typedef float f32x4 __attribute__((ext_vector_type(4)));

#define AS1 __attribute__((address_space(1)))
#define AS3 __attribute__((address_space(3)))
#define DEVI __device__ __forceinline__

DEVI float bf2f(unsigned short u){
  union { unsigned int i; float f; } v; v.i = ((unsigned int)u) << 16; return v.f;
}
DEVI unsigned short f2bf(float f){
  union { float f; unsigned int i; } v; v.f = f;
  unsigned int x = v.i;
  unsigned int r = (x + 0x7fffu + ((x >> 16) & 1u)) >> 16;
  return (unsigned short)r;
}

// ---------------------------------------------------------------- BN prep
__global__ void bnprep_k(const float* __restrict__ g1, const float* __restrict__ be1,
                         const float* __restrict__ m1, const float* __restrict__ v1,
                         const float* __restrict__ b1,
                         const float* __restrict__ gf, const float* __restrict__ bef,
                         const float* __restrict__ mf, const float* __restrict__ vf,
                         const float* __restrict__ bf,
                         float* __restrict__ sc1, float* __restrict__ sh1,
                         float* __restrict__ scf, float* __restrict__ shf)
{
  int c = threadIdx.x;
  float s = g1[c] * rsqrtf(v1[c] + 1e-5f);
  sc1[c] = s; sh1[c] = (b1[c] - m1[c]) * s + be1[c];
  s = gf[c] * rsqrtf(vf[c] + 1e-5f);
  scf[c] = s; shf[c] = (bf[c] - mf[c]) * s + bef[c];
}

// ------------------------------------------------- NCHW f32 -> padded NHWC bf16
__global__ __launch_bounds__(256)
void prep_xpad_k(const float* __restrict__ rgb, const float* __restrict__ dep,
                 unsigned short* __restrict__ Xpad)
{
  __shared__ unsigned short tile[64][65];
  int bi = blockIdx.x;
  int b = bi / 968;
  int rem = bi - b * 968;
  int cblk = rem / 121;
  int pblk = rem - cblk * 121;
  int t = threadIdx.x;
  int pl = t & 63;
  #pragma unroll
  for (int pass = 0; pass < 16; ++pass){
    int cl = pass * 4 + (t >> 6);
    int c = cblk * 64 + cl;
    const float* sp = (c < 256) ? (rgb + ((size_t)b * 256 + c) * 7744)
                                : (dep + ((size_t)b * 256 + (c - 256)) * 7744);
    tile[cl][pl] = f2bf(sp[pblk * 64 + pl]);
  }
  __syncthreads();
  int cl2 = t & 63;
  for (int pass = 0; pass < 16; ++pass){
    int pl2 = pass * 4 + (t >> 6);
    int pixg = pblk * 64 + pl2;
    int y = pixg / 88, x = pixg - y * 88;
    Xpad[(((size_t)b * 90 + y + 1) * 90 + (x + 1)) * 512 + cblk * 64 + cl2] = tile[cl2][pl2];
  }
}

// ---------------------------------------------------------------- weight reshuffles
__global__ __launch_bounds__(256)
void prep_w1t_k(const float* __restrict__ w, unsigned short* __restrict__ o)
{
  int co = blockIdx.x, t = threadIdx.x;
  const float* src = w + (size_t)co * 4608 + t * 18;
  unsigned int* op = (unsigned int*)o;
  #pragma unroll
  for (int k = 0; k < 9; ++k){
    unsigned short lo = f2bf(src[k]);
    unsigned short hi = f2bf(src[9 + k]);
    op[((size_t)k * 256 + co) * 256 + t] = lo | ((unsigned int)hi << 16);
  }
}
__global__ __launch_bounds__(256)
void prep_wfus_k(const float* __restrict__ w, unsigned short* __restrict__ o)
{
  int co = blockIdx.x, t = threadIdx.x;
  const float* src = w + (size_t)co * 4617 + t * 18;
  unsigned int* op = (unsigned int*)o;
  #pragma unroll
  for (int k = 0; k < 9; ++k){
    unsigned short lo = f2bf(src[k]);
    unsigned short hi = f2bf(src[9 + k]);
    op[((size_t)k * 256 + co) * 288 + t] = lo | ((unsigned int)hi << 16);
  }
  if (t < 32){
    #pragma unroll
    for (int k = 0; k < 9; ++k){
      unsigned int val = 0;
      if (t == 0) val = (unsigned int)f2bf(w[(size_t)co * 4617 + 512 * 9 + k]);
      op[((size_t)k * 256 + co) * 288 + 256 + t] = val;
    }
  }
}
__global__ __launch_bounds__(256)
void prep_wsr_k(const float* __restrict__ w, unsigned short* __restrict__ o)
{
  __shared__ float ld[64][65];
  int co = blockIdx.x;
  int t = threadIdx.x;
  for (int cib = 0; cib < 256; cib += 64){
    int cil = t >> 2, tq = t & 3;
    const float* src = w + ((size_t)co * 256 + cib + cil) * 64 + tq * 16;
    float v[16];
    #pragma unroll
    for (int k = 0; k < 16; ++k) v[k] = src[k];
    __syncthreads();
    #pragma unroll
    for (int k = 0; k < 16; ++k) ld[cil][tq * 16 + k] = v[k];
    __syncthreads();
    #pragma unroll
    for (int tp = 0; tp < 16; ++tp){
      int tap = tp * 4 + (t >> 6);
      int ci = t & 63;
      o[((size_t)tap * 256 + co) * 256 + cib + ci] = f2bf(ld[ci][tap]);
    }
  }
}
__global__ __launch_bounds__(256)
void tranw_k(const float* __restrict__ in, unsigned short* __restrict__ out, int R, int C)
{
  __shared__ float tl[32][33];
  int tiles_c = C >> 5;
  int tr = (blockIdx.x / tiles_c) << 5, tc = (blockIdx.x % tiles_c) << 5;
  int t = threadIdx.x; int r = t >> 5, c = t & 31;
  #pragma unroll
  for (int p = 0; p < 4; ++p)
    tl[r + p * 8][c] = in[(size_t)(tr + r + p * 8) * C + tc + c];
  __syncthreads();
  #pragma unroll
  for (int p = 0; p < 4; ++p)
    out[(size_t)(tc + r + p * 8) * R + tr + c] = f2bf(tl[c][r + p * 8]);
}

// ---------------------------------------------------------------- implicit GEMM
struct GemmP {
  const unsigned short* A;
  const unsigned short* W;
  const float* ep_scale;
  const float* ep_shift;
  void* out;
  int img_px, row_px, px_el, ch_off, y0, x0;
  int tapw, stridepix, out_w, out_imgpx;
  int Cin, Mtot, Mtiles, Ntiles, k_per;
};

template<int EPI>
__global__ __launch_bounds__(256)
void gemm_k(GemmP p)
{
  __shared__ __bf16 As[128 * 64];
  __shared__ __bf16 Bs[128 * 64];
  const int t = threadIdx.x;
  const int lane = t & 63;
  const int wid = t >> 6;
  const int wr = wid >> 1, wc = wid & 1;

  // chunked XCD swizzle (grid divisible by 8) + nt-inner decode
  const int cpx = gridDim.x >> 3;
  int pid = (blockIdx.x & 7) * cpx + (blockIdx.x >> 3);
  const int mn = p.Mtiles * p.Ntiles;
  int within = pid % mn;
  int slot = pid / mn;
  int mt = within / p.Ntiles;
  int nt = within - mt * p.Ntiles;
  int kb = slot * p.k_per;
  int tap0 = kb / p.Cin;
  int ntap = p.k_per / p.Cin;

  long long apix[4]; int cbg8[4]; int wrow[4];
  #pragma unroll
  for (int i = 0; i < 4; ++i){
    int r = i * 32 + (t >> 3);
    cbg8[i] = ((t & 7) ^ (r & 7)) * 8;
    int n = mt * 128 + r;
    int nc = n < p.Mtot ? n : 0;
    int b = nc / p.out_imgpx; int rr = nc - b * p.out_imgpx;
    int yo = rr / p.out_w;    int xo = rr - yo * p.out_w;
    apix[i] = (long long)b * p.img_px + (long long)(yo * p.stridepix + p.y0) * p.row_px
            + (xo * p.stridepix + p.x0);
    wrow[i] = (nt * 128 + r) * p.Cin + cbg8[i];
  }

  f32x4 acc[4][4];
  #pragma unroll
  for (int i = 0; i < 4; ++i)
    #pragma unroll
    for (int j = 0; j < 4; ++j)
      acc[i][j] = f32x4{0.f, 0.f, 0.f, 0.f};

  const long long wstap = 256LL * p.Cin;

  // cib outer / tap inner: A window (~46KB) reused across the 9 taps at
  // 1-K-step reuse distance -> L2/L1 hits instead of HBM re-fetch.
  for (int cib = 0; cib < p.Cin; cib += 64){
    for (int tp = 0; tp < ntap; ++tp){
      int tap = tap0 + tp;
      int dy = tap / p.tapw, dx = tap - dy * p.tapw;
      const unsigned short* wb = p.W + (long long)tap * wstap + cib;
      const long long aoff = (long long)(dy * p.row_px + dx) * p.px_el + p.ch_off + cib;
      __syncthreads();
      #pragma unroll
      for (int i = 0; i < 4; ++i){
        __builtin_amdgcn_global_load_lds(
            (AS1 void*)(p.A + apix[i] * p.px_el + aoff + cbg8[i]),
            (AS3 void*)(&As[i * 2048 + wid * 512]),
            16, 0, 0);
        __builtin_amdgcn_global_load_lds(
            (AS1 void*)(wb + wrow[i]),
            (AS3 void*)(&Bs[i * 2048 + wid * 512]),
            16, 0, 0);
      }
      __syncthreads();
      #pragma unroll
      for (int ks = 0; ks < 2; ++ks){
        bf16x8 av[4], bv[4];
        #pragma unroll
        for (int mi = 0; mi < 4; ++mi){
          int ar = wr * 64 + mi * 16 + (lane & 15);
          int cb = (ks * 4 + (lane >> 4)) ^ (ar & 7);
          av[mi] = *reinterpret_cast<const bf16x8*>(&As[ar * 64 + cb * 8]);
        }
        #pragma unroll
        for (int ni = 0; ni < 4; ++ni){
          int br = wc * 64 + ni * 16 + (lane & 15);
          int cb = (ks * 4 + (lane >> 4)) ^ (br & 7);
          bv[ni] = *reinterpret_cast<const bf16x8*>(&Bs[br * 64 + cb * 8]);
        }
        #pragma unroll
        for (int mi = 0; mi < 4; ++mi)
          #pragma unroll
          for (int ni = 0; ni < 4; ++ni)
            acc[mi][ni] = __builtin_amdgcn_mfma_f32_16x16x32_bf16(av[mi], bv[ni], acc[mi][ni], 0, 0, 0);
      }
    }
  }

  const int r0 = (lane >> 4) * 4;
  const int c0 = lane & 15;
  #pragma unroll
  for (int mi = 0; mi < 4; ++mi){
    int nbase = mt * 128 + wr * 64 + mi * 16 + r0;
    #pragma unroll
    for (int ni = 0; ni < 4; ++ni){
      int co = nt * 128 + wc * 64 + ni * 16 + c0;
      f32x4 a = acc[mi][ni];
      if constexpr (EPI == 0){
        float sc = p.ep_scale[co], sh = p.ep_shift[co];
        unsigned short* o = (unsigned short*)p.out;
        #pragma unroll
        for (int r = 0; r < 4; ++r){
          float v = fmaf(a[r], sc, sh); v = v > 0.f ? v : 0.f;
          o[(size_t)(nbase + r) * 256 + co] = f2bf(v);
        }
      } else if constexpr (EPI == 1){
        float sc = p.ep_scale[co], sh = p.ep_shift[co];
        float* o = (float*)p.out;
        int b = nbase / 7744; int s = nbase - b * 7744;
        float4 v;
        v.x = fmaxf(fmaf(a[0], sc, sh), 0.f);
        v.y = fmaxf(fmaf(a[1], sc, sh), 0.f);
        v.z = fmaxf(fmaf(a[2], sc, sh), 0.f);
        v.w = fmaxf(fmaf(a[3], sc, sh), 0.f);
        *reinterpret_cast<float4*>(o + ((size_t)(b * 256 + co)) * 7744 + s) = v;
      } else {
        float* o = (float*)p.out + (size_t)slot * 968 * 256;
        #pragma unroll
        for (int r = 0; r < 4; ++r){
          int n = nbase + r;
          if (n < p.Mtot) o[(size_t)n * 256 + co] = a[r];
        }
      }
    }
  }
}

// ---------------------------------------------------------------- spatial mask
__global__ __launch_bounds__(256)
void mask_k(const unsigned short* __restrict__ h1, const float* __restrict__ w2,
            const float* __restrict__ b2, float* __restrict__ mask,
            unsigned short* __restrict__ FusPad)
{
  __shared__ float w[256];
  int t = threadIdx.x;
  w[t] = w2[t];
  __syncthreads();
  int n = blockIdx.x * 256 + t;
  const unsigned short* row = h1 + (size_t)n * 256;
  float s = b2[0];
  for (int c = 0; c < 256; c += 8){
    union { uint4 v; unsigned short s_[8]; } u;
    u.v = *reinterpret_cast<const uint4*>(row + c);
    #pragma unroll
    for (int j = 0; j < 8; ++j) s = fmaf(bf2f(u.s_[j]), w[c + j], s);
  }
  float m = 1.f / (1.f + __expf(-s));
  mask[n] = m;
  int b = n / 7744, sr = n - b * 7744;
  int y = sr / 88, x = sr - y * 88;
  FusPad[(((size_t)b * 90 + y + 1) * 90 + (x + 1)) * 576 + 512] = f2bf(m);
}

// ---------------------------------------------------------------- f_depth * mask -> NHWC bf16
__global__ __launch_bounds__(256)
void fdm_k(const unsigned short* __restrict__ Xpad, const float* __restrict__ mask,
           unsigned short* __restrict__ fdm)
{
  int idx = blockIdx.x * 256 + threadIdx.x;
  int n = idx >> 5, cb = idx & 31;
  int b = n / 7744, s = n - b * 7744;
  int y = s / 88, x = s - y * 88;
  size_t pix = ((size_t)(b * 90 + y + 1)) * 90 + x + 1;
  union { uint4 v; unsigned short s_[8]; } u, w;
  u.v = *reinterpret_cast<const uint4*>(Xpad + pix * 512 + 256 + cb * 8);
  float m = mask[n];
  #pragma unroll
  for (int j = 0; j < 8; ++j) w.s_[j] = f2bf(bf2f(u.s_[j]) * m);
  *reinterpret_cast<uint4*>(fdm + (size_t)n * 256 + cb * 8) = w.v;
}

// ---------------------------------------------------------------- split-K sum + channel LN
__global__ __launch_bounds__(256)
void lnkvr_k(const float* __restrict__ part, const float* __restrict__ srb,
             const float* __restrict__ lng, const float* __restrict__ lnb,
             unsigned short* __restrict__ kvr)
{
  int n = blockIdx.x, t = threadIdx.x;
  float v = srb[t];
  for (int s = 0; s < 16; ++s) v += part[((size_t)s * 968 + n) * 256 + t];
  float s1 = v, s2 = v * v;
  #pragma unroll
  for (int o = 1; o < 64; o <<= 1){ s1 += __shfl_xor(s1, o, 64); s2 += __shfl_xor(s2, o, 64); }
  __shared__ float a1[4], a2[4];
  if ((t & 63) == 0){ a1[t >> 6] = s1; a2[t >> 6] = s2; }
  __syncthreads();
  float t1 = a1[0] + a1[1] + a1[2] + a1[3];
  float t2 = a2[0] + a2[1] + a2[2] + a2[3];
  float mean = t1 * (1.f / 256.f);
  float var = t2 * (1.f / 256.f) - mean * mean;
  float rstd = rsqrtf(var + 1e-5f);
  kvr[(size_t)n * 256 + t] = f2bf((v - mean) * rstd * lng[t] + lnb[t]);
}

// ---------------------------------------------------------------- 1x1 conv 256->32 (Q and K)
__global__ __launch_bounds__(256)
void dotconv_k(const unsigned short* __restrict__ src, int mode,
               const unsigned short* __restrict__ wt, const float* __restrict__ bias,
               float* __restrict__ out)
{
  __shared__ unsigned short wl[256 * 32];
  const int t = threadIdx.x;
  {
    uint4* d = (uint4*)wl; const uint4* s = (const uint4*)wt;
    #pragma unroll
    for (int k = 0; k < 4; ++k) d[t + 256 * k] = s[t + 256 * k];
  }
  __syncthreads();
  const int n = blockIdx.x * 8 + (t >> 5);
  const int co = t & 31;
  const unsigned short* row;
  if (mode == 1){
    int b = n / 7744, s2 = n - b * 7744;
    int y = s2 / 88, x = s2 - y * 88;
    row = src + (((size_t)(b * 90 + y + 1)) * 90 + (x + 1)) * 512;
  } else {
    row = src + (size_t)n * 256;
  }
  float sum = bias[co];
  for (int c = 0; c < 256; c += 8){
    union { uint4 v; unsigned short s_[8]; } u;
    u.v = *reinterpret_cast<const uint4*>(row + c);
    #pragma unroll
    for (int j = 0; j < 8; ++j)
      sum = fmaf(bf2f(u.s_[j]), bf2f(wl[(c + j) * 32 + co]), sum);
  }
  out[(size_t)n * 32 + co] = sum;
}

// ---------------------------------------------------------------- 1x1 conv 256->256 (V) -> VBt[b][c][128m] bf16
__global__ __launch_bounds__(256)
void vconv_k(const unsigned short* __restrict__ kvr, const unsigned short* __restrict__ vwt,
             const float* __restrict__ vb, unsigned short* __restrict__ VBt)
{
  __shared__ float rowf[256];
  const int n = blockIdx.x, t = threadIdx.x;
  rowf[t] = bf2f(kvr[(size_t)n * 256 + t]);
  __syncthreads();
  float sum = vb[t];
  #pragma unroll 8
  for (int c = 0; c < 256; ++c)
    sum = fmaf(rowf[c], bf2f(vwt[(size_t)c * 256 + t]), sum);
  int b = n / 121, m = n - b * 121;
  VBt[(size_t)b * 32768 + (size_t)t * 128 + m] = f2bf(sum);
}

// ---------------------------------------------------------------- MFMA attention + LN + residual
__global__ __launch_bounds__(512, 2)
void attn_k(const float* __restrict__ Qbuf, const float* __restrict__ Kbuf,
            const unsigned short* __restrict__ VBt,
            const unsigned short* __restrict__ Xpad, int resChOff,
            unsigned short* __restrict__ FusPad, int outChOff,
            const float* __restrict__ ng, const float* __restrict__ nbv,
            const float* __restrict__ gammap)
{
  __shared__ unsigned short Vt[2][256][64];
  __shared__ unsigned short Pl[2][128][64];
  __shared__ unsigned short Qs[128][64];
  __shared__ unsigned short Ks[128][64];

  const int t = threadIdx.x;
  const int lane = t & 63;
  const int w = t >> 6;
  const int c15 = lane & 15;
  const int h = lane >> 4;

  const int bid = blockIdx.x;
  const int b = bid / 61;
  const int rb = bid - b * 61;
  const int nb0 = rb * 128;

  const unsigned short* vsrc = VBt + (size_t)b * 32768;
  #pragma unroll
  for (int kt = 0; kt < 2; ++kt)
    #pragma unroll
    for (int i = 0; i < 4; ++i){
      int rowbase = i * 64 + w * 8;
      int c = rowbase + (lane >> 3);
      int mchunk = (lane & 7) ^ (c & 7);
      __builtin_amdgcn_global_load_lds(
        (AS1 void*)(vsrc + (size_t)c * 128 + kt * 64 + mchunk * 8),
        (AS3 void*)(&Vt[kt][rowbase][0]),
        16, 0, 0);
    }

  {
    const float scale = 0.17677669529663687f;  // 32^-0.5
    int n = t >> 2, part = t & 3;
    int gn = nb0 + n; if (gn > 7743) gn = 7743;
    const float* qp = Qbuf + ((size_t)b * 7744 + gn) * 32 + part * 8;
    float4 a = *reinterpret_cast<const float4*>(qp);
    float4 bb = *reinterpret_cast<const float4*>(qp + 4);
    union { uint4 v; unsigned short s_[8]; } u;
    u.s_[0] = f2bf(a.x * scale); u.s_[1] = f2bf(a.y * scale);
    u.s_[2] = f2bf(a.z * scale); u.s_[3] = f2bf(a.w * scale);
    u.s_[4] = f2bf(bb.x * scale); u.s_[5] = f2bf(bb.y * scale);
    u.s_[6] = f2bf(bb.z * scale); u.s_[7] = f2bf(bb.w * scale);
    *reinterpret_cast<uint4*>(&Qs[n][(part ^ (n & 7)) * 8]) = u.v;
  }
  {
    int m = t >> 2, part = t & 3;
    union { uint4 v; unsigned short s_[8]; } u;
    u.v = uint4{0, 0, 0, 0};
    if (m < 121){
      const float* kp = Kbuf + ((size_t)b * 121 + m) * 32 + part * 8;
      float4 a = *reinterpret_cast<const float4*>(kp);
      float4 bb = *reinterpret_cast<const float4*>(kp + 4);
      u.s_[0] = f2bf(a.x); u.s_[1] = f2bf(a.y); u.s_[2] = f2bf(a.z); u.s_[3] = f2bf(a.w);
      u.s_[4] = f2bf(bb.x); u.s_[5] = f2bf(bb.y); u.s_[6] = f2bf(bb.z); u.s_[7] = f2bf(bb.w);
    }
    *reinterpret_cast<uint4*>(&Ks[m][(part ^ (m & 7)) * 8]) = u.v;
  }
  __syncthreads();

  const int nA = w * 16 + c15;
  bf16x8 aq = *reinterpret_cast<const bf16x8*>(&Qs[nA][(h ^ (nA & 7)) * 8]);
  f32x4 sv[8];
  #pragma unroll
  for (int ni = 0; ni < 8; ++ni){
    int mrow = ni * 16 + c15;
    bf16x8 bk = *reinterpret_cast<const bf16x8*>(&Ks[mrow][(h ^ (mrow & 7)) * 8]);
    sv[ni] = __builtin_amdgcn_mfma_f32_16x16x32_bf16(aq, bk, f32x4{0.f,0.f,0.f,0.f}, 0, 0, 0);
  }
  if (c15 >= 9) sv[7] = f32x4{-1e30f, -1e30f, -1e30f, -1e30f};

  float rden[4];
  #pragma unroll
  for (int r = 0; r < 4; ++r){
    float mx = sv[0][r];
    #pragma unroll
    for (int ni = 1; ni < 8; ++ni) mx = fmaxf(mx, sv[ni][r]);
    #pragma unroll
    for (int o = 1; o < 16; o <<= 1) mx = fmaxf(mx, __shfl_xor(mx, o, 64));
    float sm = 0.f;
    #pragma unroll
    for (int ni = 0; ni < 8; ++ni){
      float p = __expf(sv[ni][r] - mx);
      sv[ni][r] = p;
      sm += p;
    }
    #pragma unroll
    for (int o = 1; o < 16; o <<= 1) sm += __shfl_xor(sm, o, 64);
    rden[r] = 1.f / sm;
  }
  #pragma unroll
  for (int ni = 0; ni < 8; ++ni){
    int m = ni * 16 + c15;
    int kt = m >> 6;
    int mq = (m & 63) >> 3;
    #pragma unroll
    for (int r = 0; r < 4; ++r){
      int n = w * 16 + 4 * h + r;
      Pl[kt][n][(mq ^ (n & 7)) * 8 + (m & 7)] = f2bf(sv[ni][r] * rden[r]);
    }
  }

  bf16x8 pa[2][2];
  #pragma unroll
  for (int kt = 0; kt < 2; ++kt)
    #pragma unroll
    for (int ks = 0; ks < 2; ++ks)
      pa[kt][ks] = *reinterpret_cast<const bf16x8*>(&Pl[kt][nA][((ks * 4 + h) ^ (nA & 7)) * 8]);

  f32x4 acc[16];
  #pragma unroll
  for (int ni = 0; ni < 16; ++ni) acc[ni] = f32x4{0.f, 0.f, 0.f, 0.f};
  #pragma unroll
  for (int ni = 0; ni < 16; ++ni){
    int crow = ni * 16 + c15;
    #pragma unroll
    for (int kt = 0; kt < 2; ++kt)
      #pragma unroll
      for (int ks = 0; ks < 2; ++ks){
        bf16x8 bv = *reinterpret_cast<const bf16x8*>(&Vt[kt][crow][((ks * 4 + h) ^ (crow & 7)) * 8]);
        acc[ni] = __builtin_amdgcn_mfma_f32_16x16x32_bf16(pa[kt][ks], bv, acc[ni], 0, 0, 0);
      }
  }

  float ngv[16], nbb[16];
  #pragma unroll
  for (int ni = 0; ni < 16; ++ni){
    int c = ni * 16 + c15;
    ngv[ni] = ng[c]; nbb[ni] = nbv[c];
  }
  float g = gammap[0]; g = fminf(fmaxf(g, 0.f), 1.f);

  #pragma unroll
  for (int r = 0; r < 4; ++r){
    float s1 = 0.f, s2 = 0.f;
    #pragma unroll
    for (int ni = 0; ni < 16; ++ni){ float v = acc[ni][r]; s1 += v; s2 += v * v; }
    #pragma unroll
    for (int o = 1; o < 16; o <<= 1){ s1 += __shfl_xor(s1, o, 64); s2 += __shfl_xor(s2, o, 64); }
    float mean = s1 * (1.f / 256.f);
    float var = s2 * (1.f / 256.f) - mean * mean;
    float rstd = rsqrtf(var + 1e-5f);

    int nloc = w * 16 + 4 * h + r;
    int rix = nb0 + nloc;
    if (rix < 7744){
      int y = rix / 88, x = rix - y * 88;
      size_t pix = ((size_t)(b * 90) + y + 1) * 90 + (x + 1);
      const unsigned short* res = Xpad + pix * 512 + resChOff;
      unsigned short* outp = FusPad + pix * 576 + outChOff;
      #pragma unroll
      for (int ni = 0; ni < 16; ++ni){
        int c = ni * 16 + c15;
        float yv = (acc[ni][r] - mean) * rstd * ngv[ni] + nbb[ni];
        outp[c] = f2bf(bf2f(res[c]) + g * yv);
      }
    }
  }
}

// ================================================================ host
extern "C" void kernel_launch(void* const* d_in, const int* in_sizes, int n_in,
                              void* d_out, int out_size, void* d_ws, size_t ws_size,
                              hipStream_t stream)
{
  const float* P[42];
  for (int i = 0; i < 42; ++i) P[i] = (const float*)d_in[i];

  char* ws = (char*)d_ws;
  size_t off = 0;
  auto take = [&](size_t bytes) -> char* {
    char* p = ws + off; off += (bytes + 255) & ~(size_t)255; return p;
  };
  unsigned short* XPAD = (unsigned short*)take(8ull * 8100 * 512 * 2);   // 66.4 MB
  unsigned short* FUSP = (unsigned short*)take(8ull * 8100 * 576 * 2);   // 74.6 MB
  unsigned short* H1   = (unsigned short*)take(61952ull * 256 * 2);      // 31.7 MB
  unsigned short* FDM  = H1;  // alias: h1 dead after mask_k
  unsigned short* W1T  = (unsigned short*)take(9ull * 256 * 512 * 2);
  unsigned short* WFT  = (unsigned short*)take(9ull * 256 * 576 * 2);
  unsigned short* WSRA = (unsigned short*)take(64ull * 256 * 256 * 2);
  unsigned short* WSRB = (unsigned short*)take(64ull * 256 * 256 * 2);
  float* PART = (float*)take(16ull * 968 * 256 * 4);                      // 15.9 MB
  float* QB   = (float*)take(61952ull * 32 * 4);
  unsigned short* KVR = (unsigned short*)take(968ull * 256 * 2);
  float* KB   = (float*)take(968ull * 32 * 4);
  unsigned short* VBT = (unsigned short*)take(8ull * 256 * 128 * 2);      // 512 KB
  float* MASK = (float*)take(61952ull * 4);
  float* SC1 = (float*)take(256 * 4);
  float* SH1 = (float*)take(256 * 4);
  float* SCF = (float*)take(256 * 4);
  float* SHF = (float*)take(256 * 4);
  unsigned short* QWTA = (unsigned short*)take(256ull * 32 * 2);
  unsigned short* KWTA = (unsigned short*)take(256ull * 32 * 2);
  unsigned short* VWTA = (unsigned short*)take(256ull * 256 * 2);
  unsigned short* QWTB = (unsigned short*)take(256ull * 32 * 2);
  unsigned short* KWTB = (unsigned short*)take(256ull * 32 * 2);
  unsigned short* VWTB = (unsigned short*)take(256ull * 256 * 2);
  (void)ws_size; (void)in_sizes; (void)n_in; (void)out_size;

  hipMemsetAsync(XPAD, 0, 8ull * 8100 * 512 * 2, stream);
  hipMemsetAsync(FUSP, 0, 8ull * 8100 * 576 * 2, stream);
  hipMemsetAsync(VBT, 0, 8ull * 256 * 128 * 2, stream);

  bnprep_k<<<1, 256, 0, stream>>>(P[4], P[5], P[6], P[7], P[3],
                                  P[38], P[39], P[40], P[41], P[37],
                                  SC1, SH1, SCF, SHF);
  prep_xpad_k<<<7744, 256, 0, stream>>>(P[0], P[1], XPAD);
  prep_w1t_k<<<256, 256, 0, stream>>>(P[2], W1T);
  prep_wfus_k<<<256, 256, 0, stream>>>(P[36], WFT);
  prep_wsr_k<<<256, 256, 0, stream>>>(P[16], WSRA);
  prep_wsr_k<<<256, 256, 0, stream>>>(P[28], WSRB);
  tranw_k<<<8, 256, 0, stream>>>(P[10], QWTA, 32, 256);
  tranw_k<<<8, 256, 0, stream>>>(P[12], KWTA, 32, 256);
  tranw_k<<<64, 256, 0, stream>>>(P[14], VWTA, 256, 256);
  tranw_k<<<8, 256, 0, stream>>>(P[22], QWTB, 32, 256);
  tranw_k<<<8, 256, 0, stream>>>(P[24], KWTB, 32, 256);
  tranw_k<<<64, 256, 0, stream>>>(P[26], VWTB, 256, 256);

  // conv1 3x3 (512->256) + BN + ReLU -> h1 NHWC bf16
  GemmP g1{};
  g1.A = XPAD; g1.W = W1T; g1.ep_scale = SC1; g1.ep_shift = SH1; g1.out = H1;
  g1.img_px = 8100; g1.row_px = 90; g1.px_el = 512; g1.ch_off = 0; g1.y0 = 0; g1.x0 = 0;
  g1.tapw = 3; g1.stridepix = 1; g1.out_w = 88; g1.out_imgpx = 7744;
  g1.Cin = 512; g1.Mtot = 61952; g1.Mtiles = 484; g1.Ntiles = 2; g1.k_per = 4608;
  gemm_k<0><<<968, 256, 0, stream>>>(g1);

  mask_k<<<242, 256, 0, stream>>>(H1, P[8], P[9], MASK, FUSP);
  fdm_k<<<7744, 256, 0, stream>>>(XPAD, MASK, FDM);

  // ---------------- d2r: Q from f_rgb, KV from f_depth_masked ----------------
  GemmP gs{};
  gs.A = FDM; gs.W = WSRA; gs.out = PART;
  gs.img_px = 7744; gs.row_px = 88; gs.px_el = 256; gs.ch_off = 0; gs.y0 = 0; gs.x0 = 0;
  gs.tapw = 8; gs.stridepix = 8; gs.out_w = 11; gs.out_imgpx = 121;
  gs.Cin = 256; gs.Mtot = 968; gs.Mtiles = 8; gs.Ntiles = 2; gs.k_per = 1024;
  gemm_k<2><<<256, 256, 0, stream>>>(gs);
  lnkvr_k<<<968, 256, 0, stream>>>(PART, P[17], P[18], P[19], KVR);
  dotconv_k<<<7744, 256, 0, stream>>>(XPAD, 1, QWTA, P[11], QB);
  dotconv_k<<<121, 256, 0, stream>>>(KVR, 0, KWTA, P[13], KB);
  vconv_k<<<968, 256, 0, stream>>>(KVR, VWTA, P[15], VBT);
  attn_k<<<488, 512, 0, stream>>>(QB, KB, VBT, XPAD, 0, FUSP, 0, P[20], P[21], P[34]);

  // ---------------- r2d: Q from f_depth_masked, KV from f_rgb ----------------
  gs.A = XPAD; gs.W = WSRB;
  gs.img_px = 8100; gs.row_px = 90; gs.px_el = 512; gs.y0 = 1; gs.x0 = 1;
  gemm_k<2><<<256, 256, 0, stream>>>(gs);
  lnkvr_k<<<968, 256, 0, stream>>>(PART, P[29], P[30], P[31], KVR);
  dotconv_k<<<7744, 256, 0, stream>>>(FDM, 0, QWTB, P[23], QB);
  dotconv_k<<<121, 256, 0, stream>>>(KVR, 0, KWTB, P[25], KB);
  vconv_k<<<968, 256, 0, stream>>>(KVR, VWTB, P[27], VBT);
  attn_k<<<488, 512, 0, stream>>>(QB, KB, VBT, XPAD, 256, FUSP, 256, P[32], P[33], P[35]);

  // final fused conv 3x3 (576->256) + BN + ReLU -> d_out f32 NCHW
  GemmP gf{};
  gf.A = FUSP; gf.W = WFT; gf.ep_scale = SCF; gf.ep_shift = SHF; gf.out = d_out;
  gf.img_px = 8100; gf.row_px = 90; gf.px_el = 576; gf.ch_off = 0; gf.y0 = 0; gf.x0 = 0;
  gf.tapw = 3; gf.stridepix = 1; gf.out_w = 88; gf.out_imgpx = 7744;
  gf.Cin = 576; gf.Mtot = 61952; gf.Mtiles = 484; gf.Ntiles = 2; gf.k_per = 5184;
  gemm_k<1><<<968, 256, 0, stream>>>(gf);
}

// Round 7
// 615.022 us; speedup vs baseline: 4.2069x; 1.1426x over previous
//
#include <hip/hip_runtime.h>
#include <hip/hip_bf16.h>

// BiDirectionalFusionModule on MI355X.
// All heavy convs = implicit GEMM, bf16 MFMA 16x16x32, f32 accumulate.
// Activations staged as zero-padded NHWC bf16. ~220MB workspace.
// R2: global_load_lds(16B) GEMM staging; coalesced weight preps.
// R3: fixed dotconv weight staging.
// R5: MFMA attention (8 waves, wave-local softmax/LN, swizzled LDS, V via lds-DMA).
// R6: GEMM L2-locality (cib-outer/tap-inner, nt-inner, XCD chunk swizzle): FETCH 574->60MB.
// R7: Q-projection fused into attn_k as MFMA prologue (kills 2x dotconv<7744> + QB
//     round-trip); targeted border/tail zeroing replaces 141MB of memsets.

typedef __bf16 bf16x8 __attribute__((ext_vector_type(8)));
typedef float f32x4 __attribute__((ext_vector_type(4)));

#define AS1 __attribute__((address_space(1)))
#define AS3 __attribute__((address_space(3)))
#define DEVI __device__ __forceinline__

DEVI float bf2f(unsigned short u){
  union { unsigned int i; float f; } v; v.i = ((unsigned int)u) << 16; return v.f;
}
DEVI unsigned short f2bf(float f){
  union { float f; unsigned int i; } v; v.f = f;
  unsigned int x = v.i;
  unsigned int r = (x + 0x7fffu + ((x >> 16) & 1u)) >> 16;
  return (unsigned short)r;
}

// ---------------------------------------------------------------- BN prep
__global__ void bnprep_k(const float* __restrict__ g1, const float* __restrict__ be1,
                         const float* __restrict__ m1, const float* __restrict__ v1,
                         const float* __restrict__ b1,
                         const float* __restrict__ gf, const float* __restrict__ bef,
                         const float* __restrict__ mf, const float* __restrict__ vf,
                         const float* __restrict__ bf,
                         float* __restrict__ sc1, float* __restrict__ sh1,
                         float* __restrict__ scf, float* __restrict__ shf)
{
  int c = threadIdx.x;
  float s = g1[c] * rsqrtf(v1[c] + 1e-5f);
  sc1[c] = s; sh1[c] = (b1[c] - m1[c]) * s + be1[c];
  s = gf[c] * rsqrtf(vf[c] + 1e-5f);
  scf[c] = s; shf[c] = (bf[c] - mf[c]) * s + bef[c];
}

// ---------------------------------------------------------------- targeted zeroing
// Zero one border pixel-row (all px_el channels) per block. 8*356 blocks.
__global__ __launch_bounds__(128)
void zero_border_k(unsigned short* __restrict__ buf, int px_el)
{
  int bi = blockIdx.x;
  int img = bi / 356, e = bi - img * 356;
  int y, x;
  if (e < 90){ y = 0; x = e; }
  else if (e < 180){ y = 89; x = e - 90; }
  else if (e < 268){ y = e - 180 + 1; x = 0; }
  else { y = e - 268 + 1; x = 89; }
  size_t pix = ((size_t)img * 90 + y) * 90 + x;
  int t = threadIdx.x;
  if (t < (px_el >> 3))
    *reinterpret_cast<uint4*>(buf + pix * px_el + t * 8) = uint4{0, 0, 0, 0};
}
// Zero FusPad interior channels 512..575 (ch512 later overwritten by mask_k).
__global__ __launch_bounds__(256)
void zero_fustail_k(unsigned short* __restrict__ FusPad)
{
  int idx = blockIdx.x * 256 + threadIdx.x;   // 61952*8
  int n = idx >> 3, ch = idx & 7;
  int b = n / 7744, s = n - b * 7744;
  int y = s / 88, x = s - y * 88;
  size_t pix = ((size_t)(b * 90 + y + 1)) * 90 + (x + 1);
  *reinterpret_cast<uint4*>(FusPad + pix * 576 + 512 + ch * 8) = uint4{0, 0, 0, 0};
}

// ------------------------------------------------- NCHW f32 -> padded NHWC bf16
__global__ __launch_bounds__(256)
void prep_xpad_k(const float* __restrict__ rgb, const float* __restrict__ dep,
                 unsigned short* __restrict__ Xpad)
{
  __shared__ unsigned short tile[64][65];
  int bi = blockIdx.x;
  int b = bi / 968;
  int rem = bi - b * 968;
  int cblk = rem / 121;
  int pblk = rem - cblk * 121;
  int t = threadIdx.x;
  int pl = t & 63;
  #pragma unroll
  for (int pass = 0; pass < 16; ++pass){
    int cl = pass * 4 + (t >> 6);
    int c = cblk * 64 + cl;
    const float* sp = (c < 256) ? (rgb + ((size_t)b * 256 + c) * 7744)
                                : (dep + ((size_t)b * 256 + (c - 256)) * 7744);
    tile[cl][pl] = f2bf(sp[pblk * 64 + pl]);
  }
  __syncthreads();
  int cl2 = t & 63;
  for (int pass = 0; pass < 16; ++pass){
    int pl2 = pass * 4 + (t >> 6);
    int pixg = pblk * 64 + pl2;
    int y = pixg / 88, x = pixg - y * 88;
    Xpad[(((size_t)b * 90 + y + 1) * 90 + (x + 1)) * 512 + cblk * 64 + cl2] = tile[cl2][pl2];
  }
}

// ---------------------------------------------------------------- weight reshuffles
__global__ __launch_bounds__(256)
void prep_w1t_k(const float* __restrict__ w, unsigned short* __restrict__ o)
{
  int co = blockIdx.x, t = threadIdx.x;
  const float* src = w + (size_t)co * 4608 + t * 18;
  unsigned int* op = (unsigned int*)o;
  #pragma unroll
  for (int k = 0; k < 9; ++k){
    unsigned short lo = f2bf(src[k]);
    unsigned short hi = f2bf(src[9 + k]);
    op[((size_t)k * 256 + co) * 256 + t] = lo | ((unsigned int)hi << 16);
  }
}
__global__ __launch_bounds__(256)
void prep_wfus_k(const float* __restrict__ w, unsigned short* __restrict__ o)
{
  int co = blockIdx.x, t = threadIdx.x;
  const float* src = w + (size_t)co * 4617 + t * 18;
  unsigned int* op = (unsigned int*)o;
  #pragma unroll
  for (int k = 0; k < 9; ++k){
    unsigned short lo = f2bf(src[k]);
    unsigned short hi = f2bf(src[9 + k]);
    op[((size_t)k * 256 + co) * 288 + t] = lo | ((unsigned int)hi << 16);
  }
  if (t < 32){
    #pragma unroll
    for (int k = 0; k < 9; ++k){
      unsigned int val = 0;
      if (t == 0) val = (unsigned int)f2bf(w[(size_t)co * 4617 + 512 * 9 + k]);
      op[((size_t)k * 256 + co) * 288 + 256 + t] = val;
    }
  }
}
__global__ __launch_bounds__(256)
void prep_wsr_k(const float* __restrict__ w, unsigned short* __restrict__ o)
{
  __shared__ float ld[64][65];
  int co = blockIdx.x;
  int t = threadIdx.x;
  for (int cib = 0; cib < 256; cib += 64){
    int cil = t >> 2, tq = t & 3;
    const float* src = w + ((size_t)co * 256 + cib + cil) * 64 + tq * 16;
    float v[16];
    #pragma unroll
    for (int k = 0; k < 16; ++k) v[k] = src[k];
    __syncthreads();
    #pragma unroll
    for (int k = 0; k < 16; ++k) ld[cil][tq * 16 + k] = v[k];
    __syncthreads();
    #pragma unroll
    for (int tp = 0; tp < 16; ++tp){
      int tap = tp * 4 + (t >> 6);
      int ci = t & 63;
      o[((size_t)tap * 256 + co) * 256 + cib + ci] = f2bf(ld[ci][tap]);
    }
  }
}
__global__ __launch_bounds__(256)
void tranw_k(const float* __restrict__ in, unsigned short* __restrict__ out, int R, int C)
{
  __shared__ float tl[32][33];
  int tiles_c = C >> 5;
  int tr = (blockIdx.x / tiles_c) << 5, tc = (blockIdx.x % tiles_c) << 5;
  int t = threadIdx.x; int r = t >> 5, c = t & 31;
  #pragma unroll
  for (int p = 0; p < 4; ++p)
    tl[r + p * 8][c] = in[(size_t)(tr + r + p * 8) * C + tc + c];
  __syncthreads();
  #pragma unroll
  for (int p = 0; p < 4; ++p)
    out[(size_t)(tc + r + p * 8) * R + tr + c] = f2bf(tl[c][r + p * 8]);
}
// Wq (32,256) f32 -> bf16 [32][256] with chunk XOR swizzle pre-applied
__global__ __launch_bounds__(256)
void wqprep_k(const float* __restrict__ w, unsigned short* __restrict__ o)
{
  int co = blockIdx.x, t = threadIdx.x;
  int c = t >> 3, e = t & 7;
  o[co * 256 + ((c ^ (co & 7)) * 8) + e] = f2bf(w[co * 256 + t]);
}

// ---------------------------------------------------------------- implicit GEMM
struct GemmP {
  const unsigned short* A;
  const unsigned short* W;
  const float* ep_scale;
  const float* ep_shift;
  void* out;
  int img_px, row_px, px_el, ch_off, y0, x0;
  int tapw, stridepix, out_w, out_imgpx;
  int Cin, Mtot, Mtiles, Ntiles, k_per;
};

template<int EPI>
__global__ __launch_bounds__(256)
void gemm_k(GemmP p)
{
  __shared__ __bf16 As[128 * 64];
  __shared__ __bf16 Bs[128 * 64];
  const int t = threadIdx.x;
  const int lane = t & 63;
  const int wid = t >> 6;
  const int wr = wid >> 1, wc = wid & 1;

  const int cpx = gridDim.x >> 3;
  int pid = (blockIdx.x & 7) * cpx + (blockIdx.x >> 3);
  const int mn = p.Mtiles * p.Ntiles;
  int within = pid % mn;
  int slot = pid / mn;
  int mt = within / p.Ntiles;
  int nt = within - mt * p.Ntiles;
  int kb = slot * p.k_per;
  int tap0 = kb / p.Cin;
  int ntap = p.k_per / p.Cin;

  long long apix[4]; int cbg8[4]; int wrow[4];
  #pragma unroll
  for (int i = 0; i < 4; ++i){
    int r = i * 32 + (t >> 3);
    cbg8[i] = ((t & 7) ^ (r & 7)) * 8;
    int n = mt * 128 + r;
    int nc = n < p.Mtot ? n : 0;
    int b = nc / p.out_imgpx; int rr = nc - b * p.out_imgpx;
    int yo = rr / p.out_w;    int xo = rr - yo * p.out_w;
    apix[i] = (long long)b * p.img_px + (long long)(yo * p.stridepix + p.y0) * p.row_px
            + (xo * p.stridepix + p.x0);
    wrow[i] = (nt * 128 + r) * p.Cin + cbg8[i];
  }

  f32x4 acc[4][4];
  #pragma unroll
  for (int i = 0; i < 4; ++i)
    #pragma unroll
    for (int j = 0; j < 4; ++j)
      acc[i][j] = f32x4{0.f, 0.f, 0.f, 0.f};

  const long long wstap = 256LL * p.Cin;

  for (int cib = 0; cib < p.Cin; cib += 64){
    for (int tp = 0; tp < ntap; ++tp){
      int tap = tap0 + tp;
      int dy = tap / p.tapw, dx = tap - dy * p.tapw;
      const unsigned short* wb = p.W + (long long)tap * wstap + cib;
      const long long aoff = (long long)(dy * p.row_px + dx) * p.px_el + p.ch_off + cib;
      __syncthreads();
      #pragma unroll
      for (int i = 0; i < 4; ++i){
        __builtin_amdgcn_global_load_lds(
            (AS1 void*)(p.A + apix[i] * p.px_el + aoff + cbg8[i]),
            (AS3 void*)(&As[i * 2048 + wid * 512]),
            16, 0, 0);
        __builtin_amdgcn_global_load_lds(
            (AS1 void*)(wb + wrow[i]),
            (AS3 void*)(&Bs[i * 2048 + wid * 512]),
            16, 0, 0);
      }
      __syncthreads();
      #pragma unroll
      for (int ks = 0; ks < 2; ++ks){
        bf16x8 av[4], bv[4];
        #pragma unroll
        for (int mi = 0; mi < 4; ++mi){
          int ar = wr * 64 + mi * 16 + (lane & 15);
          int cb = (ks * 4 + (lane >> 4)) ^ (ar & 7);
          av[mi] = *reinterpret_cast<const bf16x8*>(&As[ar * 64 + cb * 8]);
        }
        #pragma unroll
        for (int ni = 0; ni < 4; ++ni){
          int br = wc * 64 + ni * 16 + (lane & 15);
          int cb = (ks * 4 + (lane >> 4)) ^ (br & 7);
          bv[ni] = *reinterpret_cast<const bf16x8*>(&Bs[br * 64 + cb * 8]);
        }
        #pragma unroll
        for (int mi = 0; mi < 4; ++mi)
          #pragma unroll
          for (int ni = 0; ni < 4; ++ni)
            acc[mi][ni] = __builtin_amdgcn_mfma_f32_16x16x32_bf16(av[mi], bv[ni], acc[mi][ni], 0, 0, 0);
      }
    }
  }

  const int r0 = (lane >> 4) * 4;
  const int c0 = lane & 15;
  #pragma unroll
  for (int mi = 0; mi < 4; ++mi){
    int nbase = mt * 128 + wr * 64 + mi * 16 + r0;
    #pragma unroll
    for (int ni = 0; ni < 4; ++ni){
      int co = nt * 128 + wc * 64 + ni * 16 + c0;
      f32x4 a = acc[mi][ni];
      if constexpr (EPI == 0){
        float sc = p.ep_scale[co], sh = p.ep_shift[co];
        unsigned short* o = (unsigned short*)p.out;
        #pragma unroll
        for (int r = 0; r < 4; ++r){
          float v = fmaf(a[r], sc, sh); v = v > 0.f ? v : 0.f;
          o[(size_t)(nbase + r) * 256 + co] = f2bf(v);
        }
      } else if constexpr (EPI == 1){
        float sc = p.ep_scale[co], sh = p.ep_shift[co];
        float* o = (float*)p.out;
        int b = nbase / 7744; int s = nbase - b * 7744;
        float4 v;
        v.x = fmaxf(fmaf(a[0], sc, sh), 0.f);
        v.y = fmaxf(fmaf(a[1], sc, sh), 0.f);
        v.z = fmaxf(fmaf(a[2], sc, sh), 0.f);
        v.w = fmaxf(fmaf(a[3], sc, sh), 0.f);
        *reinterpret_cast<float4*>(o + ((size_t)(b * 256 + co)) * 7744 + s) = v;
      } else {
        float* o = (float*)p.out + (size_t)slot * 968 * 256;
        #pragma unroll
        for (int r = 0; r < 4; ++r){
          int n = nbase + r;
          if (n < p.Mtot) o[(size_t)n * 256 + co] = a[r];
        }
      }
    }
  }
}

// ---------------------------------------------------------------- spatial mask
__global__ __launch_bounds__(256)
void mask_k(const unsigned short* __restrict__ h1, const float* __restrict__ w2,
            const float* __restrict__ b2, float* __restrict__ mask,
            unsigned short* __restrict__ FusPad)
{
  __shared__ float w[256];
  int t = threadIdx.x;
  w[t] = w2[t];
  __syncthreads();
  int n = blockIdx.x * 256 + t;
  const unsigned short* row = h1 + (size_t)n * 256;
  float s = b2[0];
  for (int c = 0; c < 256; c += 8){
    union { uint4 v; unsigned short s_[8]; } u;
    u.v = *reinterpret_cast<const uint4*>(row + c);
    #pragma unroll
    for (int j = 0; j < 8; ++j) s = fmaf(bf2f(u.s_[j]), w[c + j], s);
  }
  float m = 1.f / (1.f + __expf(-s));
  mask[n] = m;
  int b = n / 7744, sr = n - b * 7744;
  int y = sr / 88, x = sr - y * 88;
  FusPad[(((size_t)b * 90 + y + 1) * 90 + (x + 1)) * 576 + 512] = f2bf(m);
}

// ---------------------------------------------------------------- f_depth * mask -> NHWC bf16
__global__ __launch_bounds__(256)
void fdm_k(const unsigned short* __restrict__ Xpad, const float* __restrict__ mask,
           unsigned short* __restrict__ fdm)
{
  int idx = blockIdx.x * 256 + threadIdx.x;
  int n = idx >> 5, cb = idx & 31;
  int b = n / 7744, s = n - b * 7744;
  int y = s / 88, x = s - y * 88;
  size_t pix = ((size_t)(b * 90 + y + 1)) * 90 + x + 1;
  union { uint4 v; unsigned short s_[8]; } u, w;
  u.v = *reinterpret_cast<const uint4*>(Xpad + pix * 512 + 256 + cb * 8);
  float m = mask[n];
  #pragma unroll
  for (int j = 0; j < 8; ++j) w.s_[j] = f2bf(bf2f(u.s_[j]) * m);
  *reinterpret_cast<uint4*>(fdm + (size_t)n * 256 + cb * 8) = w.v;
}

// ---------------------------------------------------------------- split-K sum + channel LN
__global__ __launch_bounds__(256)
void lnkvr_k(const float* __restrict__ part, const float* __restrict__ srb,
             const float* __restrict__ lng, const float* __restrict__ lnb,
             unsigned short* __restrict__ kvr)
{
  int n = blockIdx.x, t = threadIdx.x;
  float v = srb[t];
  for (int s = 0; s < 16; ++s) v += part[((size_t)s * 968 + n) * 256 + t];
  float s1 = v, s2 = v * v;
  #pragma unroll
  for (int o = 1; o < 64; o <<= 1){ s1 += __shfl_xor(s1, o, 64); s2 += __shfl_xor(s2, o, 64); }
  __shared__ float a1[4], a2[4];
  if ((t & 63) == 0){ a1[t >> 6] = s1; a2[t >> 6] = s2; }
  __syncthreads();
  float t1 = a1[0] + a1[1] + a1[2] + a1[3];
  float t2 = a2[0] + a2[1] + a2[2] + a2[3];
  float mean = t1 * (1.f / 256.f);
  float var = t2 * (1.f / 256.f) - mean * mean;
  float rstd = rsqrtf(var + 1e-5f);
  kvr[(size_t)n * 256 + t] = f2bf((v - mean) * rstd * lng[t] + lnb[t]);
}

// ---------------------------------------------------------------- 1x1 conv 256->32 (K only now)
__global__ __launch_bounds__(256)
void dotconv_k(const unsigned short* __restrict__ src,
               const unsigned short* __restrict__ wt, const float* __restrict__ bias,
               float* __restrict__ out)
{
  __shared__ unsigned short wl[256 * 32];
  const int t = threadIdx.x;
  {
    uint4* d = (uint4*)wl; const uint4* s = (const uint4*)wt;
    #pragma unroll
    for (int k = 0; k < 4; ++k) d[t + 256 * k] = s[t + 256 * k];
  }
  __syncthreads();
  const int n = blockIdx.x * 8 + (t >> 5);
  const int co = t & 31;
  const unsigned short* row = src + (size_t)n * 256;
  float sum = bias[co];
  for (int c = 0; c < 256; c += 8){
    union { uint4 v; unsigned short s_[8]; } u;
    u.v = *reinterpret_cast<const uint4*>(row + c);
    #pragma unroll
    for (int j = 0; j < 8; ++j)
      sum = fmaf(bf2f(u.s_[j]), bf2f(wl[(c + j) * 32 + co]), sum);
  }
  out[(size_t)n * 32 + co] = sum;
}

// ---------------------------------------------------------------- 1x1 conv 256->256 (V) -> VBt[b][c][128m] bf16
__global__ __launch_bounds__(256)
void vconv_k(const unsigned short* __restrict__ kvr, const unsigned short* __restrict__ vwt,
             const float* __restrict__ vb, unsigned short* __restrict__ VBt)
{
  __shared__ float rowf[256];
  const int n = blockIdx.x, t = threadIdx.x;
  rowf[t] = bf2f(kvr[(size_t)n * 256 + t]);
  __syncthreads();
  float sum = vb[t];
  #pragma unroll 8
  for (int c = 0; c < 256; ++c)
    sum = fmaf(rowf[c], bf2f(vwt[(size_t)c * 256 + t]), sum);
  int b = n / 121, m = n - b * 121;
  VBt[(size_t)b * 32768 + (size_t)t * 128 + m] = f2bf(sum);
}

// ---------------------------------------------------------------- MFMA attention (+fused Q-proj) + LN + residual
// 512 threads = 8 waves; 128 query rows/block (wave w owns rows 16w..16w+15).
// Q = X . Wq^T computed in-kernel (MFMA, X from global bf16, Wq in LDS).
__global__ __launch_bounds__(512, 2)
void attn_k(const unsigned short* __restrict__ Qsrc, int qmode,
            const unsigned short* __restrict__ wq, const float* __restrict__ qb,
            const float* __restrict__ Kbuf,
            const unsigned short* __restrict__ VBt,
            const unsigned short* __restrict__ Xpad, int resChOff,
            unsigned short* __restrict__ FusPad, int outChOff,
            const float* __restrict__ ng, const float* __restrict__ nbv,
            const float* __restrict__ gammap)
{
  __shared__ unsigned short Vt[2][256][64];   // 64 KB
  __shared__ unsigned short Pl[2][128][64];   // 32 KB
  __shared__ unsigned short Qs[128][64];      // 16 KB
  __shared__ unsigned short Ks[128][64];      // 16 KB
  __shared__ unsigned short Wqs[32][256];     // 16 KB (pre-swizzled)

  const int t = threadIdx.x;
  const int lane = t & 63;
  const int w = t >> 6;
  const int c15 = lane & 15;
  const int h = lane >> 4;

  const int bid = blockIdx.x;
  const int b = bid / 61;
  const int rb = bid - b * 61;
  const int nb0 = rb * 128;

  // ---- stage Vt via global_load_lds ----
  const unsigned short* vsrc = VBt + (size_t)b * 32768;
  #pragma unroll
  for (int kt = 0; kt < 2; ++kt)
    #pragma unroll
    for (int i = 0; i < 4; ++i){
      int rowbase = i * 64 + w * 8;
      int c = rowbase + (lane >> 3);
      int mchunk = (lane & 7) ^ (c & 7);
      __builtin_amdgcn_global_load_lds(
        (AS1 void*)(vsrc + (size_t)c * 128 + kt * 64 + mchunk * 8),
        (AS3 void*)(&Vt[kt][rowbase][0]),
        16, 0, 0);
    }

  // ---- stage Wqs (linear copy of pre-swizzled weights) ----
  {
    uint4* d = (uint4*)&Wqs[0][0]; const uint4* s = (const uint4*)wq;
    d[t] = s[t];                     // 512*16B = 8KB
    d[t + 512] = s[t + 512];         // +8KB
  }
  // ---- stage Ks (rows m>=121 zeroed) ----
  {
    int m = t >> 2, part = t & 3;
    union { uint4 v; unsigned short s_[8]; } u;
    u.v = uint4{0, 0, 0, 0};
    if (m < 121){
      const float* kp = Kbuf + ((size_t)b * 121 + m) * 32 + part * 8;
      float4 a = *reinterpret_cast<const float4*>(kp);
      float4 bb = *reinterpret_cast<const float4*>(kp + 4);
      u.s_[0] = f2bf(a.x); u.s_[1] = f2bf(a.y); u.s_[2] = f2bf(a.z); u.s_[3] = f2bf(a.w);
      u.s_[4] = f2bf(bb.x); u.s_[5] = f2bf(bb.y); u.s_[6] = f2bf(bb.z); u.s_[7] = f2bf(bb.w);
    }
    *reinterpret_cast<uint4*>(&Ks[m][(part ^ (m & 7)) * 8]) = u.v;
  }
  __syncthreads();   // Vt (vmcnt drained), Wqs, Ks all valid

  const int nA = w * 16 + c15;
  const float scale = 0.17677669529663687f;  // 32^-0.5

  // ---- fused Q-projection: Q[n][co] = sum_ci X[n][ci]*Wq[co][ci] ----
  {
    int gn = nb0 + nA; if (gn > 7743) gn = 7743;
    const unsigned short* xrow;
    if (qmode){
      int y = gn / 88, x = gn - y * 88;
      xrow = Qsrc + (((size_t)(b * 90) + y + 1) * 90 + (x + 1)) * 512;
    } else {
      xrow = Qsrc + ((size_t)b * 7744 + gn) * 256;
    }
    f32x4 qacc[2];
    qacc[0] = f32x4{0.f, 0.f, 0.f, 0.f};
    qacc[1] = f32x4{0.f, 0.f, 0.f, 0.f};
    #pragma unroll
    for (int kt = 0; kt < 8; ++kt){
      bf16x8 ax = *reinterpret_cast<const bf16x8*>(xrow + kt * 32 + h * 8);
      #pragma unroll
      for (int ni = 0; ni < 2; ++ni){
        int co = ni * 16 + c15;
        bf16x8 bw = *reinterpret_cast<const bf16x8*>(&Wqs[co][((kt * 4 + h) ^ (co & 7)) * 8]);
        qacc[ni] = __builtin_amdgcn_mfma_f32_16x16x32_bf16(ax, bw, qacc[ni], 0, 0, 0);
      }
    }
    // write Q (bias + scale) to Qs — wave-private rows, no barrier needed
    #pragma unroll
    for (int ni = 0; ni < 2; ++ni){
      int co = ni * 16 + c15;
      float bq = qb[co];
      #pragma unroll
      for (int r = 0; r < 4; ++r){
        int n = w * 16 + 4 * h + r;
        int chunk = (co >> 3) ^ (n & 7);
        Qs[n][chunk * 8 + (co & 7)] = f2bf((qacc[ni][r] + bq) * scale);
      }
    }
  }

  // ---- QK^T ----
  bf16x8 aq = *reinterpret_cast<const bf16x8*>(&Qs[nA][(h ^ (nA & 7)) * 8]);
  f32x4 sv[8];
  #pragma unroll
  for (int ni = 0; ni < 8; ++ni){
    int mrow = ni * 16 + c15;
    bf16x8 bk = *reinterpret_cast<const bf16x8*>(&Ks[mrow][(h ^ (mrow & 7)) * 8]);
    sv[ni] = __builtin_amdgcn_mfma_f32_16x16x32_bf16(aq, bk, f32x4{0.f,0.f,0.f,0.f}, 0, 0, 0);
  }
  if (c15 >= 9) sv[7] = f32x4{-1e30f, -1e30f, -1e30f, -1e30f};

  float rden[4];
  #pragma unroll
  for (int r = 0; r < 4; ++r){
    float mx = sv[0][r];
    #pragma unroll
    for (int ni = 1; ni < 8; ++ni) mx = fmaxf(mx, sv[ni][r]);
    #pragma unroll
    for (int o = 1; o < 16; o <<= 1) mx = fmaxf(mx, __shfl_xor(mx, o, 64));
    float sm = 0.f;
    #pragma unroll
    for (int ni = 0; ni < 8; ++ni){
      float p = __expf(sv[ni][r] - mx);
      sv[ni][r] = p;
      sm += p;
    }
    #pragma unroll
    for (int o = 1; o < 16; o <<= 1) sm += __shfl_xor(sm, o, 64);
    rden[r] = 1.f / sm;
  }
  #pragma unroll
  for (int ni = 0; ni < 8; ++ni){
    int m = ni * 16 + c15;
    int kt = m >> 6;
    int mq = (m & 63) >> 3;
    #pragma unroll
    for (int r = 0; r < 4; ++r){
      int n = w * 16 + 4 * h + r;
      Pl[kt][n][(mq ^ (n & 7)) * 8 + (m & 7)] = f2bf(sv[ni][r] * rden[r]);
    }
  }

  bf16x8 pa[2][2];
  #pragma unroll
  for (int kt = 0; kt < 2; ++kt)
    #pragma unroll
    for (int ks = 0; ks < 2; ++ks)
      pa[kt][ks] = *reinterpret_cast<const bf16x8*>(&Pl[kt][nA][((ks * 4 + h) ^ (nA & 7)) * 8]);

  f32x4 acc[16];
  #pragma unroll
  for (int ni = 0; ni < 16; ++ni) acc[ni] = f32x4{0.f, 0.f, 0.f, 0.f};
  #pragma unroll
  for (int ni = 0; ni < 16; ++ni){
    int crow = ni * 16 + c15;
    #pragma unroll
    for (int kt = 0; kt < 2; ++kt)
      #pragma unroll
      for (int ks = 0; ks < 2; ++ks){
        bf16x8 bv = *reinterpret_cast<const bf16x8*>(&Vt[kt][crow][((ks * 4 + h) ^ (crow & 7)) * 8]);
        acc[ni] = __builtin_amdgcn_mfma_f32_16x16x32_bf16(pa[kt][ks], bv, acc[ni], 0, 0, 0);
      }
  }

  float ngv[16], nbb[16];
  #pragma unroll
  for (int ni = 0; ni < 16; ++ni){
    int c = ni * 16 + c15;
    ngv[ni] = ng[c]; nbb[ni] = nbv[c];
  }
  float g = gammap[0]; g = fminf(fmaxf(g, 0.f), 1.f);

  #pragma unroll
  for (int r = 0; r < 4; ++r){
    float s1 = 0.f, s2 = 0.f;
    #pragma unroll
    for (int ni = 0; ni < 16; ++ni){ float v = acc[ni][r]; s1 += v; s2 += v * v; }
    #pragma unroll
    for (int o = 1; o < 16; o <<= 1){ s1 += __shfl_xor(s1, o, 64); s2 += __shfl_xor(s2, o, 64); }
    float mean = s1 * (1.f / 256.f);
    float var = s2 * (1.f / 256.f) - mean * mean;
    float rstd = rsqrtf(var + 1e-5f);

    int nloc = w * 16 + 4 * h + r;
    int rix = nb0 + nloc;
    if (rix < 7744){
      int y = rix / 88, x = rix - y * 88;
      size_t pix = ((size_t)(b * 90) + y + 1) * 90 + (x + 1);
      const unsigned short* res = Xpad + pix * 512 + resChOff;
      unsigned short* outp = FusPad + pix * 576 + outChOff;
      #pragma unroll
      for (int ni = 0; ni < 16; ++ni){
        int c = ni * 16 + c15;
        float yv = (acc[ni][r] - mean) * rstd * ngv[ni] + nbb[ni];
        outp[c] = f2bf(bf2f(res[c]) + g * yv);
      }
    }
  }
}

// ================================================================ host
extern "C" void kernel_launch(void* const* d_in, const int* in_sizes, int n_in,
                              void* d_out, int out_size, void* d_ws, size_t ws_size,
                              hipStream_t stream)
{
  const float* P[42];
  for (int i = 0; i < 42; ++i) P[i] = (const float*)d_in[i];

  char* ws = (char*)d_ws;
  size_t off = 0;
  auto take = [&](size_t bytes) -> char* {
    char* p = ws + off; off += (bytes + 255) & ~(size_t)255; return p;
  };
  unsigned short* XPAD = (unsigned short*)take(8ull * 8100 * 512 * 2);   // 66.4 MB
  unsigned short* FUSP = (unsigned short*)take(8ull * 8100 * 576 * 2);   // 74.6 MB
  unsigned short* H1   = (unsigned short*)take(61952ull * 256 * 2);      // 31.7 MB
  unsigned short* FDM  = H1;  // alias: h1 dead after mask_k
  unsigned short* W1T  = (unsigned short*)take(9ull * 256 * 512 * 2);
  unsigned short* WFT  = (unsigned short*)take(9ull * 256 * 576 * 2);
  unsigned short* WSRA = (unsigned short*)take(64ull * 256 * 256 * 2);
  unsigned short* WSRB = (unsigned short*)take(64ull * 256 * 256 * 2);
  float* PART = (float*)take(16ull * 968 * 256 * 4);                      // 15.9 MB
  unsigned short* KVR = (unsigned short*)take(968ull * 256 * 2);
  float* KB   = (float*)take(968ull * 32 * 4);
  unsigned short* VBT = (unsigned short*)take(8ull * 256 * 128 * 2);      // 512 KB
  float* MASK = (float*)take(61952ull * 4);
  float* SC1 = (float*)take(256 * 4);
  float* SH1 = (float*)take(256 * 4);
  float* SCF = (float*)take(256 * 4);
  float* SHF = (float*)take(256 * 4);
  unsigned short* WQSA = (unsigned short*)take(32ull * 256 * 2);
  unsigned short* WQSB = (unsigned short*)take(32ull * 256 * 2);
  unsigned short* KWTA = (unsigned short*)take(256ull * 32 * 2);
  unsigned short* VWTA = (unsigned short*)take(256ull * 256 * 2);
  unsigned short* KWTB = (unsigned short*)take(256ull * 32 * 2);
  unsigned short* VWTB = (unsigned short*)take(256ull * 256 * 2);
  (void)ws_size; (void)in_sizes; (void)n_in; (void)out_size;

  // targeted zeroing (replaces 141MB of memsets)
  zero_border_k<<<8 * 356, 128, 0, stream>>>(XPAD, 512);
  zero_border_k<<<8 * 356, 128, 0, stream>>>(FUSP, 576);
  zero_fustail_k<<<1936, 256, 0, stream>>>(FUSP);
  hipMemsetAsync(VBT, 0, 8ull * 256 * 128 * 2, stream);

  bnprep_k<<<1, 256, 0, stream>>>(P[4], P[5], P[6], P[7], P[3],
                                  P[38], P[39], P[40], P[41], P[37],
                                  SC1, SH1, SCF, SHF);
  prep_xpad_k<<<7744, 256, 0, stream>>>(P[0], P[1], XPAD);
  prep_w1t_k<<<256, 256, 0, stream>>>(P[2], W1T);
  prep_wfus_k<<<256, 256, 0, stream>>>(P[36], WFT);
  prep_wsr_k<<<256, 256, 0, stream>>>(P[16], WSRA);
  prep_wsr_k<<<256, 256, 0, stream>>>(P[28], WSRB);
  wqprep_k<<<32, 256, 0, stream>>>(P[10], WQSA);
  wqprep_k<<<32, 256, 0, stream>>>(P[22], WQSB);
  tranw_k<<<8, 256, 0, stream>>>(P[12], KWTA, 32, 256);
  tranw_k<<<64, 256, 0, stream>>>(P[14], VWTA, 256, 256);
  tranw_k<<<8, 256, 0, stream>>>(P[24], KWTB, 32, 256);
  tranw_k<<<64, 256, 0, stream>>>(P[26], VWTB, 256, 256);

  // conv1 3x3 (512->256) + BN + ReLU -> h1 NHWC bf16
  GemmP g1{};
  g1.A = XPAD; g1.W = W1T; g1.ep_scale = SC1; g1.ep_shift = SH1; g1.out = H1;
  g1.img_px = 8100; g1.row_px = 90; g1.px_el = 512; g1.ch_off = 0; g1.y0 = 0; g1.x0 = 0;
  g1.tapw = 3; g1.stridepix = 1; g1.out_w = 88; g1.out_imgpx = 7744;
  g1.Cin = 512; g1.Mtot = 61952; g1.Mtiles = 484; g1.Ntiles = 2; g1.k_per = 4608;
  gemm_k<0><<<968, 256, 0, stream>>>(g1);

  mask_k<<<242, 256, 0, stream>>>(H1, P[8], P[9], MASK, FUSP);
  fdm_k<<<7744, 256, 0, stream>>>(XPAD, MASK, FDM);

  // ---------------- d2r: Q from f_rgb (XPAD rgb), KV from f_depth_masked ----------------
  GemmP gs{};
  gs.A = FDM; gs.W = WSRA; gs.out = PART;
  gs.img_px = 7744; gs.row_px = 88; gs.px_el = 256; gs.ch_off = 0; gs.y0 = 0; gs.x0 = 0;
  gs.tapw = 8; gs.stridepix = 8; gs.out_w = 11; gs.out_imgpx = 121;
  gs.Cin = 256; gs.Mtot = 968; gs.Mtiles = 8; gs.Ntiles = 2; gs.k_per = 1024;
  gemm_k<2><<<256, 256, 0, stream>>>(gs);
  lnkvr_k<<<968, 256, 0, stream>>>(PART, P[17], P[18], P[19], KVR);
  dotconv_k<<<121, 256, 0, stream>>>(KVR, KWTA, P[13], KB);
  vconv_k<<<968, 256, 0, stream>>>(KVR, VWTA, P[15], VBT);
  attn_k<<<488, 512, 0, stream>>>(XPAD, 1, WQSA, P[11], KB, VBT, XPAD, 0,
                                  FUSP, 0, P[20], P[21], P[34]);

  // ---------------- r2d: Q from f_depth_masked (FDM), KV from f_rgb ----------------
  gs.A = XPAD; gs.W = WSRB;
  gs.img_px = 8100; gs.row_px = 90; gs.px_el = 512; gs.y0 = 1; gs.x0 = 1;
  gemm_k<2><<<256, 256, 0, stream>>>(gs);
  lnkvr_k<<<968, 256, 0, stream>>>(PART, P[29], P[30], P[31], KVR);
  dotconv_k<<<121, 256, 0, stream>>>(KVR, KWTB, P[25], KB);
  vconv_k<<<968, 256, 0, stream>>>(KVR, VWTB, P[27], VBT);
  attn_k<<<488, 512, 0, stream>>>(FDM, 0, WQSB, P[23], KB, VBT, XPAD, 256,
                                  FUSP, 256, P[32], P[33], P[35]);

  // final fused conv 3x3 (576->256) + BN + ReLU -> d_out f32 NCHW
  GemmP gf{};
  gf.A = FUSP; gf.W = WFT; gf.ep_scale = SCF; gf.ep_shift = SHF; gf.out = d_out;
  gf.img_px = 8100; gf.row_px = 90; gf.px_el = 576; gf.ch_off = 0; gf.y0 = 0; gf.x0 = 0;
  gf.tapw = 3; gf.stridepix = 1; gf.out_w = 88; gf.out_imgpx = 7744;
  gf.Cin = 576; gf.Mtot = 61952; gf.Mtiles = 484; gf.Ntiles = 2; gf.k_per = 5184;
  gemm_k<1><<<968, 256, 0, stream>>>(gf);
}

// Round 8
// 599.214 us; speedup vs baseline: 4.3179x; 1.0264x over previous
//
#include <hip/hip_runtime.h>
#include <hip/hip_bf16.h>

// BiDirectionalFusionModule on MI355X.
// All heavy convs = implicit GEMM, bf16 MFMA 16x16x32, f32 accumulate.
// Activations staged as zero-padded NHWC bf16. ~220MB workspace.
// R2: global_load_lds(16B) GEMM staging; coalesced weight preps.
// R3: fixed dotconv weight staging.
// R5: MFMA attention (8 waves, wave-local softmax/LN, swizzled LDS, V via lds-DMA).
// R6: GEMM L2-locality (cib-outer/tap-inner, nt-inner, XCD chunk swizzle): FETCH 574->60MB.
// R7: Q-proj fused into attn_k; targeted border/tail zeroing.
// R8: GEMM 2-phase pipeline — double-buffered LDS, STAGE(kt+1) issued before
//     compute(kt), counted s_waitcnt vmcnt(8) + raw s_barrier (no vmcnt(0) drain).

typedef __bf16 bf16x8 __attribute__((ext_vector_type(8)));
typedef float f32x4 __attribute__((ext_vector_type(4)));

#define AS1 __attribute__((address_space(1)))
#define AS3 __attribute__((address_space(3)))
#define DEVI __device__ __forceinline__

DEVI float bf2f(unsigned short u){
  union { unsigned int i; float f; } v; v.i = ((unsigned int)u) << 16; return v.f;
}
DEVI unsigned short f2bf(float f){
  union { float f; unsigned int i; } v; v.f = f;
  unsigned int x = v.i;
  unsigned int r = (x + 0x7fffu + ((x >> 16) & 1u)) >> 16;
  return (unsigned short)r;
}

// ---------------------------------------------------------------- BN prep
__global__ void bnprep_k(const float* __restrict__ g1, const float* __restrict__ be1,
                         const float* __restrict__ m1, const float* __restrict__ v1,
                         const float* __restrict__ b1,
                         const float* __restrict__ gf, const float* __restrict__ bef,
                         const float* __restrict__ mf, const float* __restrict__ vf,
                         const float* __restrict__ bf,
                         float* __restrict__ sc1, float* __restrict__ sh1,
                         float* __restrict__ scf, float* __restrict__ shf)
{
  int c = threadIdx.x;
  float s = g1[c] * rsqrtf(v1[c] + 1e-5f);
  sc1[c] = s; sh1[c] = (b1[c] - m1[c]) * s + be1[c];
  s = gf[c] * rsqrtf(vf[c] + 1e-5f);
  scf[c] = s; shf[c] = (bf[c] - mf[c]) * s + bef[c];
}

// ---------------------------------------------------------------- targeted zeroing
__global__ __launch_bounds__(128)
void zero_border_k(unsigned short* __restrict__ buf, int px_el)
{
  int bi = blockIdx.x;
  int img = bi / 356, e = bi - img * 356;
  int y, x;
  if (e < 90){ y = 0; x = e; }
  else if (e < 180){ y = 89; x = e - 90; }
  else if (e < 268){ y = e - 180 + 1; x = 0; }
  else { y = e - 268 + 1; x = 89; }
  size_t pix = ((size_t)img * 90 + y) * 90 + x;
  int t = threadIdx.x;
  if (t < (px_el >> 3))
    *reinterpret_cast<uint4*>(buf + pix * px_el + t * 8) = uint4{0, 0, 0, 0};
}
__global__ __launch_bounds__(256)
void zero_fustail_k(unsigned short* __restrict__ FusPad)
{
  int idx = blockIdx.x * 256 + threadIdx.x;   // 61952*8
  int n = idx >> 3, ch = idx & 7;
  int b = n / 7744, s = n - b * 7744;
  int y = s / 88, x = s - y * 88;
  size_t pix = ((size_t)(b * 90 + y + 1)) * 90 + (x + 1);
  *reinterpret_cast<uint4*>(FusPad + pix * 576 + 512 + ch * 8) = uint4{0, 0, 0, 0};
}

// ------------------------------------------------- NCHW f32 -> padded NHWC bf16
__global__ __launch_bounds__(256)
void prep_xpad_k(const float* __restrict__ rgb, const float* __restrict__ dep,
                 unsigned short* __restrict__ Xpad)
{
  __shared__ unsigned short tile[64][65];
  int bi = blockIdx.x;
  int b = bi / 968;
  int rem = bi - b * 968;
  int cblk = rem / 121;
  int pblk = rem - cblk * 121;
  int t = threadIdx.x;
  int pl = t & 63;
  #pragma unroll
  for (int pass = 0; pass < 16; ++pass){
    int cl = pass * 4 + (t >> 6);
    int c = cblk * 64 + cl;
    const float* sp = (c < 256) ? (rgb + ((size_t)b * 256 + c) * 7744)
                                : (dep + ((size_t)b * 256 + (c - 256)) * 7744);
    tile[cl][pl] = f2bf(sp[pblk * 64 + pl]);
  }
  __syncthreads();
  int cl2 = t & 63;
  for (int pass = 0; pass < 16; ++pass){
    int pl2 = pass * 4 + (t >> 6);
    int pixg = pblk * 64 + pl2;
    int y = pixg / 88, x = pixg - y * 88;
    Xpad[(((size_t)b * 90 + y + 1) * 90 + (x + 1)) * 512 + cblk * 64 + cl2] = tile[cl2][pl2];
  }
}

// ---------------------------------------------------------------- weight reshuffles
__global__ __launch_bounds__(256)
void prep_w1t_k(const float* __restrict__ w, unsigned short* __restrict__ o)
{
  int co = blockIdx.x, t = threadIdx.x;
  const float* src = w + (size_t)co * 4608 + t * 18;
  unsigned int* op = (unsigned int*)o;
  #pragma unroll
  for (int k = 0; k < 9; ++k){
    unsigned short lo = f2bf(src[k]);
    unsigned short hi = f2bf(src[9 + k]);
    op[((size_t)k * 256 + co) * 256 + t] = lo | ((unsigned int)hi << 16);
  }
}
__global__ __launch_bounds__(256)
void prep_wfus_k(const float* __restrict__ w, unsigned short* __restrict__ o)
{
  int co = blockIdx.x, t = threadIdx.x;
  const float* src = w + (size_t)co * 4617 + t * 18;
  unsigned int* op = (unsigned int*)o;
  #pragma unroll
  for (int k = 0; k < 9; ++k){
    unsigned short lo = f2bf(src[k]);
    unsigned short hi = f2bf(src[9 + k]);
    op[((size_t)k * 256 + co) * 288 + t] = lo | ((unsigned int)hi << 16);
  }
  if (t < 32){
    #pragma unroll
    for (int k = 0; k < 9; ++k){
      unsigned int val = 0;
      if (t == 0) val = (unsigned int)f2bf(w[(size_t)co * 4617 + 512 * 9 + k]);
      op[((size_t)k * 256 + co) * 288 + 256 + t] = val;
    }
  }
}
__global__ __launch_bounds__(256)
void prep_wsr_k(const float* __restrict__ w, unsigned short* __restrict__ o)
{
  __shared__ float ld[64][65];
  int co = blockIdx.x;
  int t = threadIdx.x;
  for (int cib = 0; cib < 256; cib += 64){
    int cil = t >> 2, tq = t & 3;
    const float* src = w + ((size_t)co * 256 + cib + cil) * 64 + tq * 16;
    float v[16];
    #pragma unroll
    for (int k = 0; k < 16; ++k) v[k] = src[k];
    __syncthreads();
    #pragma unroll
    for (int k = 0; k < 16; ++k) ld[cil][tq * 16 + k] = v[k];
    __syncthreads();
    #pragma unroll
    for (int tp = 0; tp < 16; ++tp){
      int tap = tp * 4 + (t >> 6);
      int ci = t & 63;
      o[((size_t)tap * 256 + co) * 256 + cib + ci] = f2bf(ld[ci][tap]);
    }
  }
}
__global__ __launch_bounds__(256)
void tranw_k(const float* __restrict__ in, unsigned short* __restrict__ out, int R, int C)
{
  __shared__ float tl[32][33];
  int tiles_c = C >> 5;
  int tr = (blockIdx.x / tiles_c) << 5, tc = (blockIdx.x % tiles_c) << 5;
  int t = threadIdx.x; int r = t >> 5, c = t & 31;
  #pragma unroll
  for (int p = 0; p < 4; ++p)
    tl[r + p * 8][c] = in[(size_t)(tr + r + p * 8) * C + tc + c];
  __syncthreads();
  #pragma unroll
  for (int p = 0; p < 4; ++p)
    out[(size_t)(tc + r + p * 8) * R + tr + c] = f2bf(tl[c][r + p * 8]);
}
// Wq (32,256) f32 -> bf16 [32][256] with chunk XOR swizzle pre-applied
__global__ __launch_bounds__(256)
void wqprep_k(const float* __restrict__ w, unsigned short* __restrict__ o)
{
  int co = blockIdx.x, t = threadIdx.x;
  int c = t >> 3, e = t & 7;
  o[co * 256 + ((c ^ (co & 7)) * 8) + e] = f2bf(w[co * 256 + t]);
}

// ---------------------------------------------------------------- implicit GEMM
struct GemmP {
  const unsigned short* A;
  const unsigned short* W;
  const float* ep_scale;
  const float* ep_shift;
  void* out;
  int img_px, row_px, px_el, ch_off, y0, x0;
  int tapw, stridepix, out_w, out_imgpx;
  int Cin, Mtot, Mtiles, Ntiles, k_per;
};

template<int EPI>
__global__ __launch_bounds__(256)
void gemm_k(GemmP p)
{
  __shared__ __bf16 As[2][128 * 64];
  __shared__ __bf16 Bs[2][128 * 64];
  const int t = threadIdx.x;
  const int lane = t & 63;
  const int wid = t >> 6;
  const int wr = wid >> 1, wc = wid & 1;

  const int cpx = gridDim.x >> 3;
  int pid = (blockIdx.x & 7) * cpx + (blockIdx.x >> 3);
  const int mn = p.Mtiles * p.Ntiles;
  int within = pid % mn;
  int slot = pid / mn;
  int mt = within / p.Ntiles;
  int nt = within - mt * p.Ntiles;
  int kb = slot * p.k_per;
  int tap0 = kb / p.Cin;
  int ntap = p.k_per / p.Cin;

  long long apix[4]; int cbg8[4]; int wrow[4];
  #pragma unroll
  for (int i = 0; i < 4; ++i){
    int r = i * 32 + (t >> 3);
    cbg8[i] = ((t & 7) ^ (r & 7)) * 8;
    int n = mt * 128 + r;
    int nc = n < p.Mtot ? n : 0;
    int b = nc / p.out_imgpx; int rr = nc - b * p.out_imgpx;
    int yo = rr / p.out_w;    int xo = rr - yo * p.out_w;
    apix[i] = (long long)b * p.img_px + (long long)(yo * p.stridepix + p.y0) * p.row_px
            + (xo * p.stridepix + p.x0);
    wrow[i] = (nt * 128 + r) * p.Cin + cbg8[i];
  }

  f32x4 acc[4][4];
  #pragma unroll
  for (int i = 0; i < 4; ++i)
    #pragma unroll
    for (int j = 0; j < 4; ++j)
      acc[i][j] = f32x4{0.f, 0.f, 0.f, 0.f};

  const long long wstap = 256LL * p.Cin;

  // stage K-step (tap, cib) into buffer buf
  auto STAGE = [&](int buf, int tap, int cib){
    int dy = tap / p.tapw, dx = tap - dy * p.tapw;
    const unsigned short* wb = p.W + (long long)tap * wstap + cib;
    const long long aoff = (long long)(dy * p.row_px + dx) * p.px_el + p.ch_off + cib;
    #pragma unroll
    for (int i = 0; i < 4; ++i){
      __builtin_amdgcn_global_load_lds(
          (AS1 void*)(p.A + apix[i] * p.px_el + aoff + cbg8[i]),
          (AS3 void*)(&As[buf][i * 2048 + wid * 512]),
          16, 0, 0);
      __builtin_amdgcn_global_load_lds(
          (AS1 void*)(wb + wrow[i]),
          (AS3 void*)(&Bs[buf][i * 2048 + wid * 512]),
          16, 0, 0);
    }
  };

  const int NT = (p.Cin >> 6) * ntap;   // cib-outer, tap-inner order
  // prologue: stage kt=0
  STAGE(0, tap0, 0);
  // next-step coordinates (kt=1)
  int tpn = 1, tap_n = tap0 + 1, cib_n = 0;
  int cur = 0;

  for (int kt = 0; kt < NT; ++kt){
    if (kt + 1 < NT){
      STAGE(cur ^ 1, tap_n, cib_n);
      // advance next coords
      ++tpn; ++tap_n;
      if (tpn == ntap){ tpn = 0; tap_n = tap0; cib_n += 64; }
      asm volatile("s_waitcnt vmcnt(8)" ::: "memory");   // kt's 8 loads landed; kt+1's in flight
    } else {
      asm volatile("s_waitcnt vmcnt(0)" ::: "memory");   // final tile: full drain
    }
    __builtin_amdgcn_s_barrier();
    __builtin_amdgcn_sched_barrier(0);

    #pragma unroll
    for (int ks = 0; ks < 2; ++ks){
      bf16x8 av[4], bv[4];
      #pragma unroll
      for (int mi = 0; mi < 4; ++mi){
        int ar = wr * 64 + mi * 16 + (lane & 15);
        int cb = (ks * 4 + (lane >> 4)) ^ (ar & 7);
        av[mi] = *reinterpret_cast<const bf16x8*>(&As[cur][ar * 64 + cb * 8]);
      }
      #pragma unroll
      for (int ni = 0; ni < 4; ++ni){
        int br = wc * 64 + ni * 16 + (lane & 15);
        int cb = (ks * 4 + (lane >> 4)) ^ (br & 7);
        bv[ni] = *reinterpret_cast<const bf16x8*>(&Bs[cur][br * 64 + cb * 8]);
      }
      #pragma unroll
      for (int mi = 0; mi < 4; ++mi)
        #pragma unroll
        for (int ni = 0; ni < 4; ++ni)
          acc[mi][ni] = __builtin_amdgcn_mfma_f32_16x16x32_bf16(av[mi], bv[ni], acc[mi][ni], 0, 0, 0);
    }

    __builtin_amdgcn_sched_barrier(0);
    __builtin_amdgcn_s_barrier();      // all waves done reading buf[cur]; safe to overwrite next iter
    cur ^= 1;
  }

  const int r0 = (lane >> 4) * 4;
  const int c0 = lane & 15;
  #pragma unroll
  for (int mi = 0; mi < 4; ++mi){
    int nbase = mt * 128 + wr * 64 + mi * 16 + r0;
    #pragma unroll
    for (int ni = 0; ni < 4; ++ni){
      int co = nt * 128 + wc * 64 + ni * 16 + c0;
      f32x4 a = acc[mi][ni];
      if constexpr (EPI == 0){
        float sc = p.ep_scale[co], sh = p.ep_shift[co];
        unsigned short* o = (unsigned short*)p.out;
        #pragma unroll
        for (int r = 0; r < 4; ++r){
          float v = fmaf(a[r], sc, sh); v = v > 0.f ? v : 0.f;
          o[(size_t)(nbase + r) * 256 + co] = f2bf(v);
        }
      } else if constexpr (EPI == 1){
        float sc = p.ep_scale[co], sh = p.ep_shift[co];
        float* o = (float*)p.out;
        int b = nbase / 7744; int s = nbase - b * 7744;
        float4 v;
        v.x = fmaxf(fmaf(a[0], sc, sh), 0.f);
        v.y = fmaxf(fmaf(a[1], sc, sh), 0.f);
        v.z = fmaxf(fmaf(a[2], sc, sh), 0.f);
        v.w = fmaxf(fmaf(a[3], sc, sh), 0.f);
        *reinterpret_cast<float4*>(o + ((size_t)(b * 256 + co)) * 7744 + s) = v;
      } else {
        float* o = (float*)p.out + (size_t)slot * 968 * 256;
        #pragma unroll
        for (int r = 0; r < 4; ++r){
          int n = nbase + r;
          if (n < p.Mtot) o[(size_t)n * 256 + co] = a[r];
        }
      }
    }
  }
}

// ---------------------------------------------------------------- spatial mask
__global__ __launch_bounds__(256)
void mask_k(const unsigned short* __restrict__ h1, const float* __restrict__ w2,
            const float* __restrict__ b2, float* __restrict__ mask,
            unsigned short* __restrict__ FusPad)
{
  __shared__ float w[256];
  int t = threadIdx.x;
  w[t] = w2[t];
  __syncthreads();
  int n = blockIdx.x * 256 + t;
  const unsigned short* row = h1 + (size_t)n * 256;
  float s = b2[0];
  for (int c = 0; c < 256; c += 8){
    union { uint4 v; unsigned short s_[8]; } u;
    u.v = *reinterpret_cast<const uint4*>(row + c);
    #pragma unroll
    for (int j = 0; j < 8; ++j) s = fmaf(bf2f(u.s_[j]), w[c + j], s);
  }
  float m = 1.f / (1.f + __expf(-s));
  mask[n] = m;
  int b = n / 7744, sr = n - b * 7744;
  int y = sr / 88, x = sr - y * 88;
  FusPad[(((size_t)b * 90 + y + 1) * 90 + (x + 1)) * 576 + 512] = f2bf(m);
}

// ---------------------------------------------------------------- f_depth * mask -> NHWC bf16
__global__ __launch_bounds__(256)
void fdm_k(const unsigned short* __restrict__ Xpad, const float* __restrict__ mask,
           unsigned short* __restrict__ fdm)
{
  int idx = blockIdx.x * 256 + threadIdx.x;
  int n = idx >> 5, cb = idx & 31;
  int b = n / 7744, s = n - b * 7744;
  int y = s / 88, x = s - y * 88;
  size_t pix = ((size_t)(b * 90 + y + 1)) * 90 + x + 1;
  union { uint4 v; unsigned short s_[8]; } u, w;
  u.v = *reinterpret_cast<const uint4*>(Xpad + pix * 512 + 256 + cb * 8);
  float m = mask[n];
  #pragma unroll
  for (int j = 0; j < 8; ++j) w.s_[j] = f2bf(bf2f(u.s_[j]) * m);
  *reinterpret_cast<uint4*>(fdm + (size_t)n * 256 + cb * 8) = w.v;
}

// ---------------------------------------------------------------- split-K sum + channel LN
__global__ __launch_bounds__(256)
void lnkvr_k(const float* __restrict__ part, const float* __restrict__ srb,
             const float* __restrict__ lng, const float* __restrict__ lnb,
             unsigned short* __restrict__ kvr)
{
  int n = blockIdx.x, t = threadIdx.x;
  float v = srb[t];
  for (int s = 0; s < 16; ++s) v += part[((size_t)s * 968 + n) * 256 + t];
  float s1 = v, s2 = v * v;
  #pragma unroll
  for (int o = 1; o < 64; o <<= 1){ s1 += __shfl_xor(s1, o, 64); s2 += __shfl_xor(s2, o, 64); }
  __shared__ float a1[4], a2[4];
  if ((t & 63) == 0){ a1[t >> 6] = s1; a2[t >> 6] = s2; }
  __syncthreads();
  float t1 = a1[0] + a1[1] + a1[2] + a1[3];
  float t2 = a2[0] + a2[1] + a2[2] + a2[3];
  float mean = t1 * (1.f / 256.f);
  float var = t2 * (1.f / 256.f) - mean * mean;
  float rstd = rsqrtf(var + 1e-5f);
  kvr[(size_t)n * 256 + t] = f2bf((v - mean) * rstd * lng[t] + lnb[t]);
}

// ---------------------------------------------------------------- 1x1 conv 256->32 (K only)
__global__ __launch_bounds__(256)
void dotconv_k(const unsigned short* __restrict__ src,
               const unsigned short* __restrict__ wt, const float* __restrict__ bias,
               float* __restrict__ out)
{
  __shared__ unsigned short wl[256 * 32];
  const int t = threadIdx.x;
  {
    uint4* d = (uint4*)wl; const uint4* s = (const uint4*)wt;
    #pragma unroll
    for (int k = 0; k < 4; ++k) d[t + 256 * k] = s[t + 256 * k];
  }
  __syncthreads();
  const int n = blockIdx.x * 8 + (t >> 5);
  const int co = t & 31;
  const unsigned short* row = src + (size_t)n * 256;
  float sum = bias[co];
  for (int c = 0; c < 256; c += 8){
    union { uint4 v; unsigned short s_[8]; } u;
    u.v = *reinterpret_cast<const uint4*>(row + c);
    #pragma unroll
    for (int j = 0; j < 8; ++j)
      sum = fmaf(bf2f(u.s_[j]), bf2f(wl[(c + j) * 32 + co]), sum);
  }
  out[(size_t)n * 32 + co] = sum;
}

// ---------------------------------------------------------------- 1x1 conv 256->256 (V) -> VBt[b][c][128m] bf16
__global__ __launch_bounds__(256)
void vconv_k(const unsigned short* __restrict__ kvr, const unsigned short* __restrict__ vwt,
             const float* __restrict__ vb, unsigned short* __restrict__ VBt)
{
  __shared__ float rowf[256];
  const int n = blockIdx.x, t = threadIdx.x;
  rowf[t] = bf2f(kvr[(size_t)n * 256 + t]);
  __syncthreads();
  float sum = vb[t];
  #pragma unroll 8
  for (int c = 0; c < 256; ++c)
    sum = fmaf(rowf[c], bf2f(vwt[(size_t)c * 256 + t]), sum);
  int b = n / 121, m = n - b * 121;
  VBt[(size_t)b * 32768 + (size_t)t * 128 + m] = f2bf(sum);
}

// ---------------------------------------------------------------- MFMA attention (+fused Q-proj) + LN + residual
__global__ __launch_bounds__(512, 2)
void attn_k(const unsigned short* __restrict__ Qsrc, int qmode,
            const unsigned short* __restrict__ wq, const float* __restrict__ qb,
            const float* __restrict__ Kbuf,
            const unsigned short* __restrict__ VBt,
            const unsigned short* __restrict__ Xpad, int resChOff,
            unsigned short* __restrict__ FusPad, int outChOff,
            const float* __restrict__ ng, const float* __restrict__ nbv,
            const float* __restrict__ gammap)
{
  __shared__ unsigned short Vt[2][256][64];
  __shared__ unsigned short Pl[2][128][64];
  __shared__ unsigned short Qs[128][64];
  __shared__ unsigned short Ks[128][64];
  __shared__ unsigned short Wqs[32][256];

  const int t = threadIdx.x;
  const int lane = t & 63;
  const int w = t >> 6;
  const int c15 = lane & 15;
  const int h = lane >> 4;

  const int bid = blockIdx.x;
  const int b = bid / 61;
  const int rb = bid - b * 61;
  const int nb0 = rb * 128;

  const unsigned short* vsrc = VBt + (size_t)b * 32768;
  #pragma unroll
  for (int kt = 0; kt < 2; ++kt)
    #pragma unroll
    for (int i = 0; i < 4; ++i){
      int rowbase = i * 64 + w * 8;
      int c = rowbase + (lane >> 3);
      int mchunk = (lane & 7) ^ (c & 7);
      __builtin_amdgcn_global_load_lds(
        (AS1 void*)(vsrc + (size_t)c * 128 + kt * 64 + mchunk * 8),
        (AS3 void*)(&Vt[kt][rowbase][0]),
        16, 0, 0);
    }

  {
    uint4* d = (uint4*)&Wqs[0][0]; const uint4* s = (const uint4*)wq;
    d[t] = s[t];
    d[t + 512] = s[t + 512];
  }
  {
    int m = t >> 2, part = t & 3;
    union { uint4 v; unsigned short s_[8]; } u;
    u.v = uint4{0, 0, 0, 0};
    if (m < 121){
      const float* kp = Kbuf + ((size_t)b * 121 + m) * 32 + part * 8;
      float4 a = *reinterpret_cast<const float4*>(kp);
      float4 bb = *reinterpret_cast<const float4*>(kp + 4);
      u.s_[0] = f2bf(a.x); u.s_[1] = f2bf(a.y); u.s_[2] = f2bf(a.z); u.s_[3] = f2bf(a.w);
      u.s_[4] = f2bf(bb.x); u.s_[5] = f2bf(bb.y); u.s_[6] = f2bf(bb.z); u.s_[7] = f2bf(bb.w);
    }
    *reinterpret_cast<uint4*>(&Ks[m][(part ^ (m & 7)) * 8]) = u.v;
  }
  __syncthreads();

  const int nA = w * 16 + c15;
  const float scale = 0.17677669529663687f;  // 32^-0.5

  {
    int gn = nb0 + nA; if (gn > 7743) gn = 7743;
    const unsigned short* xrow;
    if (qmode){
      int y = gn / 88, x = gn - y * 88;
      xrow = Qsrc + (((size_t)(b * 90) + y + 1) * 90 + (x + 1)) * 512;
    } else {
      xrow = Qsrc + ((size_t)b * 7744 + gn) * 256;
    }
    f32x4 qacc[2];
    qacc[0] = f32x4{0.f, 0.f, 0.f, 0.f};
    qacc[1] = f32x4{0.f, 0.f, 0.f, 0.f};
    #pragma unroll
    for (int kt = 0; kt < 8; ++kt){
      bf16x8 ax = *reinterpret_cast<const bf16x8*>(xrow + kt * 32 + h * 8);
      #pragma unroll
      for (int ni = 0; ni < 2; ++ni){
        int co = ni * 16 + c15;
        bf16x8 bw = *reinterpret_cast<const bf16x8*>(&Wqs[co][((kt * 4 + h) ^ (co & 7)) * 8]);
        qacc[ni] = __builtin_amdgcn_mfma_f32_16x16x32_bf16(ax, bw, qacc[ni], 0, 0, 0);
      }
    }
    #pragma unroll
    for (int ni = 0; ni < 2; ++ni){
      int co = ni * 16 + c15;
      float bq = qb[co];
      #pragma unroll
      for (int r = 0; r < 4; ++r){
        int n = w * 16 + 4 * h + r;
        int chunk = (co >> 3) ^ (n & 7);
        Qs[n][chunk * 8 + (co & 7)] = f2bf((qacc[ni][r] + bq) * scale);
      }
    }
  }

  bf16x8 aq = *reinterpret_cast<const bf16x8*>(&Qs[nA][(h ^ (nA & 7)) * 8]);
  f32x4 sv[8];
  #pragma unroll
  for (int ni = 0; ni < 8; ++ni){
    int mrow = ni * 16 + c15;
    bf16x8 bk = *reinterpret_cast<const bf16x8*>(&Ks[mrow][(h ^ (mrow & 7)) * 8]);
    sv[ni] = __builtin_amdgcn_mfma_f32_16x16x32_bf16(aq, bk, f32x4{0.f,0.f,0.f,0.f}, 0, 0, 0);
  }
  if (c15 >= 9) sv[7] = f32x4{-1e30f, -1e30f, -1e30f, -1e30f};

  float rden[4];
  #pragma unroll
  for (int r = 0; r < 4; ++r){
    float mx = sv[0][r];
    #pragma unroll
    for (int ni = 1; ni < 8; ++ni) mx = fmaxf(mx, sv[ni][r]);
    #pragma unroll
    for (int o = 1; o < 16; o <<= 1) mx = fmaxf(mx, __shfl_xor(mx, o, 64));
    float sm = 0.f;
    #pragma unroll
    for (int ni = 0; ni < 8; ++ni){
      float p = __expf(sv[ni][r] - mx);
      sv[ni][r] = p;
      sm += p;
    }
    #pragma unroll
    for (int o = 1; o < 16; o <<= 1) sm += __shfl_xor(sm, o, 64);
    rden[r] = 1.f / sm;
  }
  #pragma unroll
  for (int ni = 0; ni < 8; ++ni){
    int m = ni * 16 + c15;
    int kt = m >> 6;
    int mq = (m & 63) >> 3;
    #pragma unroll
    for (int r = 0; r < 4; ++r){
      int n = w * 16 + 4 * h + r;
      Pl[kt][n][(mq ^ (n & 7)) * 8 + (m & 7)] = f2bf(sv[ni][r] * rden[r]);
    }
  }

  bf16x8 pa[2][2];
  #pragma unroll
  for (int kt = 0; kt < 2; ++kt)
    #pragma unroll
    for (int ks = 0; ks < 2; ++ks)
      pa[kt][ks] = *reinterpret_cast<const bf16x8*>(&Pl[kt][nA][((ks * 4 + h) ^ (nA & 7)) * 8]);

  f32x4 acc[16];
  #pragma unroll
  for (int ni = 0; ni < 16; ++ni) acc[ni] = f32x4{0.f, 0.f, 0.f, 0.f};
  #pragma unroll
  for (int ni = 0; ni < 16; ++ni){
    int crow = ni * 16 + c15;
    #pragma unroll
    for (int kt = 0; kt < 2; ++kt)
      #pragma unroll
      for (int ks = 0; ks < 2; ++ks){
        bf16x8 bv = *reinterpret_cast<const bf16x8*>(&Vt[kt][crow][((ks * 4 + h) ^ (crow & 7)) * 8]);
        acc[ni] = __builtin_amdgcn_mfma_f32_16x16x32_bf16(pa[kt][ks], bv, acc[ni], 0, 0, 0);
      }
  }

  float ngv[16], nbb[16];
  #pragma unroll
  for (int ni = 0; ni < 16; ++ni){
    int c = ni * 16 + c15;
    ngv[ni] = ng[c]; nbb[ni] = nbv[c];
  }
  float g = gammap[0]; g = fminf(fmaxf(g, 0.f), 1.f);

  #pragma unroll
  for (int r = 0; r < 4; ++r){
    float s1 = 0.f, s2 = 0.f;
    #pragma unroll
    for (int ni = 0; ni < 16; ++ni){ float v = acc[ni][r]; s1 += v; s2 += v * v; }
    #pragma unroll
    for (int o = 1; o < 16; o <<= 1){ s1 += __shfl_xor(s1, o, 64); s2 += __shfl_xor(s2, o, 64); }
    float mean = s1 * (1.f / 256.f);
    float var = s2 * (1.f / 256.f) - mean * mean;
    float rstd = rsqrtf(var + 1e-5f);

    int nloc = w * 16 + 4 * h + r;
    int rix = nb0 + nloc;
    if (rix < 7744){
      int y = rix / 88, x = rix - y * 88;
      size_t pix = ((size_t)(b * 90) + y + 1) * 90 + (x + 1);
      const unsigned short* res = Xpad + pix * 512 + resChOff;
      unsigned short* outp = FusPad + pix * 576 + outChOff;
      #pragma unroll
      for (int ni = 0; ni < 16; ++ni){
        int c = ni * 16 + c15;
        float yv = (acc[ni][r] - mean) * rstd * ngv[ni] + nbb[ni];
        outp[c] = f2bf(bf2f(res[c]) + g * yv);
      }
    }
  }
}

// ================================================================ host
extern "C" void kernel_launch(void* const* d_in, const int* in_sizes, int n_in,
                              void* d_out, int out_size, void* d_ws, size_t ws_size,
                              hipStream_t stream)
{
  const float* P[42];
  for (int i = 0; i < 42; ++i) P[i] = (const float*)d_in[i];

  char* ws = (char*)d_ws;
  size_t off = 0;
  auto take = [&](size_t bytes) -> char* {
    char* p = ws + off; off += (bytes + 255) & ~(size_t)255; return p;
  };
  unsigned short* XPAD = (unsigned short*)take(8ull * 8100 * 512 * 2);   // 66.4 MB
  unsigned short* FUSP = (unsigned short*)take(8ull * 8100 * 576 * 2);   // 74.6 MB
  unsigned short* H1   = (unsigned short*)take(61952ull * 256 * 2);      // 31.7 MB
  unsigned short* FDM  = H1;  // alias: h1 dead after mask_k
  unsigned short* W1T  = (unsigned short*)take(9ull * 256 * 512 * 2);
  unsigned short* WFT  = (unsigned short*)take(9ull * 256 * 576 * 2);
  unsigned short* WSRA = (unsigned short*)take(64ull * 256 * 256 * 2);
  unsigned short* WSRB = (unsigned short*)take(64ull * 256 * 256 * 2);
  float* PART = (float*)take(16ull * 968 * 256 * 4);                      // 15.9 MB
  unsigned short* KVR = (unsigned short*)take(968ull * 256 * 2);
  float* KB   = (float*)take(968ull * 32 * 4);
  unsigned short* VBT = (unsigned short*)take(8ull * 256 * 128 * 2);      // 512 KB
  float* MASK = (float*)take(61952ull * 4);
  float* SC1 = (float*)take(256 * 4);
  float* SH1 = (float*)take(256 * 4);
  float* SCF = (float*)take(256 * 4);
  float* SHF = (float*)take(256 * 4);
  unsigned short* WQSA = (unsigned short*)take(32ull * 256 * 2);
  unsigned short* WQSB = (unsigned short*)take(32ull * 256 * 2);
  unsigned short* KWTA = (unsigned short*)take(256ull * 32 * 2);
  unsigned short* VWTA = (unsigned short*)take(256ull * 256 * 2);
  unsigned short* KWTB = (unsigned short*)take(256ull * 32 * 2);
  unsigned short* VWTB = (unsigned short*)take(256ull * 256 * 2);
  (void)ws_size; (void)in_sizes; (void)n_in; (void)out_size;

  zero_border_k<<<8 * 356, 128, 0, stream>>>(XPAD, 512);
  zero_border_k<<<8 * 356, 128, 0, stream>>>(FUSP, 576);
  zero_fustail_k<<<1936, 256, 0, stream>>>(FUSP);
  hipMemsetAsync(VBT, 0, 8ull * 256 * 128 * 2, stream);

  bnprep_k<<<1, 256, 0, stream>>>(P[4], P[5], P[6], P[7], P[3],
                                  P[38], P[39], P[40], P[41], P[37],
                                  SC1, SH1, SCF, SHF);
  prep_xpad_k<<<7744, 256, 0, stream>>>(P[0], P[1], XPAD);
  prep_w1t_k<<<256, 256, 0, stream>>>(P[2], W1T);
  prep_wfus_k<<<256, 256, 0, stream>>>(P[36], WFT);
  prep_wsr_k<<<256, 256, 0, stream>>>(P[16], WSRA);
  prep_wsr_k<<<256, 256, 0, stream>>>(P[28], WSRB);
  wqprep_k<<<32, 256, 0, stream>>>(P[10], WQSA);
  wqprep_k<<<32, 256, 0, stream>>>(P[22], WQSB);
  tranw_k<<<8, 256, 0, stream>>>(P[12], KWTA, 32, 256);
  tranw_k<<<64, 256, 0, stream>>>(P[14], VWTA, 256, 256);
  tranw_k<<<8, 256, 0, stream>>>(P[24], KWTB, 32, 256);
  tranw_k<<<64, 256, 0, stream>>>(P[26], VWTB, 256, 256);

  // conv1 3x3 (512->256) + BN + ReLU -> h1 NHWC bf16
  GemmP g1{};
  g1.A = XPAD; g1.W = W1T; g1.ep_scale = SC1; g1.ep_shift = SH1; g1.out = H1;
  g1.img_px = 8100; g1.row_px = 90; g1.px_el = 512; g1.ch_off = 0; g1.y0 = 0; g1.x0 = 0;
  g1.tapw = 3; g1.stridepix = 1; g1.out_w = 88; g1.out_imgpx = 7744;
  g1.Cin = 512; g1.Mtot = 61952; g1.Mtiles = 484; g1.Ntiles = 2; g1.k_per = 4608;
  gemm_k<0><<<968, 256, 0, stream>>>(g1);

  mask_k<<<242, 256, 0, stream>>>(H1, P[8], P[9], MASK, FUSP);
  fdm_k<<<7744, 256, 0, stream>>>(XPAD, MASK, FDM);

  // ---------------- d2r: Q from f_rgb (XPAD rgb), KV from f_depth_masked ----------------
  GemmP gs{};
  gs.A = FDM; gs.W = WSRA; gs.out = PART;
  gs.img_px = 7744; gs.row_px = 88; gs.px_el = 256; gs.ch_off = 0; gs.y0 = 0; gs.x0 = 0;
  gs.tapw = 8; gs.stridepix = 8; gs.out_w = 11; gs.out_imgpx = 121;
  gs.Cin = 256; gs.Mtot = 968; gs.Mtiles = 8; gs.Ntiles = 2; gs.k_per = 1024;
  gemm_k<2><<<256, 256, 0, stream>>>(gs);
  lnkvr_k<<<968, 256, 0, stream>>>(PART, P[17], P[18], P[19], KVR);
  dotconv_k<<<121, 256, 0, stream>>>(KVR, KWTA, P[13], KB);
  vconv_k<<<968, 256, 0, stream>>>(KVR, VWTA, P[15], VBT);
  attn_k<<<488, 512, 0, stream>>>(XPAD, 1, WQSA, P[11], KB, VBT, XPAD, 0,
                                  FUSP, 0, P[20], P[21], P[34]);

  // ---------------- r2d: Q from f_depth_masked (FDM), KV from f_rgb ----------------
  gs.A = XPAD; gs.W = WSRB;
  gs.img_px = 8100; gs.row_px = 90; gs.px_el = 512; gs.y0 = 1; gs.x0 = 1;
  gemm_k<2><<<256, 256, 0, stream>>>(gs);
  lnkvr_k<<<968, 256, 0, stream>>>(PART, P[29], P[30], P[31], KVR);
  dotconv_k<<<121, 256, 0, stream>>>(KVR, KWTB, P[25], KB);
  vconv_k<<<968, 256, 0, stream>>>(KVR, VWTB, P[27], VBT);
  attn_k<<<488, 512, 0, stream>>>(FDM, 0, WQSB, P[23], KB, VBT, XPAD, 256,
                                  FUSP, 256, P[32], P[33], P[35]);

  // final fused conv 3x3 (576->256) + BN + ReLU -> d_out f32 NCHW
  GemmP gf{};
  gf.A = FUSP; gf.W = WFT; gf.ep_scale = SCF; gf.ep_shift = SHF; gf.out = d_out;
  gf.img_px = 8100; gf.row_px = 90; gf.px_el = 576; gf.ch_off = 0; gf.y0 = 0; gf.x0 = 0;
  gf.tapw = 3; gf.stridepix = 1; gf.out_w = 88; gf.out_imgpx = 7744;
  gf.Cin = 576; gf.Mtot = 61952; gf.Mtiles = 484; gf.Ntiles = 2; gf.k_per = 5184;
  gemm_k<1><<<968, 256, 0, stream>>>(gf);
}

// Round 9
// 552.601 us; speedup vs baseline: 4.6821x; 1.0844x over previous
//
#include <hip/hip_runtime.h>
#include <hip/hip_bf16.h>

// BiDirectionalFusionModule on MI355X.
// R2: global_load_lds(16B) GEMM staging; coalesced weight preps.
// R3: fixed dotconv weight staging.
// R5: MFMA attention (8 waves, wave-local softmax/LN, swizzled LDS, V via lds-DMA).
// R6: GEMM L2-locality (cib-outer/tap-inner, nt-inner, XCD chunk swizzle): FETCH 574->60MB.
// R7: Q-proj fused into attn_k; targeted border/tail zeroing.
// R8: 2-phase counted-vmcnt on 128^2 GEMM: NULL (m139 replicated).
// R9: 8-phase 256^2 GEMM (T3+T4+T5) for the two big convs: 512thr/8waves,
//     per-wave 128x64, BK=64, 128KB LDS dbuf, 4 phases/K-step, counted vmcnt(2),
//     setprio around MFMA. M=61952=242x256 exactly; grid 242 (~1 block/CU).

typedef __bf16 bf16x8 __attribute__((ext_vector_type(8)));
typedef float f32x4 __attribute__((ext_vector_type(4)));

#define AS1 __attribute__((address_space(1)))
#define AS3 __attribute__((address_space(3)))
#define DEVI __device__ __forceinline__
#define BARRIER() do { asm volatile("" ::: "memory"); __builtin_amdgcn_s_barrier(); asm volatile("" ::: "memory"); } while (0)

DEVI float bf2f(unsigned short u){
  union { unsigned int i; float f; } v; v.i = ((unsigned int)u) << 16; return v.f;
}
DEVI unsigned short f2bf(float f){
  union { float f; unsigned int i; } v; v.f = f;
  unsigned int x = v.i;
  unsigned int r = (x + 0x7fffu + ((x >> 16) & 1u)) >> 16;
  return (unsigned short)r;
}

// ---------------------------------------------------------------- BN prep
__global__ void bnprep_k(const float* __restrict__ g1, const float* __restrict__ be1,
                         const float* __restrict__ m1, const float* __restrict__ v1,
                         const float* __restrict__ b1,
                         const float* __restrict__ gf, const float* __restrict__ bef,
                         const float* __restrict__ mf, const float* __restrict__ vf,
                         const float* __restrict__ bf,
                         float* __restrict__ sc1, float* __restrict__ sh1,
                         float* __restrict__ scf, float* __restrict__ shf)
{
  int c = threadIdx.x;
  float s = g1[c] * rsqrtf(v1[c] + 1e-5f);
  sc1[c] = s; sh1[c] = (b1[c] - m1[c]) * s + be1[c];
  s = gf[c] * rsqrtf(vf[c] + 1e-5f);
  scf[c] = s; shf[c] = (bf[c] - mf[c]) * s + bef[c];
}

// ---------------------------------------------------------------- targeted zeroing
__global__ __launch_bounds__(128)
void zero_border_k(unsigned short* __restrict__ buf, int px_el)
{
  int bi = blockIdx.x;
  int img = bi / 356, e = bi - img * 356;
  int y, x;
  if (e < 90){ y = 0; x = e; }
  else if (e < 180){ y = 89; x = e - 90; }
  else if (e < 268){ y = e - 180 + 1; x = 0; }
  else { y = e - 268 + 1; x = 89; }
  size_t pix = ((size_t)img * 90 + y) * 90 + x;
  int t = threadIdx.x;
  if (t < (px_el >> 3))
    *reinterpret_cast<uint4*>(buf + pix * px_el + t * 8) = uint4{0, 0, 0, 0};
}
__global__ __launch_bounds__(256)
void zero_fustail_k(unsigned short* __restrict__ FusPad)
{
  int idx = blockIdx.x * 256 + threadIdx.x;   // 61952*8
  int n = idx >> 3, ch = idx & 7;
  int b = n / 7744, s = n - b * 7744;
  int y = s / 88, x = s - y * 88;
  size_t pix = ((size_t)(b * 90 + y + 1)) * 90 + (x + 1);
  *reinterpret_cast<uint4*>(FusPad + pix * 576 + 512 + ch * 8) = uint4{0, 0, 0, 0};
}

// ------------------------------------------------- NCHW f32 -> padded NHWC bf16
__global__ __launch_bounds__(256)
void prep_xpad_k(const float* __restrict__ rgb, const float* __restrict__ dep,
                 unsigned short* __restrict__ Xpad)
{
  __shared__ unsigned short tile[64][65];
  int bi = blockIdx.x;
  int b = bi / 968;
  int rem = bi - b * 968;
  int cblk = rem / 121;
  int pblk = rem - cblk * 121;
  int t = threadIdx.x;
  int pl = t & 63;
  #pragma unroll
  for (int pass = 0; pass < 16; ++pass){
    int cl = pass * 4 + (t >> 6);
    int c = cblk * 64 + cl;
    const float* sp = (c < 256) ? (rgb + ((size_t)b * 256 + c) * 7744)
                                : (dep + ((size_t)b * 256 + (c - 256)) * 7744);
    tile[cl][pl] = f2bf(sp[pblk * 64 + pl]);
  }
  __syncthreads();
  int cl2 = t & 63;
  for (int pass = 0; pass < 16; ++pass){
    int pl2 = pass * 4 + (t >> 6);
    int pixg = pblk * 64 + pl2;
    int y = pixg / 88, x = pixg - y * 88;
    Xpad[(((size_t)b * 90 + y + 1) * 90 + (x + 1)) * 512 + cblk * 64 + cl2] = tile[cl2][pl2];
  }
}

// ---------------------------------------------------------------- weight reshuffles
__global__ __launch_bounds__(256)
void prep_w1t_k(const float* __restrict__ w, unsigned short* __restrict__ o)
{
  int co = blockIdx.x, t = threadIdx.x;
  const float* src = w + (size_t)co * 4608 + t * 18;
  unsigned int* op = (unsigned int*)o;
  #pragma unroll
  for (int k = 0; k < 9; ++k){
    unsigned short lo = f2bf(src[k]);
    unsigned short hi = f2bf(src[9 + k]);
    op[((size_t)k * 256 + co) * 256 + t] = lo | ((unsigned int)hi << 16);
  }
}
__global__ __launch_bounds__(256)
void prep_wfus_k(const float* __restrict__ w, unsigned short* __restrict__ o)
{
  int co = blockIdx.x, t = threadIdx.x;
  const float* src = w + (size_t)co * 4617 + t * 18;
  unsigned int* op = (unsigned int*)o;
  #pragma unroll
  for (int k = 0; k < 9; ++k){
    unsigned short lo = f2bf(src[k]);
    unsigned short hi = f2bf(src[9 + k]);
    op[((size_t)k * 256 + co) * 288 + t] = lo | ((unsigned int)hi << 16);
  }
  if (t < 32){
    #pragma unroll
    for (int k = 0; k < 9; ++k){
      unsigned int val = 0;
      if (t == 0) val = (unsigned int)f2bf(w[(size_t)co * 4617 + 512 * 9 + k]);
      op[((size_t)k * 256 + co) * 288 + 256 + t] = val;
    }
  }
}
__global__ __launch_bounds__(256)
void prep_wsr_k(const float* __restrict__ w, unsigned short* __restrict__ o)
{
  __shared__ float ld[64][65];
  int co = blockIdx.x;
  int t = threadIdx.x;
  for (int cib = 0; cib < 256; cib += 64){
    int cil = t >> 2, tq = t & 3;
    const float* src = w + ((size_t)co * 256 + cib + cil) * 64 + tq * 16;
    float v[16];
    #pragma unroll
    for (int k = 0; k < 16; ++k) v[k] = src[k];
    __syncthreads();
    #pragma unroll
    for (int k = 0; k < 16; ++k) ld[cil][tq * 16 + k] = v[k];
    __syncthreads();
    #pragma unroll
    for (int tp = 0; tp < 16; ++tp){
      int tap = tp * 4 + (t >> 6);
      int ci = t & 63;
      o[((size_t)tap * 256 + co) * 256 + cib + ci] = f2bf(ld[ci][tap]);
    }
  }
}
__global__ __launch_bounds__(256)
void tranw_k(const float* __restrict__ in, unsigned short* __restrict__ out, int R, int C)
{
  __shared__ float tl[32][33];
  int tiles_c = C >> 5;
  int tr = (blockIdx.x / tiles_c) << 5, tc = (blockIdx.x % tiles_c) << 5;
  int t = threadIdx.x; int r = t >> 5, c = t & 31;
  #pragma unroll
  for (int p = 0; p < 4; ++p)
    tl[r + p * 8][c] = in[(size_t)(tr + r + p * 8) * C + tc + c];
  __syncthreads();
  #pragma unroll
  for (int p = 0; p < 4; ++p)
    out[(size_t)(tc + r + p * 8) * R + tr + c] = f2bf(tl[c][r + p * 8]);
}
__global__ __launch_bounds__(256)
void wqprep_k(const float* __restrict__ w, unsigned short* __restrict__ o)
{
  int co = blockIdx.x, t = threadIdx.x;
  int c = t >> 3, e = t & 7;
  o[co * 256 + ((c ^ (co & 7)) * 8) + e] = f2bf(w[co * 256 + t]);
}

// ---------------------------------------------------------------- GEMM params
struct GemmP {
  const unsigned short* A;
  const unsigned short* W;
  const float* ep_scale;
  const float* ep_shift;
  void* out;
  int img_px, row_px, px_el, ch_off, y0, x0;
  int tapw, stridepix, out_w, out_imgpx;
  int Cin, Mtot, Mtiles, Ntiles, k_per;
};

// ---------------------------------------------------------------- 128^2 GEMM (SR convs, EPI=2)
template<int EPI>
__global__ __launch_bounds__(256)
void gemm_k(GemmP p)
{
  __shared__ __bf16 As[2][128 * 64];
  __shared__ __bf16 Bs[2][128 * 64];
  const int t = threadIdx.x;
  const int lane = t & 63;
  const int wid = t >> 6;
  const int wr = wid >> 1, wc = wid & 1;

  const int cpx = gridDim.x >> 3;
  int pid = (blockIdx.x & 7) * cpx + (blockIdx.x >> 3);
  const int mn = p.Mtiles * p.Ntiles;
  int within = pid % mn;
  int slot = pid / mn;
  int mt = within / p.Ntiles;
  int nt = within - mt * p.Ntiles;
  int kb = slot * p.k_per;
  int tap0 = kb / p.Cin;
  int ntap = p.k_per / p.Cin;

  long long apix[4]; int cbg8[4]; int wrow[4];
  #pragma unroll
  for (int i = 0; i < 4; ++i){
    int r = i * 32 + (t >> 3);
    cbg8[i] = ((t & 7) ^ (r & 7)) * 8;
    int n = mt * 128 + r;
    int nc = n < p.Mtot ? n : 0;
    int b = nc / p.out_imgpx; int rr = nc - b * p.out_imgpx;
    int yo = rr / p.out_w;    int xo = rr - yo * p.out_w;
    apix[i] = (long long)b * p.img_px + (long long)(yo * p.stridepix + p.y0) * p.row_px
            + (xo * p.stridepix + p.x0);
    wrow[i] = (nt * 128 + r) * p.Cin + cbg8[i];
  }

  f32x4 acc[4][4];
  #pragma unroll
  for (int i = 0; i < 4; ++i)
    #pragma unroll
    for (int j = 0; j < 4; ++j)
      acc[i][j] = f32x4{0.f, 0.f, 0.f, 0.f};

  const long long wstap = 256LL * p.Cin;

  auto STAGE = [&](int buf, int tap, int cib){
    int dy = tap / p.tapw, dx = tap - dy * p.tapw;
    const unsigned short* wb = p.W + (long long)tap * wstap + cib;
    const long long aoff = (long long)(dy * p.row_px + dx) * p.px_el + p.ch_off + cib;
    #pragma unroll
    for (int i = 0; i < 4; ++i){
      __builtin_amdgcn_global_load_lds(
          (AS1 void*)(p.A + apix[i] * p.px_el + aoff + cbg8[i]),
          (AS3 void*)(&As[buf][i * 2048 + wid * 512]),
          16, 0, 0);
      __builtin_amdgcn_global_load_lds(
          (AS1 void*)(wb + wrow[i]),
          (AS3 void*)(&Bs[buf][i * 2048 + wid * 512]),
          16, 0, 0);
    }
  };

  const int NT = (p.Cin >> 6) * ntap;
  STAGE(0, tap0, 0);
  int tpn = 1, tap_n = tap0 + 1, cib_n = 0;
  int cur = 0;

  for (int kt = 0; kt < NT; ++kt){
    if (kt + 1 < NT){
      STAGE(cur ^ 1, tap_n, cib_n);
      ++tpn; ++tap_n;
      if (tpn == ntap){ tpn = 0; tap_n = tap0; cib_n += 64; }
      asm volatile("s_waitcnt vmcnt(8)" ::: "memory");
    } else {
      asm volatile("s_waitcnt vmcnt(0)" ::: "memory");
    }
    __builtin_amdgcn_s_barrier();
    __builtin_amdgcn_sched_barrier(0);

    #pragma unroll
    for (int ks = 0; ks < 2; ++ks){
      bf16x8 av[4], bv[4];
      #pragma unroll
      for (int mi = 0; mi < 4; ++mi){
        int ar = wr * 64 + mi * 16 + (lane & 15);
        int cb = (ks * 4 + (lane >> 4)) ^ (ar & 7);
        av[mi] = *reinterpret_cast<const bf16x8*>(&As[cur][ar * 64 + cb * 8]);
      }
      #pragma unroll
      for (int ni = 0; ni < 4; ++ni){
        int br = wc * 64 + ni * 16 + (lane & 15);
        int cb = (ks * 4 + (lane >> 4)) ^ (br & 7);
        bv[ni] = *reinterpret_cast<const bf16x8*>(&Bs[cur][br * 64 + cb * 8]);
      }
      #pragma unroll
      for (int mi = 0; mi < 4; ++mi)
        #pragma unroll
        for (int ni = 0; ni < 4; ++ni)
          acc[mi][ni] = __builtin_amdgcn_mfma_f32_16x16x32_bf16(av[mi], bv[ni], acc[mi][ni], 0, 0, 0);
    }

    __builtin_amdgcn_sched_barrier(0);
    __builtin_amdgcn_s_barrier();
    cur ^= 1;
  }

  const int r0 = (lane >> 4) * 4;
  const int c0 = lane & 15;
  #pragma unroll
  for (int mi = 0; mi < 4; ++mi){
    int nbase = mt * 128 + wr * 64 + mi * 16 + r0;
    #pragma unroll
    for (int ni = 0; ni < 4; ++ni){
      int co = nt * 128 + wc * 64 + ni * 16 + c0;
      f32x4 a = acc[mi][ni];
      float* o = (float*)p.out + (size_t)slot * 968 * 256;
      #pragma unroll
      for (int r = 0; r < 4; ++r){
        int n = nbase + r;
        if (n < p.Mtot) o[(size_t)n * 256 + co] = a[r];
      }
    }
  }
}

// ---------------------------------------------------------------- 256^2 8-phase GEMM (big convs)
// 512 thr = 8 waves (2M x 4N); per-wave 128x64 out; BK=64; LDS 128KB dbuf.
// Per K-step: 4 phases of {ds-read subtile + 2 stage-issues, barrier, 16 MFMA, barrier};
// counted vmcnt(2) at phase 0 only (never drain in main loop).
template<int EPI>   // 0: BN+ReLU -> bf16 NHWC[.][256]   1: BN+ReLU -> f32 NCHW
__global__ __launch_bounds__(512, 2)
void gemm256_k(GemmP p)
{
  __shared__ __bf16 As[2][256 * 64];
  __shared__ __bf16 Bs[2][256 * 64];
  const int t = threadIdx.x;
  const int lane = t & 63;
  const int w = t >> 6;
  const int wr = w >> 2, wc = w & 3;
  const int c15 = lane & 15;
  const int h = lane >> 4;

  // bijective chunked XCD swizzle (m204; grid not multiple of 8)
  const int nwg = gridDim.x;
  const int q = nwg >> 3, r8 = nwg & 7;
  const int bid = blockIdx.x;
  const int xcd = bid & 7;
  const int mt = (xcd < r8 ? xcd * (q + 1) : r8 * (q + 1) + (xcd - r8) * q) + (bid >> 3);

  long long apixel[4];
  const unsigned short* wsrc[4];
  int lbase[4];
  #pragma unroll
  for (int i = 0; i < 4; ++i){
    int r = i * 64 + (t >> 3);
    int cb = ((t & 7) ^ (r & 7)) * 8;
    int n = mt * 256 + r;                   // Mtot = 242*256 exactly, no clamp
    int b = n / p.out_imgpx; int rr = n - b * p.out_imgpx;
    int yo = rr / p.out_w;   int xo = rr - yo * p.out_w;
    long long pix = (long long)b * p.img_px + (long long)(yo * p.stridepix + p.y0) * p.row_px
                  + (xo * p.stridepix + p.x0);
    apixel[i] = pix * p.px_el + p.ch_off + cb;
    wsrc[i] = p.W + (long long)r * p.Cin + cb;
    lbase[i] = i * 4096 + w * 512;          // wave-uniform LDS base (elements)
  }

  f32x4 acc[8][4];
  #pragma unroll
  for (int i = 0; i < 8; ++i)
    #pragma unroll
    for (int j = 0; j < 4; ++j)
      acc[i][j] = f32x4{0.f, 0.f, 0.f, 0.f};

  const long long wstap = 256LL * p.Cin;
  const int ntap = p.k_per / p.Cin;         // 9
  const int NT = (p.Cin >> 6) * ntap;       // 72 or 81

  auto STG = [&](int buf, int i, long long aoff, long long woff){
    __builtin_amdgcn_global_load_lds(
        (AS1 void*)(p.A + apixel[i] + aoff),
        (AS3 void*)(&As[buf][lbase[i]]), 16, 0, 0);
    __builtin_amdgcn_global_load_lds(
        (AS1 void*)(wsrc[i] + woff),
        (AS3 void*)(&Bs[buf][lbase[i]]), 16, 0, 0);
  };
  auto LDA = [&](bf16x8* av, int mi0, int ks, int buf){
    #pragma unroll
    for (int m = 0; m < 4; ++m){
      int ar = wr * 128 + (mi0 + m) * 16 + c15;
      int cb = (ks * 4 + h) ^ (ar & 7);
      av[m] = *reinterpret_cast<const bf16x8*>(&As[buf][ar * 64 + cb * 8]);
    }
  };
  auto LDB = [&](bf16x8* bv, int ks, int buf){
    #pragma unroll
    for (int n = 0; n < 4; ++n){
      int br = wc * 64 + n * 16 + c15;
      int cb = (ks * 4 + h) ^ (br & 7);
      bv[n] = *reinterpret_cast<const bf16x8*>(&Bs[buf][br * 64 + cb * 8]);
    }
  };
  auto MM = [&](bf16x8* av, bf16x8* bv, int mi0){
    __builtin_amdgcn_s_setprio(1);
    #pragma unroll
    for (int m = 0; m < 4; ++m)
      #pragma unroll
      for (int n = 0; n < 4; ++n)
        acc[mi0 + m][n] = __builtin_amdgcn_mfma_f32_16x16x32_bf16(av[m], bv[n], acc[mi0 + m][n], 0, 0, 0);
    __builtin_amdgcn_s_setprio(0);
  };

  // prologue: stage kt=0 (tap 0, cib 0 -> offsets 0)
  #pragma unroll
  for (int i = 0; i < 4; ++i) STG(0, i, 0, 0);

  int tap_n = 1, cib_n = 0;   // coords of kt+1 (tap-inner, cib-outer)
  int cur = 0;

  for (int kt = 0; kt < NT; ++kt){
    const bool last = (kt == NT - 1);
    long long aoff_n = 0, woff_n = 0;
    if (!last){
      int dy = tap_n / p.tapw, dx = tap_n - dy * p.tapw;
      aoff_n = (long long)(dy * p.row_px + dx) * p.px_el + cib_n;
      woff_n = (long long)tap_n * wstap + cib_n;
    }
    bf16x8 av[4], bv[4];

    // ---- phase 0: validate buf[cur], compute mi0-3 ks0 ----
    if (!last){
      STG(cur ^ 1, 0, aoff_n, woff_n);
      asm volatile("s_waitcnt vmcnt(2)" ::: "memory");   // all 8 of kt landed; pair0 of kt+1 in flight
    } else {
      asm volatile("s_waitcnt vmcnt(0)" ::: "memory");
    }
    BARRIER();
    LDA(av, 0, 0, cur); LDB(bv, 0, cur);
    MM(av, bv, 0);
    BARRIER();
    // ---- phase 1: mi4-7 ks0 ----
    LDA(av, 4, 0, cur);
    if (!last) STG(cur ^ 1, 1, aoff_n, woff_n);
    BARRIER();
    MM(av, bv, 4);
    BARRIER();
    // ---- phase 2: mi0-3 ks1 ----
    LDA(av, 0, 1, cur); LDB(bv, 1, cur);
    if (!last) STG(cur ^ 1, 2, aoff_n, woff_n);
    BARRIER();
    MM(av, bv, 0);
    BARRIER();
    // ---- phase 3: mi4-7 ks1 ----
    LDA(av, 4, 1, cur);
    if (!last) STG(cur ^ 1, 3, aoff_n, woff_n);
    BARRIER();
    MM(av, bv, 4);
    BARRIER();

    cur ^= 1;
    if (!last){ ++tap_n; if (tap_n == ntap){ tap_n = 0; cib_n += 64; } }
  }

  // ---- epilogue ----
  const int r0 = (lane >> 4) * 4;
  #pragma unroll
  for (int mi = 0; mi < 8; ++mi){
    int nbase = mt * 256 + wr * 128 + mi * 16 + r0;
    #pragma unroll
    for (int ni = 0; ni < 4; ++ni){
      int co = wc * 64 + ni * 16 + c15;
      f32x4 a = acc[mi][ni];
      if constexpr (EPI == 0){
        float sc = p.ep_scale[co], sh = p.ep_shift[co];
        unsigned short* o = (unsigned short*)p.out;
        #pragma unroll
        for (int r = 0; r < 4; ++r){
          float v = fmaf(a[r], sc, sh); v = v > 0.f ? v : 0.f;
          o[(size_t)(nbase + r) * 256 + co] = f2bf(v);
        }
      } else {
        float sc = p.ep_scale[co], sh = p.ep_shift[co];
        float* o = (float*)p.out;
        int b = nbase / 7744; int s = nbase - b * 7744;
        float4 v;
        v.x = fmaxf(fmaf(a[0], sc, sh), 0.f);
        v.y = fmaxf(fmaf(a[1], sc, sh), 0.f);
        v.z = fmaxf(fmaf(a[2], sc, sh), 0.f);
        v.w = fmaxf(fmaf(a[3], sc, sh), 0.f);
        *reinterpret_cast<float4*>(o + ((size_t)(b * 256 + co)) * 7744 + s) = v;
      }
    }
  }
}

// ---------------------------------------------------------------- spatial mask
__global__ __launch_bounds__(256)
void mask_k(const unsigned short* __restrict__ h1, const float* __restrict__ w2,
            const float* __restrict__ b2, float* __restrict__ mask,
            unsigned short* __restrict__ FusPad)
{
  __shared__ float w[256];
  int t = threadIdx.x;
  w[t] = w2[t];
  __syncthreads();
  int n = blockIdx.x * 256 + t;
  const unsigned short* row = h1 + (size_t)n * 256;
  float s = b2[0];
  for (int c = 0; c < 256; c += 8){
    union { uint4 v; unsigned short s_[8]; } u;
    u.v = *reinterpret_cast<const uint4*>(row + c);
    #pragma unroll
    for (int j = 0; j < 8; ++j) s = fmaf(bf2f(u.s_[j]), w[c + j], s);
  }
  float m = 1.f / (1.f + __expf(-s));
  mask[n] = m;
  int b = n / 7744, sr = n - b * 7744;
  int y = sr / 88, x = sr - y * 88;
  FusPad[(((size_t)b * 90 + y + 1) * 90 + (x + 1)) * 576 + 512] = f2bf(m);
}

// ---------------------------------------------------------------- f_depth * mask -> NHWC bf16
__global__ __launch_bounds__(256)
void fdm_k(const unsigned short* __restrict__ Xpad, const float* __restrict__ mask,
           unsigned short* __restrict__ fdm)
{
  int idx = blockIdx.x * 256 + threadIdx.x;
  int n = idx >> 5, cb = idx & 31;
  int b = n / 7744, s = n - b * 7744;
  int y = s / 88, x = s - y * 88;
  size_t pix = ((size_t)(b * 90 + y + 1)) * 90 + x + 1;
  union { uint4 v; unsigned short s_[8]; } u, w;
  u.v = *reinterpret_cast<const uint4*>(Xpad + pix * 512 + 256 + cb * 8);
  float m = mask[n];
  #pragma unroll
  for (int j = 0; j < 8; ++j) w.s_[j] = f2bf(bf2f(u.s_[j]) * m);
  *reinterpret_cast<uint4*>(fdm + (size_t)n * 256 + cb * 8) = w.v;
}

// ---------------------------------------------------------------- split-K sum + channel LN
__global__ __launch_bounds__(256)
void lnkvr_k(const float* __restrict__ part, const float* __restrict__ srb,
             const float* __restrict__ lng, const float* __restrict__ lnb,
             unsigned short* __restrict__ kvr)
{
  int n = blockIdx.x, t = threadIdx.x;
  float v = srb[t];
  for (int s = 0; s < 16; ++s) v += part[((size_t)s * 968 + n) * 256 + t];
  float s1 = v, s2 = v * v;
  #pragma unroll
  for (int o = 1; o < 64; o <<= 1){ s1 += __shfl_xor(s1, o, 64); s2 += __shfl_xor(s2, o, 64); }
  __shared__ float a1[4], a2[4];
  if ((t & 63) == 0){ a1[t >> 6] = s1; a2[t >> 6] = s2; }
  __syncthreads();
  float t1 = a1[0] + a1[1] + a1[2] + a1[3];
  float t2 = a2[0] + a2[1] + a2[2] + a2[3];
  float mean = t1 * (1.f / 256.f);
  float var = t2 * (1.f / 256.f) - mean * mean;
  float rstd = rsqrtf(var + 1e-5f);
  kvr[(size_t)n * 256 + t] = f2bf((v - mean) * rstd * lng[t] + lnb[t]);
}

// ---------------------------------------------------------------- 1x1 conv 256->32 (K only)
__global__ __launch_bounds__(256)
void dotconv_k(const unsigned short* __restrict__ src,
               const unsigned short* __restrict__ wt, const float* __restrict__ bias,
               float* __restrict__ out)
{
  __shared__ unsigned short wl[256 * 32];
  const int t = threadIdx.x;
  {
    uint4* d = (uint4*)wl; const uint4* s = (const uint4*)wt;
    #pragma unroll
    for (int k = 0; k < 4; ++k) d[t + 256 * k] = s[t + 256 * k];
  }
  __syncthreads();
  const int n = blockIdx.x * 8 + (t >> 5);
  const int co = t & 31;
  const unsigned short* row = src + (size_t)n * 256;
  float sum = bias[co];
  for (int c = 0; c < 256; c += 8){
    union { uint4 v; unsigned short s_[8]; } u;
    u.v = *reinterpret_cast<const uint4*>(row + c);
    #pragma unroll
    for (int j = 0; j < 8; ++j)
      sum = fmaf(bf2f(u.s_[j]), bf2f(wl[(c + j) * 32 + co]), sum);
  }
  out[(size_t)n * 32 + co] = sum;
}

// ---------------------------------------------------------------- 1x1 conv 256->256 (V) -> VBt[b][c][128m] bf16
__global__ __launch_bounds__(256)
void vconv_k(const unsigned short* __restrict__ kvr, const unsigned short* __restrict__ vwt,
             const float* __restrict__ vb, unsigned short* __restrict__ VBt)
{
  __shared__ float rowf[256];
  const int n = blockIdx.x, t = threadIdx.x;
  rowf[t] = bf2f(kvr[(size_t)n * 256 + t]);
  __syncthreads();
  float sum = vb[t];
  #pragma unroll 8
  for (int c = 0; c < 256; ++c)
    sum = fmaf(rowf[c], bf2f(vwt[(size_t)c * 256 + t]), sum);
  int b = n / 121, m = n - b * 121;
  VBt[(size_t)b * 32768 + (size_t)t * 128 + m] = f2bf(sum);
}

// ---------------------------------------------------------------- MFMA attention (+fused Q-proj) + LN + residual
__global__ __launch_bounds__(512, 2)
void attn_k(const unsigned short* __restrict__ Qsrc, int qmode,
            const unsigned short* __restrict__ wq, const float* __restrict__ qb,
            const float* __restrict__ Kbuf,
            const unsigned short* __restrict__ VBt,
            const unsigned short* __restrict__ Xpad, int resChOff,
            unsigned short* __restrict__ FusPad, int outChOff,
            const float* __restrict__ ng, const float* __restrict__ nbv,
            const float* __restrict__ gammap)
{
  __shared__ unsigned short Vt[2][256][64];
  __shared__ unsigned short Pl[2][128][64];
  __shared__ unsigned short Qs[128][64];
  __shared__ unsigned short Ks[128][64];
  __shared__ unsigned short Wqs[32][256];

  const int t = threadIdx.x;
  const int lane = t & 63;
  const int w = t >> 6;
  const int c15 = lane & 15;
  const int h = lane >> 4;

  const int bid = blockIdx.x;
  const int b = bid / 61;
  const int rb = bid - b * 61;
  const int nb0 = rb * 128;

  const unsigned short* vsrc = VBt + (size_t)b * 32768;
  #pragma unroll
  for (int kt = 0; kt < 2; ++kt)
    #pragma unroll
    for (int i = 0; i < 4; ++i){
      int rowbase = i * 64 + w * 8;
      int c = rowbase + (lane >> 3);
      int mchunk = (lane & 7) ^ (c & 7);
      __builtin_amdgcn_global_load_lds(
        (AS1 void*)(vsrc + (size_t)c * 128 + kt * 64 + mchunk * 8),
        (AS3 void*)(&Vt[kt][rowbase][0]),
        16, 0, 0);
    }

  {
    uint4* d = (uint4*)&Wqs[0][0]; const uint4* s = (const uint4*)wq;
    d[t] = s[t];
    d[t + 512] = s[t + 512];
  }
  {
    int m = t >> 2, part = t & 3;
    union { uint4 v; unsigned short s_[8]; } u;
    u.v = uint4{0, 0, 0, 0};
    if (m < 121){
      const float* kp = Kbuf + ((size_t)b * 121 + m) * 32 + part * 8;
      float4 a = *reinterpret_cast<const float4*>(kp);
      float4 bb = *reinterpret_cast<const float4*>(kp + 4);
      u.s_[0] = f2bf(a.x); u.s_[1] = f2bf(a.y); u.s_[2] = f2bf(a.z); u.s_[3] = f2bf(a.w);
      u.s_[4] = f2bf(bb.x); u.s_[5] = f2bf(bb.y); u.s_[6] = f2bf(bb.z); u.s_[7] = f2bf(bb.w);
    }
    *reinterpret_cast<uint4*>(&Ks[m][(part ^ (m & 7)) * 8]) = u.v;
  }
  __syncthreads();

  const int nA = w * 16 + c15;
  const float scale = 0.17677669529663687f;  // 32^-0.5

  {
    int gn = nb0 + nA; if (gn > 7743) gn = 7743;
    const unsigned short* xrow;
    if (qmode){
      int y = gn / 88, x = gn - y * 88;
      xrow = Qsrc + (((size_t)(b * 90) + y + 1) * 90 + (x + 1)) * 512;
    } else {
      xrow = Qsrc + ((size_t)b * 7744 + gn) * 256;
    }
    f32x4 qacc[2];
    qacc[0] = f32x4{0.f, 0.f, 0.f, 0.f};
    qacc[1] = f32x4{0.f, 0.f, 0.f, 0.f};
    #pragma unroll
    for (int kt = 0; kt < 8; ++kt){
      bf16x8 ax = *reinterpret_cast<const bf16x8*>(xrow + kt * 32 + h * 8);
      #pragma unroll
      for (int ni = 0; ni < 2; ++ni){
        int co = ni * 16 + c15;
        bf16x8 bw = *reinterpret_cast<const bf16x8*>(&Wqs[co][((kt * 4 + h) ^ (co & 7)) * 8]);
        qacc[ni] = __builtin_amdgcn_mfma_f32_16x16x32_bf16(ax, bw, qacc[ni], 0, 0, 0);
      }
    }
    #pragma unroll
    for (int ni = 0; ni < 2; ++ni){
      int co = ni * 16 + c15;
      float bq = qb[co];
      #pragma unroll
      for (int r = 0; r < 4; ++r){
        int n = w * 16 + 4 * h + r;
        int chunk = (co >> 3) ^ (n & 7);
        Qs[n][chunk * 8 + (co & 7)] = f2bf((qacc[ni][r] + bq) * scale);
      }
    }
  }

  bf16x8 aq = *reinterpret_cast<const bf16x8*>(&Qs[nA][(h ^ (nA & 7)) * 8]);
  f32x4 sv[8];
  #pragma unroll
  for (int ni = 0; ni < 8; ++ni){
    int mrow = ni * 16 + c15;
    bf16x8 bk = *reinterpret_cast<const bf16x8*>(&Ks[mrow][(h ^ (mrow & 7)) * 8]);
    sv[ni] = __builtin_amdgcn_mfma_f32_16x16x32_bf16(aq, bk, f32x4{0.f,0.f,0.f,0.f}, 0, 0, 0);
  }
  if (c15 >= 9) sv[7] = f32x4{-1e30f, -1e30f, -1e30f, -1e30f};

  float rden[4];
  #pragma unroll
  for (int r = 0; r < 4; ++r){
    float mx = sv[0][r];
    #pragma unroll
    for (int ni = 1; ni < 8; ++ni) mx = fmaxf(mx, sv[ni][r]);
    #pragma unroll
    for (int o = 1; o < 16; o <<= 1) mx = fmaxf(mx, __shfl_xor(mx, o, 64));
    float sm = 0.f;
    #pragma unroll
    for (int ni = 0; ni < 8; ++ni){
      float p = __expf(sv[ni][r] - mx);
      sv[ni][r] = p;
      sm += p;
    }
    #pragma unroll
    for (int o = 1; o < 16; o <<= 1) sm += __shfl_xor(sm, o, 64);
    rden[r] = 1.f / sm;
  }
  #pragma unroll
  for (int ni = 0; ni < 8; ++ni){
    int m = ni * 16 + c15;
    int kt = m >> 6;
    int mq = (m & 63) >> 3;
    #pragma unroll
    for (int r = 0; r < 4; ++r){
      int n = w * 16 + 4 * h + r;
      Pl[kt][n][(mq ^ (n & 7)) * 8 + (m & 7)] = f2bf(sv[ni][r] * rden[r]);
    }
  }

  bf16x8 pa[2][2];
  #pragma unroll
  for (int kt = 0; kt < 2; ++kt)
    #pragma unroll
    for (int ks = 0; ks < 2; ++ks)
      pa[kt][ks] = *reinterpret_cast<const bf16x8*>(&Pl[kt][nA][((ks * 4 + h) ^ (nA & 7)) * 8]);

  f32x4 acc[16];
  #pragma unroll
  for (int ni = 0; ni < 16; ++ni) acc[ni] = f32x4{0.f, 0.f, 0.f, 0.f};
  #pragma unroll
  for (int ni = 0; ni < 16; ++ni){
    int crow = ni * 16 + c15;
    #pragma unroll
    for (int kt = 0; kt < 2; ++kt)
      #pragma unroll
      for (int ks = 0; ks < 2; ++ks){
        bf16x8 bv = *reinterpret_cast<const bf16x8*>(&Vt[kt][crow][((ks * 4 + h) ^ (crow & 7)) * 8]);
        acc[ni] = __builtin_amdgcn_mfma_f32_16x16x32_bf16(pa[kt][ks], bv, acc[ni], 0, 0, 0);
      }
  }

  float ngv[16], nbb[16];
  #pragma unroll
  for (int ni = 0; ni < 16; ++ni){
    int c = ni * 16 + c15;
    ngv[ni] = ng[c]; nbb[ni] = nbv[c];
  }
  float g = gammap[0]; g = fminf(fmaxf(g, 0.f), 1.f);

  #pragma unroll
  for (int r = 0; r < 4; ++r){
    float s1 = 0.f, s2 = 0.f;
    #pragma unroll
    for (int ni = 0; ni < 16; ++ni){ float v = acc[ni][r]; s1 += v; s2 += v * v; }
    #pragma unroll
    for (int o = 1; o < 16; o <<= 1){ s1 += __shfl_xor(s1, o, 64); s2 += __shfl_xor(s2, o, 64); }
    float mean = s1 * (1.f / 256.f);
    float var = s2 * (1.f / 256.f) - mean * mean;
    float rstd = rsqrtf(var + 1e-5f);

    int nloc = w * 16 + 4 * h + r;
    int rix = nb0 + nloc;
    if (rix < 7744){
      int y = rix / 88, x = rix - y * 88;
      size_t pix = ((size_t)(b * 90) + y + 1) * 90 + (x + 1);
      const unsigned short* res = Xpad + pix * 512 + resChOff;
      unsigned short* outp = FusPad + pix * 576 + outChOff;
      #pragma unroll
      for (int ni = 0; ni < 16; ++ni){
        int c = ni * 16 + c15;
        float yv = (acc[ni][r] - mean) * rstd * ngv[ni] + nbb[ni];
        outp[c] = f2bf(bf2f(res[c]) + g * yv);
      }
    }
  }
}

// ================================================================ host
extern "C" void kernel_launch(void* const* d_in, const int* in_sizes, int n_in,
                              void* d_out, int out_size, void* d_ws, size_t ws_size,
                              hipStream_t stream)
{
  const float* P[42];
  for (int i = 0; i < 42; ++i) P[i] = (const float*)d_in[i];

  char* ws = (char*)d_ws;
  size_t off = 0;
  auto take = [&](size_t bytes) -> char* {
    char* p = ws + off; off += (bytes + 255) & ~(size_t)255; return p;
  };
  unsigned short* XPAD = (unsigned short*)take(8ull * 8100 * 512 * 2);   // 66.4 MB
  unsigned short* FUSP = (unsigned short*)take(8ull * 8100 * 576 * 2);   // 74.6 MB
  unsigned short* H1   = (unsigned short*)take(61952ull * 256 * 2);      // 31.7 MB
  unsigned short* FDM  = H1;  // alias: h1 dead after mask_k
  unsigned short* W1T  = (unsigned short*)take(9ull * 256 * 512 * 2);
  unsigned short* WFT  = (unsigned short*)take(9ull * 256 * 576 * 2);
  unsigned short* WSRA = (unsigned short*)take(64ull * 256 * 256 * 2);
  unsigned short* WSRB = (unsigned short*)take(64ull * 256 * 256 * 2);
  float* PART = (float*)take(16ull * 968 * 256 * 4);                      // 15.9 MB
  unsigned short* KVR = (unsigned short*)take(968ull * 256 * 2);
  float* KB   = (float*)take(968ull * 32 * 4);
  unsigned short* VBT = (unsigned short*)take(8ull * 256 * 128 * 2);      // 512 KB
  float* MASK = (float*)take(61952ull * 4);
  float* SC1 = (float*)take(256 * 4);
  float* SH1 = (float*)take(256 * 4);
  float* SCF = (float*)take(256 * 4);
  float* SHF = (float*)take(256 * 4);
  unsigned short* WQSA = (unsigned short*)take(32ull * 256 * 2);
  unsigned short* WQSB = (unsigned short*)take(32ull * 256 * 2);
  unsigned short* KWTA = (unsigned short*)take(256ull * 32 * 2);
  unsigned short* VWTA = (unsigned short*)take(256ull * 256 * 2);
  unsigned short* KWTB = (unsigned short*)take(256ull * 32 * 2);
  unsigned short* VWTB = (unsigned short*)take(256ull * 256 * 2);
  (void)ws_size; (void)in_sizes; (void)n_in; (void)out_size;

  zero_border_k<<<8 * 356, 128, 0, stream>>>(XPAD, 512);
  zero_border_k<<<8 * 356, 128, 0, stream>>>(FUSP, 576);
  zero_fustail_k<<<1936, 256, 0, stream>>>(FUSP);
  hipMemsetAsync(VBT, 0, 8ull * 256 * 128 * 2, stream);

  bnprep_k<<<1, 256, 0, stream>>>(P[4], P[5], P[6], P[7], P[3],
                                  P[38], P[39], P[40], P[41], P[37],
                                  SC1, SH1, SCF, SHF);
  prep_xpad_k<<<7744, 256, 0, stream>>>(P[0], P[1], XPAD);
  prep_w1t_k<<<256, 256, 0, stream>>>(P[2], W1T);
  prep_wfus_k<<<256, 256, 0, stream>>>(P[36], WFT);
  prep_wsr_k<<<256, 256, 0, stream>>>(P[16], WSRA);
  prep_wsr_k<<<256, 256, 0, stream>>>(P[28], WSRB);
  wqprep_k<<<32, 256, 0, stream>>>(P[10], WQSA);
  wqprep_k<<<32, 256, 0, stream>>>(P[22], WQSB);
  tranw_k<<<8, 256, 0, stream>>>(P[12], KWTA, 32, 256);
  tranw_k<<<64, 256, 0, stream>>>(P[14], VWTA, 256, 256);
  tranw_k<<<8, 256, 0, stream>>>(P[24], KWTB, 32, 256);
  tranw_k<<<64, 256, 0, stream>>>(P[26], VWTB, 256, 256);

  // conv1 3x3 (512->256) + BN + ReLU -> h1 NHWC bf16   [256^2 8-phase kernel]
  GemmP g1{};
  g1.A = XPAD; g1.W = W1T; g1.ep_scale = SC1; g1.ep_shift = SH1; g1.out = H1;
  g1.img_px = 8100; g1.row_px = 90; g1.px_el = 512; g1.ch_off = 0; g1.y0 = 0; g1.x0 = 0;
  g1.tapw = 3; g1.stridepix = 1; g1.out_w = 88; g1.out_imgpx = 7744;
  g1.Cin = 512; g1.Mtot = 61952; g1.Mtiles = 242; g1.Ntiles = 1; g1.k_per = 4608;
  gemm256_k<0><<<242, 512, 0, stream>>>(g1);

  mask_k<<<242, 256, 0, stream>>>(H1, P[8], P[9], MASK, FUSP);
  fdm_k<<<7744, 256, 0, stream>>>(XPAD, MASK, FDM);

  // ---------------- d2r: Q from f_rgb (XPAD rgb), KV from f_depth_masked ----------------
  GemmP gs{};
  gs.A = FDM; gs.W = WSRA; gs.out = PART;
  gs.img_px = 7744; gs.row_px = 88; gs.px_el = 256; gs.ch_off = 0; gs.y0 = 0; gs.x0 = 0;
  gs.tapw = 8; gs.stridepix = 8; gs.out_w = 11; gs.out_imgpx = 121;
  gs.Cin = 256; gs.Mtot = 968; gs.Mtiles = 8; gs.Ntiles = 2; gs.k_per = 1024;
  gemm_k<2><<<256, 256, 0, stream>>>(gs);
  lnkvr_k<<<968, 256, 0, stream>>>(PART, P[17], P[18], P[19], KVR);
  dotconv_k<<<121, 256, 0, stream>>>(KVR, KWTA, P[13], KB);
  vconv_k<<<968, 256, 0, stream>>>(KVR, VWTA, P[15], VBT);
  attn_k<<<488, 512, 0, stream>>>(XPAD, 1, WQSA, P[11], KB, VBT, XPAD, 0,
                                  FUSP, 0, P[20], P[21], P[34]);

  // ---------------- r2d: Q from f_depth_masked (FDM), KV from f_rgb ----------------
  gs.A = XPAD; gs.W = WSRB;
  gs.img_px = 8100; gs.row_px = 90; gs.px_el = 512; gs.y0 = 1; gs.x0 = 1;
  gemm_k<2><<<256, 256, 0, stream>>>(gs);
  lnkvr_k<<<968, 256, 0, stream>>>(PART, P[29], P[30], P[31], KVR);
  dotconv_k<<<121, 256, 0, stream>>>(KVR, KWTB, P[25], KB);
  vconv_k<<<968, 256, 0, stream>>>(KVR, VWTB, P[27], VBT);
  attn_k<<<488, 512, 0, stream>>>(FDM, 0, WQSB, P[23], KB, VBT, XPAD, 256,
                                  FUSP, 256, P[32], P[33], P[35]);

  // final fused conv 3x3 (576->256) + BN + ReLU -> d_out f32 NCHW   [256^2 8-phase kernel]
  GemmP gf{};
  gf.A = FUSP; gf.W = WFT; gf.ep_scale = SCF; gf.ep_shift = SHF; gf.out = d_out;
  gf.img_px = 8100; gf.row_px = 90; gf.px_el = 576; gf.ch_off = 0; gf.y0 = 0; gf.x0 = 0;
  gf.tapw = 3; gf.stridepix = 1; gf.out_w = 88; gf.out_imgpx = 7744;
  gf.Cin = 576; gf.Mtot = 61952; gf.Mtiles = 242; gf.Ntiles = 1; gf.k_per = 5184;
  gemm256_k<1><<<242, 512, 0, stream>>>(gf);
}

// Round 10
// 547.271 us; speedup vs baseline: 4.7277x; 1.0097x over previous
//
#include <hip/hip_runtime.h>
#include <hip/hip_bf16.h>

// BiDirectionalFusionModule on MI355X.
// R2: global_load_lds(16B) GEMM staging; coalesced weight preps.
// R5: MFMA attention (8 waves, wave-local softmax/LN, swizzled LDS, V via lds-DMA).
// R6: GEMM L2-locality (cib-outer/tap-inner, XCD chunk swizzle): FETCH 574->60MB.
// R7: Q-proj fused into attn_k; targeted border/tail zeroing.
// R9: 8-phase 256^2 GEMM (T3+T4+T5) for the two big convs: 553us, MfmaUtil 36%.
// R10: template-faithful phase schedule (ds_reads between barrier pairs, STG
//      pairs 0+1 at ph0 w/ vmcnt(4)); d2r/r2d tails merged into 4 launches
//      (SR-gemm x1, lnkvr x1, vconv+Kproj x1, attn x1).

typedef __bf16 bf16x8 __attribute__((ext_vector_type(8)));
typedef float f32x4 __attribute__((ext_vector_type(4)));

#define AS1 __attribute__((address_space(1)))
#define AS3 __attribute__((address_space(3)))
#define DEVI __device__ __forceinline__
#define BARRIER() do { asm volatile("" ::: "memory"); __builtin_amdgcn_s_barrier(); asm volatile("" ::: "memory"); } while (0)

DEVI float bf2f(unsigned short u){
  union { unsigned int i; float f; } v; v.i = ((unsigned int)u) << 16; return v.f;
}
DEVI unsigned short f2bf(float f){
  union { float f; unsigned int i; } v; v.f = f;
  unsigned int x = v.i;
  unsigned int r = (x + 0x7fffu + ((x >> 16) & 1u)) >> 16;
  return (unsigned short)r;
}

// ---------------------------------------------------------------- BN prep
__global__ void bnprep_k(const float* __restrict__ g1, const float* __restrict__ be1,
                         const float* __restrict__ m1, const float* __restrict__ v1,
                         const float* __restrict__ b1,
                         const float* __restrict__ gf, const float* __restrict__ bef,
                         const float* __restrict__ mf, const float* __restrict__ vf,
                         const float* __restrict__ bf,
                         float* __restrict__ sc1, float* __restrict__ sh1,
                         float* __restrict__ scf, float* __restrict__ shf)
{
  int c = threadIdx.x;
  float s = g1[c] * rsqrtf(v1[c] + 1e-5f);
  sc1[c] = s; sh1[c] = (b1[c] - m1[c]) * s + be1[c];
  s = gf[c] * rsqrtf(vf[c] + 1e-5f);
  scf[c] = s; shf[c] = (bf[c] - mf[c]) * s + bef[c];
}

// ---------------------------------------------------------------- targeted zeroing
__global__ __launch_bounds__(128)
void zero_border_k(unsigned short* __restrict__ buf, int px_el)
{
  int bi = blockIdx.x;
  int img = bi / 356, e = bi - img * 356;
  int y, x;
  if (e < 90){ y = 0; x = e; }
  else if (e < 180){ y = 89; x = e - 90; }
  else if (e < 268){ y = e - 180 + 1; x = 0; }
  else { y = e - 268 + 1; x = 89; }
  size_t pix = ((size_t)img * 90 + y) * 90 + x;
  int t = threadIdx.x;
  if (t < (px_el >> 3))
    *reinterpret_cast<uint4*>(buf + pix * px_el + t * 8) = uint4{0, 0, 0, 0};
}
__global__ __launch_bounds__(256)
void zero_fustail_k(unsigned short* __restrict__ FusPad)
{
  int idx = blockIdx.x * 256 + threadIdx.x;   // 61952*8
  int n = idx >> 3, ch = idx & 7;
  int b = n / 7744, s = n - b * 7744;
  int y = s / 88, x = s - y * 88;
  size_t pix = ((size_t)(b * 90 + y + 1)) * 90 + (x + 1);
  *reinterpret_cast<uint4*>(FusPad + pix * 576 + 512 + ch * 8) = uint4{0, 0, 0, 0};
}

// ------------------------------------------------- NCHW f32 -> padded NHWC bf16
__global__ __launch_bounds__(256)
void prep_xpad_k(const float* __restrict__ rgb, const float* __restrict__ dep,
                 unsigned short* __restrict__ Xpad)
{
  __shared__ unsigned short tile[64][65];
  int bi = blockIdx.x;
  int b = bi / 968;
  int rem = bi - b * 968;
  int cblk = rem / 121;
  int pblk = rem - cblk * 121;
  int t = threadIdx.x;
  int pl = t & 63;
  #pragma unroll
  for (int pass = 0; pass < 16; ++pass){
    int cl = pass * 4 + (t >> 6);
    int c = cblk * 64 + cl;
    const float* sp = (c < 256) ? (rgb + ((size_t)b * 256 + c) * 7744)
                                : (dep + ((size_t)b * 256 + (c - 256)) * 7744);
    tile[cl][pl] = f2bf(sp[pblk * 64 + pl]);
  }
  __syncthreads();
  int cl2 = t & 63;
  for (int pass = 0; pass < 16; ++pass){
    int pl2 = pass * 4 + (t >> 6);
    int pixg = pblk * 64 + pl2;
    int y = pixg / 88, x = pixg - y * 88;
    Xpad[(((size_t)b * 90 + y + 1) * 90 + (x + 1)) * 512 + cblk * 64 + cl2] = tile[cl2][pl2];
  }
}

// ---------------------------------------------------------------- weight reshuffles
__global__ __launch_bounds__(256)
void prep_w1t_k(const float* __restrict__ w, unsigned short* __restrict__ o)
{
  int co = blockIdx.x, t = threadIdx.x;
  const float* src = w + (size_t)co * 4608 + t * 18;
  unsigned int* op = (unsigned int*)o;
  #pragma unroll
  for (int k = 0; k < 9; ++k){
    unsigned short lo = f2bf(src[k]);
    unsigned short hi = f2bf(src[9 + k]);
    op[((size_t)k * 256 + co) * 256 + t] = lo | ((unsigned int)hi << 16);
  }
}
__global__ __launch_bounds__(256)
void prep_wfus_k(const float* __restrict__ w, unsigned short* __restrict__ o)
{
  int co = blockIdx.x, t = threadIdx.x;
  const float* src = w + (size_t)co * 4617 + t * 18;
  unsigned int* op = (unsigned int*)o;
  #pragma unroll
  for (int k = 0; k < 9; ++k){
    unsigned short lo = f2bf(src[k]);
    unsigned short hi = f2bf(src[9 + k]);
    op[((size_t)k * 256 + co) * 288 + t] = lo | ((unsigned int)hi << 16);
  }
  if (t < 32){
    #pragma unroll
    for (int k = 0; k < 9; ++k){
      unsigned int val = 0;
      if (t == 0) val = (unsigned int)f2bf(w[(size_t)co * 4617 + 512 * 9 + k]);
      op[((size_t)k * 256 + co) * 288 + 256 + t] = val;
    }
  }
}
__global__ __launch_bounds__(256)
void prep_wsr_k(const float* __restrict__ w, unsigned short* __restrict__ o)
{
  __shared__ float ld[64][65];
  int co = blockIdx.x;
  int t = threadIdx.x;
  for (int cib = 0; cib < 256; cib += 64){
    int cil = t >> 2, tq = t & 3;
    const float* src = w + ((size_t)co * 256 + cib + cil) * 64 + tq * 16;
    float v[16];
    #pragma unroll
    for (int k = 0; k < 16; ++k) v[k] = src[k];
    __syncthreads();
    #pragma unroll
    for (int k = 0; k < 16; ++k) ld[cil][tq * 16 + k] = v[k];
    __syncthreads();
    #pragma unroll
    for (int tp = 0; tp < 16; ++tp){
      int tap = tp * 4 + (t >> 6);
      int ci = t & 63;
      o[((size_t)tap * 256 + co) * 256 + cib + ci] = f2bf(ld[ci][tap]);
    }
  }
}
__global__ __launch_bounds__(256)
void tranw_k(const float* __restrict__ in, unsigned short* __restrict__ out, int R, int C)
{
  __shared__ float tl[32][33];
  int tiles_c = C >> 5;
  int tr = (blockIdx.x / tiles_c) << 5, tc = (blockIdx.x % tiles_c) << 5;
  int t = threadIdx.x; int r = t >> 5, c = t & 31;
  #pragma unroll
  for (int p = 0; p < 4; ++p)
    tl[r + p * 8][c] = in[(size_t)(tr + r + p * 8) * C + tc + c];
  __syncthreads();
  #pragma unroll
  for (int p = 0; p < 4; ++p)
    out[(size_t)(tc + r + p * 8) * R + tr + c] = f2bf(tl[c][r + p * 8]);
}
__global__ __launch_bounds__(256)
void wqprep_k(const float* __restrict__ w, unsigned short* __restrict__ o)
{
  int co = blockIdx.x, t = threadIdx.x;
  int c = t >> 3, e = t & 7;
  o[co * 256 + ((c ^ (co & 7)) * 8) + e] = f2bf(w[co * 256 + t]);
}

// ---------------------------------------------------------------- GEMM params
struct GemmP {
  const unsigned short* A;
  const unsigned short* W;
  const float* ep_scale;
  const float* ep_shift;
  void* out;
  int img_px, row_px, px_el, ch_off, y0, x0;
  int tapw, stridepix, out_w, out_imgpx;
  int Cin, Mtot, Mtiles, Ntiles, k_per;
};

// ---------------------------------------------------------------- merged SR conv GEMM (f32 partials)
// 256 blocks: swizzled pid < 128 -> side A (d2r), else side B (r2d). 8 slots x 16 tiles each.
__global__ __launch_bounds__(256)
void gemm_sr_k(GemmP pa, GemmP pb, float* __restrict__ outA, float* __restrict__ outB)
{
  const int t = threadIdx.x;
  const int lane = t & 63;
  const int wid = t >> 6;
  const int wr = wid >> 1, wc = wid & 1;

  const int cpx = gridDim.x >> 3;
  int pid = (blockIdx.x & 7) * cpx + (blockIdx.x >> 3);
  const int side = pid >= 128;
  const GemmP& p = side ? pb : pa;
  float* outp = side ? outB : outA;
  pid &= 127;

  __shared__ __bf16 As[2][128 * 64];
  __shared__ __bf16 Bs[2][128 * 64];

  const int mn = p.Mtiles * p.Ntiles;   // 16
  int within = pid % mn;
  int slot = pid / mn;                  // 0..7
  int mt = within / p.Ntiles;
  int nt = within - mt * p.Ntiles;
  int kb = slot * p.k_per;
  int tap0 = kb / p.Cin;
  int ntap = p.k_per / p.Cin;           // 8

  long long apix[4]; int cbg8[4]; int wrow[4];
  #pragma unroll
  for (int i = 0; i < 4; ++i){
    int r = i * 32 + (t >> 3);
    cbg8[i] = ((t & 7) ^ (r & 7)) * 8;
    int n = mt * 128 + r;
    int nc = n < p.Mtot ? n : 0;
    int b = nc / p.out_imgpx; int rr = nc - b * p.out_imgpx;
    int yo = rr / p.out_w;    int xo = rr - yo * p.out_w;
    apix[i] = (long long)b * p.img_px + (long long)(yo * p.stridepix + p.y0) * p.row_px
            + (xo * p.stridepix + p.x0);
    wrow[i] = (nt * 128 + r) * p.Cin + cbg8[i];
  }

  f32x4 acc[4][4];
  #pragma unroll
  for (int i = 0; i < 4; ++i)
    #pragma unroll
    for (int j = 0; j < 4; ++j)
      acc[i][j] = f32x4{0.f, 0.f, 0.f, 0.f};

  const long long wstap = 256LL * p.Cin;

  auto STAGE = [&](int buf, int tap, int cib){
    int dy = tap / p.tapw, dx = tap - dy * p.tapw;
    const unsigned short* wb = p.W + (long long)tap * wstap + cib;
    const long long aoff = (long long)(dy * p.row_px + dx) * p.px_el + p.ch_off + cib;
    #pragma unroll
    for (int i = 0; i < 4; ++i){
      __builtin_amdgcn_global_load_lds(
          (AS1 void*)(p.A + apix[i] * p.px_el + aoff + cbg8[i]),
          (AS3 void*)(&As[buf][i * 2048 + wid * 512]),
          16, 0, 0);
      __builtin_amdgcn_global_load_lds(
          (AS1 void*)(wb + wrow[i]),
          (AS3 void*)(&Bs[buf][i * 2048 + wid * 512]),
          16, 0, 0);
    }
  };

  const int NT = (p.Cin >> 6) * ntap;
  STAGE(0, tap0, 0);
  int tpn = 1, tap_n = tap0 + 1, cib_n = 0;
  int cur = 0;

  for (int kt = 0; kt < NT; ++kt){
    if (kt + 1 < NT){
      STAGE(cur ^ 1, tap_n, cib_n);
      ++tpn; ++tap_n;
      if (tpn == ntap){ tpn = 0; tap_n = tap0; cib_n += 64; }
      asm volatile("s_waitcnt vmcnt(8)" ::: "memory");
    } else {
      asm volatile("s_waitcnt vmcnt(0)" ::: "memory");
    }
    __builtin_amdgcn_s_barrier();
    __builtin_amdgcn_sched_barrier(0);

    #pragma unroll
    for (int ks = 0; ks < 2; ++ks){
      bf16x8 av[4], bv[4];
      #pragma unroll
      for (int mi = 0; mi < 4; ++mi){
        int ar = wr * 64 + mi * 16 + (lane & 15);
        int cb = (ks * 4 + (lane >> 4)) ^ (ar & 7);
        av[mi] = *reinterpret_cast<const bf16x8*>(&As[cur][ar * 64 + cb * 8]);
      }
      #pragma unroll
      for (int ni = 0; ni < 4; ++ni){
        int br = wc * 64 + ni * 16 + (lane & 15);
        int cb = (ks * 4 + (lane >> 4)) ^ (br & 7);
        bv[ni] = *reinterpret_cast<const bf16x8*>(&Bs[cur][br * 64 + cb * 8]);
      }
      #pragma unroll
      for (int mi = 0; mi < 4; ++mi)
        #pragma unroll
        for (int ni = 0; ni < 4; ++ni)
          acc[mi][ni] = __builtin_amdgcn_mfma_f32_16x16x32_bf16(av[mi], bv[ni], acc[mi][ni], 0, 0, 0);
    }

    __builtin_amdgcn_sched_barrier(0);
    __builtin_amdgcn_s_barrier();
    cur ^= 1;
  }

  const int r0 = (lane >> 4) * 4;
  const int c0 = lane & 15;
  #pragma unroll
  for (int mi = 0; mi < 4; ++mi){
    int nbase = mt * 128 + wr * 64 + mi * 16 + r0;
    #pragma unroll
    for (int ni = 0; ni < 4; ++ni){
      int co = nt * 128 + wc * 64 + ni * 16 + c0;
      f32x4 a = acc[mi][ni];
      float* o = outp + (size_t)slot * 968 * 256;
      #pragma unroll
      for (int r = 0; r < 4; ++r){
        int n = nbase + r;
        if (n < p.Mtot) o[(size_t)n * 256 + co] = a[r];
      }
    }
  }
}

// ---------------------------------------------------------------- 256^2 8-phase GEMM (big convs)
// R10 schedule: ds_reads for phase p+1 between phase p's close and p+1's open
// barriers; STG pairs 0+1 at ph0 (vmcnt(4)), pair 2 after ph0, pair 3 after ph2.
template<int EPI>   // 0: BN+ReLU -> bf16 NHWC[.][256]   1: BN+ReLU -> f32 NCHW
__global__ __launch_bounds__(512, 2)
void gemm256_k(GemmP p)
{
  __shared__ __bf16 As[2][256 * 64];
  __shared__ __bf16 Bs[2][256 * 64];
  const int t = threadIdx.x;
  const int lane = t & 63;
  const int w = t >> 6;
  const int wr = w >> 2, wc = w & 3;
  const int c15 = lane & 15;
  const int h = lane >> 4;

  // bijective chunked XCD swizzle (m204)
  const int nwg = gridDim.x;
  const int q = nwg >> 3, r8 = nwg & 7;
  const int bid = blockIdx.x;
  const int xcd = bid & 7;
  const int mt = (xcd < r8 ? xcd * (q + 1) : r8 * (q + 1) + (xcd - r8) * q) + (bid >> 3);

  long long apixel[4];
  const unsigned short* wsrc[4];
  int lbase[4];
  #pragma unroll
  for (int i = 0; i < 4; ++i){
    int r = i * 64 + (t >> 3);
    int cb = ((t & 7) ^ (r & 7)) * 8;
    int n = mt * 256 + r;                   // Mtot = 242*256 exactly
    int b = n / p.out_imgpx; int rr = n - b * p.out_imgpx;
    int yo = rr / p.out_w;   int xo = rr - yo * p.out_w;
    long long pix = (long long)b * p.img_px + (long long)(yo * p.stridepix + p.y0) * p.row_px
                  + (xo * p.stridepix + p.x0);
    apixel[i] = pix * p.px_el + p.ch_off + cb;
    wsrc[i] = p.W + (long long)r * p.Cin + cb;
    lbase[i] = i * 4096 + w * 512;
  }

  f32x4 acc[8][4];
  #pragma unroll
  for (int i = 0; i < 8; ++i)
    #pragma unroll
    for (int j = 0; j < 4; ++j)
      acc[i][j] = f32x4{0.f, 0.f, 0.f, 0.f};

  const long long wstap = 256LL * p.Cin;
  const int ntap = p.k_per / p.Cin;         // 9
  const int NT = (p.Cin >> 6) * ntap;       // 72 or 81

  auto STG = [&](int buf, int i, long long aoff, long long woff){
    __builtin_amdgcn_global_load_lds(
        (AS1 void*)(p.A + apixel[i] + aoff),
        (AS3 void*)(&As[buf][lbase[i]]), 16, 0, 0);
    __builtin_amdgcn_global_load_lds(
        (AS1 void*)(wsrc[i] + woff),
        (AS3 void*)(&Bs[buf][lbase[i]]), 16, 0, 0);
  };
  auto LDA = [&](bf16x8* av, int mi0, int ks, int buf){
    #pragma unroll
    for (int m = 0; m < 4; ++m){
      int ar = wr * 128 + (mi0 + m) * 16 + c15;
      int cb = (ks * 4 + h) ^ (ar & 7);
      av[m] = *reinterpret_cast<const bf16x8*>(&As[buf][ar * 64 + cb * 8]);
    }
  };
  auto LDB = [&](bf16x8* bv, int ks, int buf){
    #pragma unroll
    for (int n = 0; n < 4; ++n){
      int br = wc * 64 + n * 16 + c15;
      int cb = (ks * 4 + h) ^ (br & 7);
      bv[n] = *reinterpret_cast<const bf16x8*>(&Bs[buf][br * 64 + cb * 8]);
    }
  };
  auto MM = [&](bf16x8* av, bf16x8* bv, int mi0){
    __builtin_amdgcn_s_setprio(1);
    #pragma unroll
    for (int m = 0; m < 4; ++m)
      #pragma unroll
      for (int n = 0; n < 4; ++n)
        acc[mi0 + m][n] = __builtin_amdgcn_mfma_f32_16x16x32_bf16(av[m], bv[n], acc[mi0 + m][n], 0, 0, 0);
    __builtin_amdgcn_s_setprio(0);
  };

  // prologue: stage kt=0 fully
  #pragma unroll
  for (int i = 0; i < 4; ++i) STG(0, i, 0, 0);

  int tap_n = 1, cib_n = 0;
  int cur = 0;
  bf16x8 A0[4], A1[4], B0[4], B1[4];

  for (int kt = 0; kt < NT; ++kt){
    const bool last = (kt == NT - 1);
    long long aoff_n = 0, woff_n = 0;
    if (!last){
      int dy = tap_n / p.tapw, dx = tap_n - dy * p.tapw;
      aoff_n = (long long)(dy * p.row_px + dx) * p.px_el + cib_n;
      woff_n = (long long)tap_n * wstap + cib_n;
    }

    // ---- phase 0: STG pairs 0+1, counted wait, validate buf, compute mi0-3 ks0 ----
    if (!last){
      STG(cur ^ 1, 0, aoff_n, woff_n);
      STG(cur ^ 1, 1, aoff_n, woff_n);
      asm volatile("s_waitcnt vmcnt(4)" ::: "memory");   // kt's 8 loads done; kt+1 pair0+1 in flight
    } else {
      asm volatile("s_waitcnt vmcnt(0)" ::: "memory");
    }
    BARRIER();                       // open ph0 (buf[cur] valid)
    LDA(A0, 0, 0, cur); LDB(B0, 0, cur);
    MM(A0, B0, 0);
    BARRIER();                       // close ph0
    // ---- gap: ph1 ds-reads + STG pair 2 ----
    LDA(A1, 4, 0, cur);
    if (!last) STG(cur ^ 1, 2, aoff_n, woff_n);
    BARRIER();                       // open ph1
    MM(A1, B0, 4);
    BARRIER();                       // close ph1
    // ---- gap: ph2 ds-reads + STG pair 3 ----
    LDA(A0, 0, 1, cur); LDB(B1, 1, cur);
    if (!last) STG(cur ^ 1, 3, aoff_n, woff_n);
    BARRIER();                       // open ph2
    MM(A0, B1, 0);
    BARRIER();                       // close ph2
    // ---- gap: ph3 ds-reads ----
    LDA(A1, 4, 1, cur);
    BARRIER();                       // open ph3
    MM(A1, B1, 4);
    BARRIER();                       // close ph3 (all reads of buf[cur] done)

    cur ^= 1;
    if (!last){ ++tap_n; if (tap_n == ntap){ tap_n = 0; cib_n += 64; } }
  }

  // ---- epilogue ----
  const int r0 = (lane >> 4) * 4;
  #pragma unroll
  for (int mi = 0; mi < 8; ++mi){
    int nbase = mt * 256 + wr * 128 + mi * 16 + r0;
    #pragma unroll
    for (int ni = 0; ni < 4; ++ni){
      int co = wc * 64 + ni * 16 + c15;
      f32x4 a = acc[mi][ni];
      if constexpr (EPI == 0){
        float sc = p.ep_scale[co], sh = p.ep_shift[co];
        unsigned short* o = (unsigned short*)p.out;
        #pragma unroll
        for (int r = 0; r < 4; ++r){
          float v = fmaf(a[r], sc, sh); v = v > 0.f ? v : 0.f;
          o[(size_t)(nbase + r) * 256 + co] = f2bf(v);
        }
      } else {
        float sc = p.ep_scale[co], sh = p.ep_shift[co];
        float* o = (float*)p.out;
        int b = nbase / 7744; int s = nbase - b * 7744;
        float4 v;
        v.x = fmaxf(fmaf(a[0], sc, sh), 0.f);
        v.y = fmaxf(fmaf(a[1], sc, sh), 0.f);
        v.z = fmaxf(fmaf(a[2], sc, sh), 0.f);
        v.w = fmaxf(fmaf(a[3], sc, sh), 0.f);
        *reinterpret_cast<float4*>(o + ((size_t)(b * 256 + co)) * 7744 + s) = v;
      }
    }
  }
}

// ---------------------------------------------------------------- spatial mask
__global__ __launch_bounds__(256)
void mask_k(const unsigned short* __restrict__ h1, const float* __restrict__ w2,
            const float* __restrict__ b2, float* __restrict__ mask,
            unsigned short* __restrict__ FusPad)
{
  __shared__ float w[256];
  int t = threadIdx.x;
  w[t] = w2[t];
  __syncthreads();
  int n = blockIdx.x * 256 + t;
  const unsigned short* row = h1 + (size_t)n * 256;
  float s = b2[0];
  for (int c = 0; c < 256; c += 8){
    union { uint4 v; unsigned short s_[8]; } u;
    u.v = *reinterpret_cast<const uint4*>(row + c);
    #pragma unroll
    for (int j = 0; j < 8; ++j) s = fmaf(bf2f(u.s_[j]), w[c + j], s);
  }
  float m = 1.f / (1.f + __expf(-s));
  mask[n] = m;
  int b = n / 7744, sr = n - b * 7744;
  int y = sr / 88, x = sr - y * 88;
  FusPad[(((size_t)b * 90 + y + 1) * 90 + (x + 1)) * 576 + 512] = f2bf(m);
}

// ---------------------------------------------------------------- f_depth * mask -> NHWC bf16
__global__ __launch_bounds__(256)
void fdm_k(const unsigned short* __restrict__ Xpad, const float* __restrict__ mask,
           unsigned short* __restrict__ fdm)
{
  int idx = blockIdx.x * 256 + threadIdx.x;
  int n = idx >> 5, cb = idx & 31;
  int b = n / 7744, s = n - b * 7744;
  int y = s / 88, x = s - y * 88;
  size_t pix = ((size_t)(b * 90 + y + 1)) * 90 + x + 1;
  union { uint4 v; unsigned short s_[8]; } u, w;
  u.v = *reinterpret_cast<const uint4*>(Xpad + pix * 512 + 256 + cb * 8);
  float m = mask[n];
  #pragma unroll
  for (int j = 0; j < 8; ++j) w.s_[j] = f2bf(bf2f(u.s_[j]) * m);
  *reinterpret_cast<uint4*>(fdm + (size_t)n * 256 + cb * 8) = w.v;
}

// ---------------------------------------------------------------- merged split-K sum + channel LN (both sides)
__global__ __launch_bounds__(256)
void lnkvr2_k(const float* __restrict__ partA, const float* __restrict__ partB,
              const float* __restrict__ srbA, const float* __restrict__ srbB,
              const float* __restrict__ lngA, const float* __restrict__ lngB,
              const float* __restrict__ lnbA, const float* __restrict__ lnbB,
              unsigned short* __restrict__ kvrA, unsigned short* __restrict__ kvrB)
{
  int n = blockIdx.x, t = threadIdx.x;
  int side = n >= 968; n -= side * 968;
  const float* part = side ? partB : partA;
  const float* srb = side ? srbB : srbA;
  const float* lng = side ? lngB : lngA;
  const float* lnb = side ? lnbB : lnbA;
  unsigned short* kvr = side ? kvrB : kvrA;

  float v = srb[t];
  for (int s = 0; s < 8; ++s) v += part[((size_t)s * 968 + n) * 256 + t];
  float s1 = v, s2 = v * v;
  #pragma unroll
  for (int o = 1; o < 64; o <<= 1){ s1 += __shfl_xor(s1, o, 64); s2 += __shfl_xor(s2, o, 64); }
  __shared__ float a1[4], a2[4];
  if ((t & 63) == 0){ a1[t >> 6] = s1; a2[t >> 6] = s2; }
  __syncthreads();
  float t1 = a1[0] + a1[1] + a1[2] + a1[3];
  float t2 = a2[0] + a2[1] + a2[2] + a2[3];
  float mean = t1 * (1.f / 256.f);
  float var = t2 * (1.f / 256.f) - mean * mean;
  float rstd = rsqrtf(var + 1e-5f);
  kvr[(size_t)n * 256 + t] = f2bf((v - mean) * rstd * lng[t] + lnb[t]);
}

// ---------------------------------------------------------------- merged V-conv (+ K-proj) both sides
// VBt[b][c][128m] bf16; KB[n][32] f32 (K 1x1 conv folded in, reuses LDS row).
__global__ __launch_bounds__(256)
void vconv2_k(const unsigned short* __restrict__ kvrA, const unsigned short* __restrict__ kvrB,
              const unsigned short* __restrict__ vwtA, const unsigned short* __restrict__ vwtB,
              const float* __restrict__ vbA, const float* __restrict__ vbB,
              const unsigned short* __restrict__ kwtA, const unsigned short* __restrict__ kwtB,
              const float* __restrict__ kbA, const float* __restrict__ kbB,
              unsigned short* __restrict__ VBtA, unsigned short* __restrict__ VBtB,
              float* __restrict__ KBA, float* __restrict__ KBB)
{
  int n = blockIdx.x;
  int side = n >= 968; n -= side * 968;
  const unsigned short* kvr = side ? kvrB : kvrA;
  const unsigned short* vwt = side ? vwtB : vwtA;
  const float* vb = side ? vbB : vbA;
  const unsigned short* kwt = side ? kwtB : kwtA;
  const float* kbias = side ? kbB : kbA;
  unsigned short* VBt = side ? VBtB : VBtA;
  float* KB = side ? KBB : KBA;

  __shared__ float rowf[256];
  const int t = threadIdx.x;
  rowf[t] = bf2f(kvr[(size_t)n * 256 + t]);
  __syncthreads();
  float sum = vb[t];
  #pragma unroll 8
  for (int c = 0; c < 256; ++c)
    sum = fmaf(rowf[c], bf2f(vwt[(size_t)c * 256 + t]), sum);
  int b = n / 121, m = n - b * 121;
  VBt[(size_t)b * 32768 + (size_t)t * 128 + m] = f2bf(sum);

  if (t < 32){
    float ks = kbias[t];
    #pragma unroll 8
    for (int c = 0; c < 256; ++c)
      ks = fmaf(rowf[c], bf2f(kwt[c * 32 + t]), ks);
    KB[(size_t)n * 32 + t] = ks;
  }
}

// ---------------------------------------------------------------- merged MFMA attention (+fused Q-proj) + LN + residual
struct AttnS {
  const unsigned short* Qsrc;
  const unsigned short* wq;
  const float* qb;
  const float* Kbuf;
  const unsigned short* VBt;
  const float* ng;
  const float* nb;
  const float* gm;
  int qmode, resOff, outOff;
};

__global__ __launch_bounds__(512, 2)
void attn2_k(AttnS s0, AttnS s1,
             const unsigned short* __restrict__ Xpad,
             unsigned short* __restrict__ FusPad)
{
  __shared__ unsigned short Vt[2][256][64];
  __shared__ unsigned short Pl[2][128][64];
  __shared__ unsigned short Qs[128][64];
  __shared__ unsigned short Ks[128][64];
  __shared__ unsigned short Wqs[32][256];

  int bid = blockIdx.x;
  const int side = bid >= 488;
  bid -= side * 488;
  const AttnS& s = side ? s1 : s0;

  const int t = threadIdx.x;
  const int lane = t & 63;
  const int w = t >> 6;
  const int c15 = lane & 15;
  const int h = lane >> 4;

  const int b = bid / 61;
  const int rb = bid - b * 61;
  const int nb0 = rb * 128;

  const unsigned short* vsrc = s.VBt + (size_t)b * 32768;
  #pragma unroll
  for (int kt = 0; kt < 2; ++kt)
    #pragma unroll
    for (int i = 0; i < 4; ++i){
      int rowbase = i * 64 + w * 8;
      int c = rowbase + (lane >> 3);
      int mchunk = (lane & 7) ^ (c & 7);
      __builtin_amdgcn_global_load_lds(
        (AS1 void*)(vsrc + (size_t)c * 128 + kt * 64 + mchunk * 8),
        (AS3 void*)(&Vt[kt][rowbase][0]),
        16, 0, 0);
    }

  {
    uint4* d = (uint4*)&Wqs[0][0]; const uint4* sw = (const uint4*)s.wq;
    d[t] = sw[t];
    d[t + 512] = sw[t + 512];
  }
  {
    int m = t >> 2, part = t & 3;
    union { uint4 v; unsigned short s_[8]; } u;
    u.v = uint4{0, 0, 0, 0};
    if (m < 121){
      const float* kp = s.Kbuf + ((size_t)b * 121 + m) * 32 + part * 8;
      float4 a = *reinterpret_cast<const float4*>(kp);
      float4 bb = *reinterpret_cast<const float4*>(kp + 4);
      u.s_[0] = f2bf(a.x); u.s_[1] = f2bf(a.y); u.s_[2] = f2bf(a.z); u.s_[3] = f2bf(a.w);
      u.s_[4] = f2bf(bb.x); u.s_[5] = f2bf(bb.y); u.s_[6] = f2bf(bb.z); u.s_[7] = f2bf(bb.w);
    }
    *reinterpret_cast<uint4*>(&Ks[m][(part ^ (m & 7)) * 8]) = u.v;
  }
  __syncthreads();

  const int nA = w * 16 + c15;
  const float scale = 0.17677669529663687f;  // 32^-0.5

  {
    int gn = nb0 + nA; if (gn > 7743) gn = 7743;
    const unsigned short* xrow;
    if (s.qmode){
      int y = gn / 88, x = gn - y * 88;
      xrow = s.Qsrc + (((size_t)(b * 90) + y + 1) * 90 + (x + 1)) * 512;
    } else {
      xrow = s.Qsrc + ((size_t)b * 7744 + gn) * 256;
    }
    f32x4 qacc[2];
    qacc[0] = f32x4{0.f, 0.f, 0.f, 0.f};
    qacc[1] = f32x4{0.f, 0.f, 0.f, 0.f};
    #pragma unroll
    for (int kt = 0; kt < 8; ++kt){
      bf16x8 ax = *reinterpret_cast<const bf16x8*>(xrow + kt * 32 + h * 8);
      #pragma unroll
      for (int ni = 0; ni < 2; ++ni){
        int co = ni * 16 + c15;
        bf16x8 bw = *reinterpret_cast<const bf16x8*>(&Wqs[co][((kt * 4 + h) ^ (co & 7)) * 8]);
        qacc[ni] = __builtin_amdgcn_mfma_f32_16x16x32_bf16(ax, bw, qacc[ni], 0, 0, 0);
      }
    }
    #pragma unroll
    for (int ni = 0; ni < 2; ++ni){
      int co = ni * 16 + c15;
      float bq = s.qb[co];
      #pragma unroll
      for (int r = 0; r < 4; ++r){
        int n = w * 16 + 4 * h + r;
        int chunk = (co >> 3) ^ (n & 7);
        Qs[n][chunk * 8 + (co & 7)] = f2bf((qacc[ni][r] + bq) * scale);
      }
    }
  }

  bf16x8 aq = *reinterpret_cast<const bf16x8*>(&Qs[nA][(h ^ (nA & 7)) * 8]);
  f32x4 sv[8];
  #pragma unroll
  for (int ni = 0; ni < 8; ++ni){
    int mrow = ni * 16 + c15;
    bf16x8 bk = *reinterpret_cast<const bf16x8*>(&Ks[mrow][(h ^ (mrow & 7)) * 8]);
    sv[ni] = __builtin_amdgcn_mfma_f32_16x16x32_bf16(aq, bk, f32x4{0.f,0.f,0.f,0.f}, 0, 0, 0);
  }
  if (c15 >= 9) sv[7] = f32x4{-1e30f, -1e30f, -1e30f, -1e30f};

  float rden[4];
  #pragma unroll
  for (int r = 0; r < 4; ++r){
    float mx = sv[0][r];
    #pragma unroll
    for (int ni = 1; ni < 8; ++ni) mx = fmaxf(mx, sv[ni][r]);
    #pragma unroll
    for (int o = 1; o < 16; o <<= 1) mx = fmaxf(mx, __shfl_xor(mx, o, 64));
    float sm = 0.f;
    #pragma unroll
    for (int ni = 0; ni < 8; ++ni){
      float p = __expf(sv[ni][r] - mx);
      sv[ni][r] = p;
      sm += p;
    }
    #pragma unroll
    for (int o = 1; o < 16; o <<= 1) sm += __shfl_xor(sm, o, 64);
    rden[r] = 1.f / sm;
  }
  #pragma unroll
  for (int ni = 0; ni < 8; ++ni){
    int m = ni * 16 + c15;
    int kt = m >> 6;
    int mq = (m & 63) >> 3;
    #pragma unroll
    for (int r = 0; r < 4; ++r){
      int n = w * 16 + 4 * h + r;
      Pl[kt][n][(mq ^ (n & 7)) * 8 + (m & 7)] = f2bf(sv[ni][r] * rden[r]);
    }
  }

  bf16x8 pa[2][2];
  #pragma unroll
  for (int kt = 0; kt < 2; ++kt)
    #pragma unroll
    for (int ks = 0; ks < 2; ++ks)
      pa[kt][ks] = *reinterpret_cast<const bf16x8*>(&Pl[kt][nA][((ks * 4 + h) ^ (nA & 7)) * 8]);

  f32x4 acc[16];
  #pragma unroll
  for (int ni = 0; ni < 16; ++ni) acc[ni] = f32x4{0.f, 0.f, 0.f, 0.f};
  #pragma unroll
  for (int ni = 0; ni < 16; ++ni){
    int crow = ni * 16 + c15;
    #pragma unroll
    for (int kt = 0; kt < 2; ++kt)
      #pragma unroll
      for (int ks = 0; ks < 2; ++ks){
        bf16x8 bv = *reinterpret_cast<const bf16x8*>(&Vt[kt][crow][((ks * 4 + h) ^ (crow & 7)) * 8]);
        acc[ni] = __builtin_amdgcn_mfma_f32_16x16x32_bf16(pa[kt][ks], bv, acc[ni], 0, 0, 0);
      }
  }

  float ngv[16], nbb[16];
  #pragma unroll
  for (int ni = 0; ni < 16; ++ni){
    int c = ni * 16 + c15;
    ngv[ni] = s.ng[c]; nbb[ni] = s.nb[c];
  }
  float g = s.gm[0]; g = fminf(fmaxf(g, 0.f), 1.f);

  #pragma unroll
  for (int r = 0; r < 4; ++r){
    float s1 = 0.f, s2 = 0.f;
    #pragma unroll
    for (int ni = 0; ni < 16; ++ni){ float v = acc[ni][r]; s1 += v; s2 += v * v; }
    #pragma unroll
    for (int o = 1; o < 16; o <<= 1){ s1 += __shfl_xor(s1, o, 64); s2 += __shfl_xor(s2, o, 64); }
    float mean = s1 * (1.f / 256.f);
    float var = s2 * (1.f / 256.f) - mean * mean;
    float rstd = rsqrtf(var + 1e-5f);

    int nloc = w * 16 + 4 * h + r;
    int rix = nb0 + nloc;
    if (rix < 7744){
      int y = rix / 88, x = rix - y * 88;
      size_t pix = ((size_t)(b * 90) + y + 1) * 90 + (x + 1);
      const unsigned short* res = Xpad + pix * 512 + s.resOff;
      unsigned short* outp = FusPad + pix * 576 + s.outOff;
      #pragma unroll
      for (int ni = 0; ni < 16; ++ni){
        int c = ni * 16 + c15;
        float yv = (acc[ni][r] - mean) * rstd * ngv[ni] + nbb[ni];
        outp[c] = f2bf(bf2f(res[c]) + g * yv);
      }
    }
  }
}

// ================================================================ host
extern "C" void kernel_launch(void* const* d_in, const int* in_sizes, int n_in,
                              void* d_out, int out_size, void* d_ws, size_t ws_size,
                              hipStream_t stream)
{
  const float* P[42];
  for (int i = 0; i < 42; ++i) P[i] = (const float*)d_in[i];

  char* ws = (char*)d_ws;
  size_t off = 0;
  auto take = [&](size_t bytes) -> char* {
    char* p = ws + off; off += (bytes + 255) & ~(size_t)255; return p;
  };
  unsigned short* XPAD = (unsigned short*)take(8ull * 8100 * 512 * 2);   // 66.4 MB
  unsigned short* FUSP = (unsigned short*)take(8ull * 8100 * 576 * 2);   // 74.6 MB
  unsigned short* H1   = (unsigned short*)take(61952ull * 256 * 2);      // 31.7 MB
  unsigned short* FDM  = H1;  // alias: h1 dead after mask_k
  unsigned short* W1T  = (unsigned short*)take(9ull * 256 * 512 * 2);
  unsigned short* WFT  = (unsigned short*)take(9ull * 256 * 576 * 2);
  unsigned short* WSRA = (unsigned short*)take(64ull * 256 * 256 * 2);
  unsigned short* WSRB = (unsigned short*)take(64ull * 256 * 256 * 2);
  float* PARTA = (float*)take(8ull * 968 * 256 * 4);                      // 7.9 MB
  float* PARTB = (float*)take(8ull * 968 * 256 * 4);                      // 7.9 MB
  unsigned short* KVRA = (unsigned short*)take(968ull * 256 * 2);
  unsigned short* KVRB = (unsigned short*)take(968ull * 256 * 2);
  float* KBA  = (float*)take(968ull * 32 * 4);
  float* KBB  = (float*)take(968ull * 32 * 4);
  unsigned short* VBTA = (unsigned short*)take(2ull * 8 * 256 * 128 * 2); // A and B contiguous, 1MB
  unsigned short* VBTB = VBTA + 8ull * 256 * 128;
  float* MASK = (float*)take(61952ull * 4);
  float* SC1 = (float*)take(256 * 4);
  float* SH1 = (float*)take(256 * 4);
  float* SCF = (float*)take(256 * 4);
  float* SHF = (float*)take(256 * 4);
  unsigned short* WQSA = (unsigned short*)take(32ull * 256 * 2);
  unsigned short* WQSB = (unsigned short*)take(32ull * 256 * 2);
  unsigned short* KWTA = (unsigned short*)take(256ull * 32 * 2);
  unsigned short* VWTA = (unsigned short*)take(256ull * 256 * 2);
  unsigned short* KWTB = (unsigned short*)take(256ull * 32 * 2);
  unsigned short* VWTB = (unsigned short*)take(256ull * 256 * 2);
  (void)ws_size; (void)in_sizes; (void)n_in; (void)out_size;

  zero_border_k<<<8 * 356, 128, 0, stream>>>(XPAD, 512);
  zero_border_k<<<8 * 356, 128, 0, stream>>>(FUSP, 576);
  zero_fustail_k<<<1936, 256, 0, stream>>>(FUSP);
  hipMemsetAsync(VBTA, 0, 2ull * 8 * 256 * 128 * 2, stream);   // zero pad rows m=121..127, both sides

  bnprep_k<<<1, 256, 0, stream>>>(P[4], P[5], P[6], P[7], P[3],
                                  P[38], P[39], P[40], P[41], P[37],
                                  SC1, SH1, SCF, SHF);
  prep_xpad_k<<<7744, 256, 0, stream>>>(P[0], P[1], XPAD);
  prep_w1t_k<<<256, 256, 0, stream>>>(P[2], W1T);
  prep_wfus_k<<<256, 256, 0, stream>>>(P[36], WFT);
  prep_wsr_k<<<256, 256, 0, stream>>>(P[16], WSRA);
  prep_wsr_k<<<256, 256, 0, stream>>>(P[28], WSRB);
  wqprep_k<<<32, 256, 0, stream>>>(P[10], WQSA);
  wqprep_k<<<32, 256, 0, stream>>>(P[22], WQSB);
  tranw_k<<<8, 256, 0, stream>>>(P[12], KWTA, 32, 256);
  tranw_k<<<64, 256, 0, stream>>>(P[14], VWTA, 256, 256);
  tranw_k<<<8, 256, 0, stream>>>(P[24], KWTB, 32, 256);
  tranw_k<<<64, 256, 0, stream>>>(P[26], VWTB, 256, 256);

  // conv1 3x3 (512->256) + BN + ReLU -> h1 NHWC bf16   [256^2 8-phase kernel]
  GemmP g1{};
  g1.A = XPAD; g1.W = W1T; g1.ep_scale = SC1; g1.ep_shift = SH1; g1.out = H1;
  g1.img_px = 8100; g1.row_px = 90; g1.px_el = 512; g1.ch_off = 0; g1.y0 = 0; g1.x0 = 0;
  g1.tapw = 3; g1.stridepix = 1; g1.out_w = 88; g1.out_imgpx = 7744;
  g1.Cin = 512; g1.Mtot = 61952; g1.Mtiles = 242; g1.Ntiles = 1; g1.k_per = 4608;
  gemm256_k<0><<<242, 512, 0, stream>>>(g1);

  mask_k<<<242, 256, 0, stream>>>(H1, P[8], P[9], MASK, FUSP);
  fdm_k<<<7744, 256, 0, stream>>>(XPAD, MASK, FDM);

  // ---------------- merged SRA pipelines (d2r: A=FDM/W=WSRA ; r2d: A=XPAD/W=WSRB) ----------------
  GemmP ga{};
  ga.A = FDM; ga.W = WSRA; ga.out = nullptr;
  ga.img_px = 7744; ga.row_px = 88; ga.px_el = 256; ga.ch_off = 0; ga.y0 = 0; ga.x0 = 0;
  ga.tapw = 8; ga.stridepix = 8; ga.out_w = 11; ga.out_imgpx = 121;
  ga.Cin = 256; ga.Mtot = 968; ga.Mtiles = 8; ga.Ntiles = 2; ga.k_per = 2048;
  GemmP gb = ga;
  gb.A = XPAD; gb.W = WSRB;
  gb.img_px = 8100; gb.row_px = 90; gb.px_el = 512; gb.y0 = 1; gb.x0 = 1;
  gemm_sr_k<<<256, 256, 0, stream>>>(ga, gb, PARTA, PARTB);

  lnkvr2_k<<<1936, 256, 0, stream>>>(PARTA, PARTB, P[17], P[29], P[18], P[30],
                                     P[19], P[31], KVRA, KVRB);
  vconv2_k<<<1936, 256, 0, stream>>>(KVRA, KVRB, VWTA, VWTB, P[15], P[27],
                                     KWTA, KWTB, P[13], P[25],
                                     VBTA, VBTB, KBA, KBB);

  AttnS s0{XPAD, WQSA, P[11], KBA, VBTA, P[20], P[21], P[34], 1, 0, 0};
  AttnS s1{FDM,  WQSB, P[23], KBB, VBTB, P[32], P[33], P[35], 0, 256, 256};
  attn2_k<<<976, 512, 0, stream>>>(s0, s1, XPAD, FUSP);

  // final fused conv 3x3 (576->256) + BN + ReLU -> d_out f32 NCHW   [256^2 8-phase kernel]
  GemmP gf{};
  gf.A = FUSP; gf.W = WFT; gf.ep_scale = SCF; gf.ep_shift = SHF; gf.out = d_out;
  gf.img_px = 8100; gf.row_px = 90; gf.px_el = 576; gf.ch_off = 0; gf.y0 = 0; gf.x0 = 0;
  gf.tapw = 3; gf.stridepix = 1; gf.out_w = 88; gf.out_imgpx = 7744;
  gf.Cin = 576; gf.Mtot = 61952; gf.Mtiles = 242; gf.Ntiles = 1; gf.k_per = 5184;
  gemm256_k<1><<<242, 512, 0, stream>>>(gf);
}

// Round 11
// 534.767 us; speedup vs baseline: 4.8382x; 1.0234x over previous
//
#include <hip/hip_runtime.h>
#include <hip/hip_bf16.h>

// BiDirectionalFusionModule on MI355X.
// R2: global_load_lds(16B) GEMM staging; coalesced weight preps.
// R5: MFMA attention (8 waves, wave-local softmax/LN, swizzled LDS, V via lds-DMA).
// R6: GEMM L2-locality (cib-outer/tap-inner, XCD chunk swizzle): FETCH 574->60MB.
// R7: Q-proj fused into attn_k; targeted border/tail zeroing.
// R9: 8-phase 256^2 GEMM (T3+T4+T5): 188us/conv, MfmaUtil 36% (measured best).
// R10: merged d2r/r2d tail (4 launches); gemm256 resched REGRESSED (200us) -> reverted.
// R11: recombination of measured-best pieces: R9 gemm256_k + R10 merged tail.

typedef __bf16 bf16x8 __attribute__((ext_vector_type(8)));
typedef float f32x4 __attribute__((ext_vector_type(4)));

#define AS1 __attribute__((address_space(1)))
#define AS3 __attribute__((address_space(3)))
#define DEVI __device__ __forceinline__
#define BARRIER() do { asm volatile("" ::: "memory"); __builtin_amdgcn_s_barrier(); asm volatile("" ::: "memory"); } while (0)

DEVI float bf2f(unsigned short u){
  union { unsigned int i; float f; } v; v.i = ((unsigned int)u) << 16; return v.f;
}
DEVI unsigned short f2bf(float f){
  union { float f; unsigned int i; } v; v.f = f;
  unsigned int x = v.i;
  unsigned int r = (x + 0x7fffu + ((x >> 16) & 1u)) >> 16;
  return (unsigned short)r;
}

// ---------------------------------------------------------------- BN prep
__global__ void bnprep_k(const float* __restrict__ g1, const float* __restrict__ be1,
                         const float* __restrict__ m1, const float* __restrict__ v1,
                         const float* __restrict__ b1,
                         const float* __restrict__ gf, const float* __restrict__ bef,
                         const float* __restrict__ mf, const float* __restrict__ vf,
                         const float* __restrict__ bf,
                         float* __restrict__ sc1, float* __restrict__ sh1,
                         float* __restrict__ scf, float* __restrict__ shf)
{
  int c = threadIdx.x;
  float s = g1[c] * rsqrtf(v1[c] + 1e-5f);
  sc1[c] = s; sh1[c] = (b1[c] - m1[c]) * s + be1[c];
  s = gf[c] * rsqrtf(vf[c] + 1e-5f);
  scf[c] = s; shf[c] = (bf[c] - mf[c]) * s + bef[c];
}

// ---------------------------------------------------------------- targeted zeroing
__global__ __launch_bounds__(128)
void zero_border_k(unsigned short* __restrict__ buf, int px_el)
{
  int bi = blockIdx.x;
  int img = bi / 356, e = bi - img * 356;
  int y, x;
  if (e < 90){ y = 0; x = e; }
  else if (e < 180){ y = 89; x = e - 90; }
  else if (e < 268){ y = e - 180 + 1; x = 0; }
  else { y = e - 268 + 1; x = 89; }
  size_t pix = ((size_t)img * 90 + y) * 90 + x;
  int t = threadIdx.x;
  if (t < (px_el >> 3))
    *reinterpret_cast<uint4*>(buf + pix * px_el + t * 8) = uint4{0, 0, 0, 0};
}
__global__ __launch_bounds__(256)
void zero_fustail_k(unsigned short* __restrict__ FusPad)
{
  int idx = blockIdx.x * 256 + threadIdx.x;   // 61952*8
  int n = idx >> 3, ch = idx & 7;
  int b = n / 7744, s = n - b * 7744;
  int y = s / 88, x = s - y * 88;
  size_t pix = ((size_t)(b * 90 + y + 1)) * 90 + (x + 1);
  *reinterpret_cast<uint4*>(FusPad + pix * 576 + 512 + ch * 8) = uint4{0, 0, 0, 0};
}

// ------------------------------------------------- NCHW f32 -> padded NHWC bf16
__global__ __launch_bounds__(256)
void prep_xpad_k(const float* __restrict__ rgb, const float* __restrict__ dep,
                 unsigned short* __restrict__ Xpad)
{
  __shared__ unsigned short tile[64][65];
  int bi = blockIdx.x;
  int b = bi / 968;
  int rem = bi - b * 968;
  int cblk = rem / 121;
  int pblk = rem - cblk * 121;
  int t = threadIdx.x;
  int pl = t & 63;
  #pragma unroll
  for (int pass = 0; pass < 16; ++pass){
    int cl = pass * 4 + (t >> 6);
    int c = cblk * 64 + cl;
    const float* sp = (c < 256) ? (rgb + ((size_t)b * 256 + c) * 7744)
                                : (dep + ((size_t)b * 256 + (c - 256)) * 7744);
    tile[cl][pl] = f2bf(sp[pblk * 64 + pl]);
  }
  __syncthreads();
  int cl2 = t & 63;
  for (int pass = 0; pass < 16; ++pass){
    int pl2 = pass * 4 + (t >> 6);
    int pixg = pblk * 64 + pl2;
    int y = pixg / 88, x = pixg - y * 88;
    Xpad[(((size_t)b * 90 + y + 1) * 90 + (x + 1)) * 512 + cblk * 64 + cl2] = tile[cl2][pl2];
  }
}

// ---------------------------------------------------------------- weight reshuffles
__global__ __launch_bounds__(256)
void prep_w1t_k(const float* __restrict__ w, unsigned short* __restrict__ o)
{
  int co = blockIdx.x, t = threadIdx.x;
  const float* src = w + (size_t)co * 4608 + t * 18;
  unsigned int* op = (unsigned int*)o;
  #pragma unroll
  for (int k = 0; k < 9; ++k){
    unsigned short lo = f2bf(src[k]);
    unsigned short hi = f2bf(src[9 + k]);
    op[((size_t)k * 256 + co) * 256 + t] = lo | ((unsigned int)hi << 16);
  }
}
__global__ __launch_bounds__(256)
void prep_wfus_k(const float* __restrict__ w, unsigned short* __restrict__ o)
{
  int co = blockIdx.x, t = threadIdx.x;
  const float* src = w + (size_t)co * 4617 + t * 18;
  unsigned int* op = (unsigned int*)o;
  #pragma unroll
  for (int k = 0; k < 9; ++k){
    unsigned short lo = f2bf(src[k]);
    unsigned short hi = f2bf(src[9 + k]);
    op[((size_t)k * 256 + co) * 288 + t] = lo | ((unsigned int)hi << 16);
  }
  if (t < 32){
    #pragma unroll
    for (int k = 0; k < 9; ++k){
      unsigned int val = 0;
      if (t == 0) val = (unsigned int)f2bf(w[(size_t)co * 4617 + 512 * 9 + k]);
      op[((size_t)k * 256 + co) * 288 + 256 + t] = val;
    }
  }
}
__global__ __launch_bounds__(256)
void prep_wsr_k(const float* __restrict__ w, unsigned short* __restrict__ o)
{
  __shared__ float ld[64][65];
  int co = blockIdx.x;
  int t = threadIdx.x;
  for (int cib = 0; cib < 256; cib += 64){
    int cil = t >> 2, tq = t & 3;
    const float* src = w + ((size_t)co * 256 + cib + cil) * 64 + tq * 16;
    float v[16];
    #pragma unroll
    for (int k = 0; k < 16; ++k) v[k] = src[k];
    __syncthreads();
    #pragma unroll
    for (int k = 0; k < 16; ++k) ld[cil][tq * 16 + k] = v[k];
    __syncthreads();
    #pragma unroll
    for (int tp = 0; tp < 16; ++tp){
      int tap = tp * 4 + (t >> 6);
      int ci = t & 63;
      o[((size_t)tap * 256 + co) * 256 + cib + ci] = f2bf(ld[ci][tap]);
    }
  }
}
__global__ __launch_bounds__(256)
void tranw_k(const float* __restrict__ in, unsigned short* __restrict__ out, int R, int C)
{
  __shared__ float tl[32][33];
  int tiles_c = C >> 5;
  int tr = (blockIdx.x / tiles_c) << 5, tc = (blockIdx.x % tiles_c) << 5;
  int t = threadIdx.x; int r = t >> 5, c = t & 31;
  #pragma unroll
  for (int p = 0; p < 4; ++p)
    tl[r + p * 8][c] = in[(size_t)(tr + r + p * 8) * C + tc + c];
  __syncthreads();
  #pragma unroll
  for (int p = 0; p < 4; ++p)
    out[(size_t)(tc + r + p * 8) * R + tr + c] = f2bf(tl[c][r + p * 8]);
}
__global__ __launch_bounds__(256)
void wqprep_k(const float* __restrict__ w, unsigned short* __restrict__ o)
{
  int co = blockIdx.x, t = threadIdx.x;
  int c = t >> 3, e = t & 7;
  o[co * 256 + ((c ^ (co & 7)) * 8) + e] = f2bf(w[co * 256 + t]);
}

// ---------------------------------------------------------------- GEMM params
struct GemmP {
  const unsigned short* A;
  const unsigned short* W;
  const float* ep_scale;
  const float* ep_shift;
  void* out;
  int img_px, row_px, px_el, ch_off, y0, x0;
  int tapw, stridepix, out_w, out_imgpx;
  int Cin, Mtot, Mtiles, Ntiles, k_per;
};

// ---------------------------------------------------------------- merged SR conv GEMM (f32 partials)
__global__ __launch_bounds__(256)
void gemm_sr_k(GemmP pa, GemmP pb, float* __restrict__ outA, float* __restrict__ outB)
{
  const int t = threadIdx.x;
  const int lane = t & 63;
  const int wid = t >> 6;
  const int wr = wid >> 1, wc = wid & 1;

  const int cpx = gridDim.x >> 3;
  int pid = (blockIdx.x & 7) * cpx + (blockIdx.x >> 3);
  const int side = pid >= 128;
  const GemmP& p = side ? pb : pa;
  float* outp = side ? outB : outA;
  pid &= 127;

  __shared__ __bf16 As[2][128 * 64];
  __shared__ __bf16 Bs[2][128 * 64];

  const int mn = p.Mtiles * p.Ntiles;   // 16
  int within = pid % mn;
  int slot = pid / mn;                  // 0..7
  int mt = within / p.Ntiles;
  int nt = within - mt * p.Ntiles;
  int kb = slot * p.k_per;
  int tap0 = kb / p.Cin;
  int ntap = p.k_per / p.Cin;           // 8

  long long apix[4]; int cbg8[4]; int wrow[4];
  #pragma unroll
  for (int i = 0; i < 4; ++i){
    int r = i * 32 + (t >> 3);
    cbg8[i] = ((t & 7) ^ (r & 7)) * 8;
    int n = mt * 128 + r;
    int nc = n < p.Mtot ? n : 0;
    int b = nc / p.out_imgpx; int rr = nc - b * p.out_imgpx;
    int yo = rr / p.out_w;    int xo = rr - yo * p.out_w;
    apix[i] = (long long)b * p.img_px + (long long)(yo * p.stridepix + p.y0) * p.row_px
            + (xo * p.stridepix + p.x0);
    wrow[i] = (nt * 128 + r) * p.Cin + cbg8[i];
  }

  f32x4 acc[4][4];
  #pragma unroll
  for (int i = 0; i < 4; ++i)
    #pragma unroll
    for (int j = 0; j < 4; ++j)
      acc[i][j] = f32x4{0.f, 0.f, 0.f, 0.f};

  const long long wstap = 256LL * p.Cin;

  auto STAGE = [&](int buf, int tap, int cib){
    int dy = tap / p.tapw, dx = tap - dy * p.tapw;
    const unsigned short* wb = p.W + (long long)tap * wstap + cib;
    const long long aoff = (long long)(dy * p.row_px + dx) * p.px_el + p.ch_off + cib;
    #pragma unroll
    for (int i = 0; i < 4; ++i){
      __builtin_amdgcn_global_load_lds(
          (AS1 void*)(p.A + apix[i] * p.px_el + aoff + cbg8[i]),
          (AS3 void*)(&As[buf][i * 2048 + wid * 512]),
          16, 0, 0);
      __builtin_amdgcn_global_load_lds(
          (AS1 void*)(wb + wrow[i]),
          (AS3 void*)(&Bs[buf][i * 2048 + wid * 512]),
          16, 0, 0);
    }
  };

  const int NT = (p.Cin >> 6) * ntap;
  STAGE(0, tap0, 0);
  int tpn = 1, tap_n = tap0 + 1, cib_n = 0;
  int cur = 0;

  for (int kt = 0; kt < NT; ++kt){
    if (kt + 1 < NT){
      STAGE(cur ^ 1, tap_n, cib_n);
      ++tpn; ++tap_n;
      if (tpn == ntap){ tpn = 0; tap_n = tap0; cib_n += 64; }
      asm volatile("s_waitcnt vmcnt(8)" ::: "memory");
    } else {
      asm volatile("s_waitcnt vmcnt(0)" ::: "memory");
    }
    __builtin_amdgcn_s_barrier();
    __builtin_amdgcn_sched_barrier(0);

    #pragma unroll
    for (int ks = 0; ks < 2; ++ks){
      bf16x8 av[4], bv[4];
      #pragma unroll
      for (int mi = 0; mi < 4; ++mi){
        int ar = wr * 64 + mi * 16 + (lane & 15);
        int cb = (ks * 4 + (lane >> 4)) ^ (ar & 7);
        av[mi] = *reinterpret_cast<const bf16x8*>(&As[cur][ar * 64 + cb * 8]);
      }
      #pragma unroll
      for (int ni = 0; ni < 4; ++ni){
        int br = wc * 64 + ni * 16 + (lane & 15);
        int cb = (ks * 4 + (lane >> 4)) ^ (br & 7);
        bv[ni] = *reinterpret_cast<const bf16x8*>(&Bs[cur][br * 64 + cb * 8]);
      }
      #pragma unroll
      for (int mi = 0; mi < 4; ++mi)
        #pragma unroll
        for (int ni = 0; ni < 4; ++ni)
          acc[mi][ni] = __builtin_amdgcn_mfma_f32_16x16x32_bf16(av[mi], bv[ni], acc[mi][ni], 0, 0, 0);
    }

    __builtin_amdgcn_sched_barrier(0);
    __builtin_amdgcn_s_barrier();
    cur ^= 1;
  }

  const int r0 = (lane >> 4) * 4;
  const int c0 = lane & 15;
  #pragma unroll
  for (int mi = 0; mi < 4; ++mi){
    int nbase = mt * 128 + wr * 64 + mi * 16 + r0;
    #pragma unroll
    for (int ni = 0; ni < 4; ++ni){
      int co = nt * 128 + wc * 64 + ni * 16 + c0;
      f32x4 a = acc[mi][ni];
      float* o = outp + (size_t)slot * 968 * 256;
      #pragma unroll
      for (int r = 0; r < 4; ++r){
        int n = nbase + r;
        if (n < p.Mtot) o[(size_t)n * 256 + co] = a[r];
      }
    }
  }
}

// ---------------------------------------------------------------- 256^2 8-phase GEMM (big convs, R9 schedule)
// Phase p: [STG pair p (+vmcnt at p=0)] BARRIER; LDA/LDB; 16 MFMA (setprio); BARRIER.
template<int EPI>   // 0: BN+ReLU -> bf16 NHWC[.][256]   1: BN+ReLU -> f32 NCHW
__global__ __launch_bounds__(512, 2)
void gemm256_k(GemmP p)
{
  __shared__ __bf16 As[2][256 * 64];
  __shared__ __bf16 Bs[2][256 * 64];
  const int t = threadIdx.x;
  const int lane = t & 63;
  const int w = t >> 6;
  const int wr = w >> 2, wc = w & 3;
  const int c15 = lane & 15;
  const int h = lane >> 4;

  // bijective chunked XCD swizzle (m204)
  const int nwg = gridDim.x;
  const int q = nwg >> 3, r8 = nwg & 7;
  const int bid = blockIdx.x;
  const int xcd = bid & 7;
  const int mt = (xcd < r8 ? xcd * (q + 1) : r8 * (q + 1) + (xcd - r8) * q) + (bid >> 3);

  long long apixel[4];
  const unsigned short* wsrc[4];
  int lbase[4];
  #pragma unroll
  for (int i = 0; i < 4; ++i){
    int r = i * 64 + (t >> 3);
    int cb = ((t & 7) ^ (r & 7)) * 8;
    int n = mt * 256 + r;                   // Mtot = 242*256 exactly
    int b = n / p.out_imgpx; int rr = n - b * p.out_imgpx;
    int yo = rr / p.out_w;   int xo = rr - yo * p.out_w;
    long long pix = (long long)b * p.img_px + (long long)(yo * p.stridepix + p.y0) * p.row_px
                  + (xo * p.stridepix + p.x0);
    apixel[i] = pix * p.px_el + p.ch_off + cb;
    wsrc[i] = p.W + (long long)r * p.Cin + cb;
    lbase[i] = i * 4096 + w * 512;
  }

  f32x4 acc[8][4];
  #pragma unroll
  for (int i = 0; i < 8; ++i)
    #pragma unroll
    for (int j = 0; j < 4; ++j)
      acc[i][j] = f32x4{0.f, 0.f, 0.f, 0.f};

  const long long wstap = 256LL * p.Cin;
  const int ntap = p.k_per / p.Cin;         // 9
  const int NT = (p.Cin >> 6) * ntap;       // 72 or 81

  auto STG = [&](int buf, int i, long long aoff, long long woff){
    __builtin_amdgcn_global_load_lds(
        (AS1 void*)(p.A + apixel[i] + aoff),
        (AS3 void*)(&As[buf][lbase[i]]), 16, 0, 0);
    __builtin_amdgcn_global_load_lds(
        (AS1 void*)(wsrc[i] + woff),
        (AS3 void*)(&Bs[buf][lbase[i]]), 16, 0, 0);
  };
  auto LDA = [&](bf16x8* av, int mi0, int ks, int buf){
    #pragma unroll
    for (int m = 0; m < 4; ++m){
      int ar = wr * 128 + (mi0 + m) * 16 + c15;
      int cb = (ks * 4 + h) ^ (ar & 7);
      av[m] = *reinterpret_cast<const bf16x8*>(&As[buf][ar * 64 + cb * 8]);
    }
  };
  auto LDB = [&](bf16x8* bv, int ks, int buf){
    #pragma unroll
    for (int n = 0; n < 4; ++n){
      int br = wc * 64 + n * 16 + c15;
      int cb = (ks * 4 + h) ^ (br & 7);
      bv[n] = *reinterpret_cast<const bf16x8*>(&Bs[buf][br * 64 + cb * 8]);
    }
  };
  auto MM = [&](bf16x8* av, bf16x8* bv, int mi0){
    __builtin_amdgcn_s_setprio(1);
    #pragma unroll
    for (int m = 0; m < 4; ++m)
      #pragma unroll
      for (int n = 0; n < 4; ++n)
        acc[mi0 + m][n] = __builtin_amdgcn_mfma_f32_16x16x32_bf16(av[m], bv[n], acc[mi0 + m][n], 0, 0, 0);
    __builtin_amdgcn_s_setprio(0);
  };

  // prologue: stage kt=0 fully
  #pragma unroll
  for (int i = 0; i < 4; ++i) STG(0, i, 0, 0);

  int tap_n = 1, cib_n = 0;
  int cur = 0;

  for (int kt = 0; kt < NT; ++kt){
    const bool last = (kt == NT - 1);
    long long aoff_n = 0, woff_n = 0;
    if (!last){
      int dy = tap_n / p.tapw, dx = tap_n - dy * p.tapw;
      aoff_n = (long long)(dy * p.row_px + dx) * p.px_el + cib_n;
      woff_n = (long long)tap_n * wstap + cib_n;
    }
    bf16x8 av[4], bv[4];

    // ---- phase 0 ----
    if (!last){
      STG(cur ^ 1, 0, aoff_n, woff_n);
      asm volatile("s_waitcnt vmcnt(2)" ::: "memory");   // kt's 8 landed; kt+1 pair0 in flight
    } else {
      asm volatile("s_waitcnt vmcnt(0)" ::: "memory");
    }
    BARRIER();
    LDA(av, 0, 0, cur); LDB(bv, 0, cur);
    MM(av, bv, 0);
    BARRIER();
    // ---- phase 1 ----
    LDA(av, 4, 0, cur);
    if (!last) STG(cur ^ 1, 1, aoff_n, woff_n);
    BARRIER();
    MM(av, bv, 4);
    BARRIER();
    // ---- phase 2 ----
    LDA(av, 0, 1, cur); LDB(bv, 1, cur);
    if (!last) STG(cur ^ 1, 2, aoff_n, woff_n);
    BARRIER();
    MM(av, bv, 0);
    BARRIER();
    // ---- phase 3 ----
    LDA(av, 4, 1, cur);
    if (!last) STG(cur ^ 1, 3, aoff_n, woff_n);
    BARRIER();
    MM(av, bv, 4);
    BARRIER();

    cur ^= 1;
    if (!last){ ++tap_n; if (tap_n == ntap){ tap_n = 0; cib_n += 64; } }
  }

  // ---- epilogue ----
  const int r0 = (lane >> 4) * 4;
  #pragma unroll
  for (int mi = 0; mi < 8; ++mi){
    int nbase = mt * 256 + wr * 128 + mi * 16 + r0;
    #pragma unroll
    for (int ni = 0; ni < 4; ++ni){
      int co = wc * 64 + ni * 16 + c15;
      f32x4 a = acc[mi][ni];
      if constexpr (EPI == 0){
        float sc = p.ep_scale[co], sh = p.ep_shift[co];
        unsigned short* o = (unsigned short*)p.out;
        #pragma unroll
        for (int r = 0; r < 4; ++r){
          float v = fmaf(a[r], sc, sh); v = v > 0.f ? v : 0.f;
          o[(size_t)(nbase + r) * 256 + co] = f2bf(v);
        }
      } else {
        float sc = p.ep_scale[co], sh = p.ep_shift[co];
        float* o = (float*)p.out;
        int b = nbase / 7744; int s = nbase - b * 7744;
        float4 v;
        v.x = fmaxf(fmaf(a[0], sc, sh), 0.f);
        v.y = fmaxf(fmaf(a[1], sc, sh), 0.f);
        v.z = fmaxf(fmaf(a[2], sc, sh), 0.f);
        v.w = fmaxf(fmaf(a[3], sc, sh), 0.f);
        *reinterpret_cast<float4*>(o + ((size_t)(b * 256 + co)) * 7744 + s) = v;
      }
    }
  }
}

// ---------------------------------------------------------------- spatial mask
__global__ __launch_bounds__(256)
void mask_k(const unsigned short* __restrict__ h1, const float* __restrict__ w2,
            const float* __restrict__ b2, float* __restrict__ mask,
            unsigned short* __restrict__ FusPad)
{
  __shared__ float w[256];
  int t = threadIdx.x;
  w[t] = w2[t];
  __syncthreads();
  int n = blockIdx.x * 256 + t;
  const unsigned short* row = h1 + (size_t)n * 256;
  float s = b2[0];
  for (int c = 0; c < 256; c += 8){
    union { uint4 v; unsigned short s_[8]; } u;
    u.v = *reinterpret_cast<const uint4*>(row + c);
    #pragma unroll
    for (int j = 0; j < 8; ++j) s = fmaf(bf2f(u.s_[j]), w[c + j], s);
  }
  float m = 1.f / (1.f + __expf(-s));
  mask[n] = m;
  int b = n / 7744, sr = n - b * 7744;
  int y = sr / 88, x = sr - y * 88;
  FusPad[(((size_t)b * 90 + y + 1) * 90 + (x + 1)) * 576 + 512] = f2bf(m);
}

// ---------------------------------------------------------------- f_depth * mask -> NHWC bf16
__global__ __launch_bounds__(256)
void fdm_k(const unsigned short* __restrict__ Xpad, const float* __restrict__ mask,
           unsigned short* __restrict__ fdm)
{
  int idx = blockIdx.x * 256 + threadIdx.x;
  int n = idx >> 5, cb = idx & 31;
  int b = n / 7744, s = n - b * 7744;
  int y = s / 88, x = s - y * 88;
  size_t pix = ((size_t)(b * 90 + y + 1)) * 90 + x + 1;
  union { uint4 v; unsigned short s_[8]; } u, w;
  u.v = *reinterpret_cast<const uint4*>(Xpad + pix * 512 + 256 + cb * 8);
  float m = mask[n];
  #pragma unroll
  for (int j = 0; j < 8; ++j) w.s_[j] = f2bf(bf2f(u.s_[j]) * m);
  *reinterpret_cast<uint4*>(fdm + (size_t)n * 256 + cb * 8) = w.v;
}

// ---------------------------------------------------------------- merged split-K sum + channel LN (both sides)
__global__ __launch_bounds__(256)
void lnkvr2_k(const float* __restrict__ partA, const float* __restrict__ partB,
              const float* __restrict__ srbA, const float* __restrict__ srbB,
              const float* __restrict__ lngA, const float* __restrict__ lngB,
              const float* __restrict__ lnbA, const float* __restrict__ lnbB,
              unsigned short* __restrict__ kvrA, unsigned short* __restrict__ kvrB)
{
  int n = blockIdx.x, t = threadIdx.x;
  int side = n >= 968; n -= side * 968;
  const float* part = side ? partB : partA;
  const float* srb = side ? srbB : srbA;
  const float* lng = side ? lngB : lngA;
  const float* lnb = side ? lnbB : lnbA;
  unsigned short* kvr = side ? kvrB : kvrA;

  float v = srb[t];
  for (int s = 0; s < 8; ++s) v += part[((size_t)s * 968 + n) * 256 + t];
  float s1 = v, s2 = v * v;
  #pragma unroll
  for (int o = 1; o < 64; o <<= 1){ s1 += __shfl_xor(s1, o, 64); s2 += __shfl_xor(s2, o, 64); }
  __shared__ float a1[4], a2[4];
  if ((t & 63) == 0){ a1[t >> 6] = s1; a2[t >> 6] = s2; }
  __syncthreads();
  float t1 = a1[0] + a1[1] + a1[2] + a1[3];
  float t2 = a2[0] + a2[1] + a2[2] + a2[3];
  float mean = t1 * (1.f / 256.f);
  float var = t2 * (1.f / 256.f) - mean * mean;
  float rstd = rsqrtf(var + 1e-5f);
  kvr[(size_t)n * 256 + t] = f2bf((v - mean) * rstd * lng[t] + lnb[t]);
}

// ---------------------------------------------------------------- merged V-conv (+ K-proj) both sides
__global__ __launch_bounds__(256)
void vconv2_k(const unsigned short* __restrict__ kvrA, const unsigned short* __restrict__ kvrB,
              const unsigned short* __restrict__ vwtA, const unsigned short* __restrict__ vwtB,
              const float* __restrict__ vbA, const float* __restrict__ vbB,
              const unsigned short* __restrict__ kwtA, const unsigned short* __restrict__ kwtB,
              const float* __restrict__ kbA, const float* __restrict__ kbB,
              unsigned short* __restrict__ VBtA, unsigned short* __restrict__ VBtB,
              float* __restrict__ KBA, float* __restrict__ KBB)
{
  int n = blockIdx.x;
  int side = n >= 968; n -= side * 968;
  const unsigned short* kvr = side ? kvrB : kvrA;
  const unsigned short* vwt = side ? vwtB : vwtA;
  const float* vb = side ? vbB : vbA;
  const unsigned short* kwt = side ? kwtB : kwtA;
  const float* kbias = side ? kbB : kbA;
  unsigned short* VBt = side ? VBtB : VBtA;
  float* KB = side ? KBB : KBA;

  __shared__ float rowf[256];
  const int t = threadIdx.x;
  rowf[t] = bf2f(kvr[(size_t)n * 256 + t]);
  __syncthreads();
  float sum = vb[t];
  #pragma unroll 8
  for (int c = 0; c < 256; ++c)
    sum = fmaf(rowf[c], bf2f(vwt[(size_t)c * 256 + t]), sum);
  int b = n / 121, m = n - b * 121;
  VBt[(size_t)b * 32768 + (size_t)t * 128 + m] = f2bf(sum);

  if (t < 32){
    float ks = kbias[t];
    #pragma unroll 8
    for (int c = 0; c < 256; ++c)
      ks = fmaf(rowf[c], bf2f(kwt[c * 32 + t]), ks);
    KB[(size_t)n * 32 + t] = ks;
  }
}

// ---------------------------------------------------------------- merged MFMA attention (+fused Q-proj) + LN + residual
struct AttnS {
  const unsigned short* Qsrc;
  const unsigned short* wq;
  const float* qb;
  const float* Kbuf;
  const unsigned short* VBt;
  const float* ng;
  const float* nb;
  const float* gm;
  int qmode, resOff, outOff;
};

__global__ __launch_bounds__(512, 2)
void attn2_k(AttnS s0, AttnS s1,
             const unsigned short* __restrict__ Xpad,
             unsigned short* __restrict__ FusPad)
{
  __shared__ unsigned short Vt[2][256][64];
  __shared__ unsigned short Pl[2][128][64];
  __shared__ unsigned short Qs[128][64];
  __shared__ unsigned short Ks[128][64];
  __shared__ unsigned short Wqs[32][256];

  int bid = blockIdx.x;
  const int side = bid >= 488;
  bid -= side * 488;
  const AttnS& s = side ? s1 : s0;

  const int t = threadIdx.x;
  const int lane = t & 63;
  const int w = t >> 6;
  const int c15 = lane & 15;
  const int h = lane >> 4;

  const int b = bid / 61;
  const int rb = bid - b * 61;
  const int nb0 = rb * 128;

  const unsigned short* vsrc = s.VBt + (size_t)b * 32768;
  #pragma unroll
  for (int kt = 0; kt < 2; ++kt)
    #pragma unroll
    for (int i = 0; i < 4; ++i){
      int rowbase = i * 64 + w * 8;
      int c = rowbase + (lane >> 3);
      int mchunk = (lane & 7) ^ (c & 7);
      __builtin_amdgcn_global_load_lds(
        (AS1 void*)(vsrc + (size_t)c * 128 + kt * 64 + mchunk * 8),
        (AS3 void*)(&Vt[kt][rowbase][0]),
        16, 0, 0);
    }

  {
    uint4* d = (uint4*)&Wqs[0][0]; const uint4* sw = (const uint4*)s.wq;
    d[t] = sw[t];
    d[t + 512] = sw[t + 512];
  }
  {
    int m = t >> 2, part = t & 3;
    union { uint4 v; unsigned short s_[8]; } u;
    u.v = uint4{0, 0, 0, 0};
    if (m < 121){
      const float* kp = s.Kbuf + ((size_t)b * 121 + m) * 32 + part * 8;
      float4 a = *reinterpret_cast<const float4*>(kp);
      float4 bb = *reinterpret_cast<const float4*>(kp + 4);
      u.s_[0] = f2bf(a.x); u.s_[1] = f2bf(a.y); u.s_[2] = f2bf(a.z); u.s_[3] = f2bf(a.w);
      u.s_[4] = f2bf(bb.x); u.s_[5] = f2bf(bb.y); u.s_[6] = f2bf(bb.z); u.s_[7] = f2bf(bb.w);
    }
    *reinterpret_cast<uint4*>(&Ks[m][(part ^ (m & 7)) * 8]) = u.v;
  }
  __syncthreads();

  const int nA = w * 16 + c15;
  const float scale = 0.17677669529663687f;  // 32^-0.5

  {
    int gn = nb0 + nA; if (gn > 7743) gn = 7743;
    const unsigned short* xrow;
    if (s.qmode){
      int y = gn / 88, x = gn - y * 88;
      xrow = s.Qsrc + (((size_t)(b * 90) + y + 1) * 90 + (x + 1)) * 512;
    } else {
      xrow = s.Qsrc + ((size_t)b * 7744 + gn) * 256;
    }
    f32x4 qacc[2];
    qacc[0] = f32x4{0.f, 0.f, 0.f, 0.f};
    qacc[1] = f32x4{0.f, 0.f, 0.f, 0.f};
    #pragma unroll
    for (int kt = 0; kt < 8; ++kt){
      bf16x8 ax = *reinterpret_cast<const bf16x8*>(xrow + kt * 32 + h * 8);
      #pragma unroll
      for (int ni = 0; ni < 2; ++ni){
        int co = ni * 16 + c15;
        bf16x8 bw = *reinterpret_cast<const bf16x8*>(&Wqs[co][((kt * 4 + h) ^ (co & 7)) * 8]);
        qacc[ni] = __builtin_amdgcn_mfma_f32_16x16x32_bf16(ax, bw, qacc[ni], 0, 0, 0);
      }
    }
    #pragma unroll
    for (int ni = 0; ni < 2; ++ni){
      int co = ni * 16 + c15;
      float bq = s.qb[co];
      #pragma unroll
      for (int r = 0; r < 4; ++r){
        int n = w * 16 + 4 * h + r;
        int chunk = (co >> 3) ^ (n & 7);
        Qs[n][chunk * 8 + (co & 7)] = f2bf((qacc[ni][r] + bq) * scale);
      }
    }
  }

  bf16x8 aq = *reinterpret_cast<const bf16x8*>(&Qs[nA][(h ^ (nA & 7)) * 8]);
  f32x4 sv[8];
  #pragma unroll
  for (int ni = 0; ni < 8; ++ni){
    int mrow = ni * 16 + c15;
    bf16x8 bk = *reinterpret_cast<const bf16x8*>(&Ks[mrow][(h ^ (mrow & 7)) * 8]);
    sv[ni] = __builtin_amdgcn_mfma_f32_16x16x32_bf16(aq, bk, f32x4{0.f,0.f,0.f,0.f}, 0, 0, 0);
  }
  if (c15 >= 9) sv[7] = f32x4{-1e30f, -1e30f, -1e30f, -1e30f};

  float rden[4];
  #pragma unroll
  for (int r = 0; r < 4; ++r){
    float mx = sv[0][r];
    #pragma unroll
    for (int ni = 1; ni < 8; ++ni) mx = fmaxf(mx, sv[ni][r]);
    #pragma unroll
    for (int o = 1; o < 16; o <<= 1) mx = fmaxf(mx, __shfl_xor(mx, o, 64));
    float sm = 0.f;
    #pragma unroll
    for (int ni = 0; ni < 8; ++ni){
      float p = __expf(sv[ni][r] - mx);
      sv[ni][r] = p;
      sm += p;
    }
    #pragma unroll
    for (int o = 1; o < 16; o <<= 1) sm += __shfl_xor(sm, o, 64);
    rden[r] = 1.f / sm;
  }
  #pragma unroll
  for (int ni = 0; ni < 8; ++ni){
    int m = ni * 16 + c15;
    int kt = m >> 6;
    int mq = (m & 63) >> 3;
    #pragma unroll
    for (int r = 0; r < 4; ++r){
      int n = w * 16 + 4 * h + r;
      Pl[kt][n][(mq ^ (n & 7)) * 8 + (m & 7)] = f2bf(sv[ni][r] * rden[r]);
    }
  }

  bf16x8 pa[2][2];
  #pragma unroll
  for (int kt = 0; kt < 2; ++kt)
    #pragma unroll
    for (int ks = 0; ks < 2; ++ks)
      pa[kt][ks] = *reinterpret_cast<const bf16x8*>(&Pl[kt][nA][((ks * 4 + h) ^ (nA & 7)) * 8]);

  f32x4 acc[16];
  #pragma unroll
  for (int ni = 0; ni < 16; ++ni) acc[ni] = f32x4{0.f, 0.f, 0.f, 0.f};
  #pragma unroll
  for (int ni = 0; ni < 16; ++ni){
    int crow = ni * 16 + c15;
    #pragma unroll
    for (int kt = 0; kt < 2; ++kt)
      #pragma unroll
      for (int ks = 0; ks < 2; ++ks){
        bf16x8 bv = *reinterpret_cast<const bf16x8*>(&Vt[kt][crow][((ks * 4 + h) ^ (crow & 7)) * 8]);
        acc[ni] = __builtin_amdgcn_mfma_f32_16x16x32_bf16(pa[kt][ks], bv, acc[ni], 0, 0, 0);
      }
  }

  float ngv[16], nbb[16];
  #pragma unroll
  for (int ni = 0; ni < 16; ++ni){
    int c = ni * 16 + c15;
    ngv[ni] = s.ng[c]; nbb[ni] = s.nb[c];
  }
  float g = s.gm[0]; g = fminf(fmaxf(g, 0.f), 1.f);

  #pragma unroll
  for (int r = 0; r < 4; ++r){
    float s1 = 0.f, s2 = 0.f;
    #pragma unroll
    for (int ni = 0; ni < 16; ++ni){ float v = acc[ni][r]; s1 += v; s2 += v * v; }
    #pragma unroll
    for (int o = 1; o < 16; o <<= 1){ s1 += __shfl_xor(s1, o, 64); s2 += __shfl_xor(s2, o, 64); }
    float mean = s1 * (1.f / 256.f);
    float var = s2 * (1.f / 256.f) - mean * mean;
    float rstd = rsqrtf(var + 1e-5f);

    int nloc = w * 16 + 4 * h + r;
    int rix = nb0 + nloc;
    if (rix < 7744){
      int y = rix / 88, x = rix - y * 88;
      size_t pix = ((size_t)(b * 90) + y + 1) * 90 + (x + 1);
      const unsigned short* res = Xpad + pix * 512 + s.resOff;
      unsigned short* outp = FusPad + pix * 576 + s.outOff;
      #pragma unroll
      for (int ni = 0; ni < 16; ++ni){
        int c = ni * 16 + c15;
        float yv = (acc[ni][r] - mean) * rstd * ngv[ni] + nbb[ni];
        outp[c] = f2bf(bf2f(res[c]) + g * yv);
      }
    }
  }
}

// ================================================================ host
extern "C" void kernel_launch(void* const* d_in, const int* in_sizes, int n_in,
                              void* d_out, int out_size, void* d_ws, size_t ws_size,
                              hipStream_t stream)
{
  const float* P[42];
  for (int i = 0; i < 42; ++i) P[i] = (const float*)d_in[i];

  char* ws = (char*)d_ws;
  size_t off = 0;
  auto take = [&](size_t bytes) -> char* {
    char* p = ws + off; off += (bytes + 255) & ~(size_t)255; return p;
  };
  unsigned short* XPAD = (unsigned short*)take(8ull * 8100 * 512 * 2);   // 66.4 MB
  unsigned short* FUSP = (unsigned short*)take(8ull * 8100 * 576 * 2);   // 74.6 MB
  unsigned short* H1   = (unsigned short*)take(61952ull * 256 * 2);      // 31.7 MB
  unsigned short* FDM  = H1;  // alias: h1 dead after mask_k
  unsigned short* W1T  = (unsigned short*)take(9ull * 256 * 512 * 2);
  unsigned short* WFT  = (unsigned short*)take(9ull * 256 * 576 * 2);
  unsigned short* WSRA = (unsigned short*)take(64ull * 256 * 256 * 2);
  unsigned short* WSRB = (unsigned short*)take(64ull * 256 * 256 * 2);
  float* PARTA = (float*)take(8ull * 968 * 256 * 4);
  float* PARTB = (float*)take(8ull * 968 * 256 * 4);
  unsigned short* KVRA = (unsigned short*)take(968ull * 256 * 2);
  unsigned short* KVRB = (unsigned short*)take(968ull * 256 * 2);
  float* KBA  = (float*)take(968ull * 32 * 4);
  float* KBB  = (float*)take(968ull * 32 * 4);
  unsigned short* VBTA = (unsigned short*)take(2ull * 8 * 256 * 128 * 2);
  unsigned short* VBTB = VBTA + 8ull * 256 * 128;
  float* MASK = (float*)take(61952ull * 4);
  float* SC1 = (float*)take(256 * 4);
  float* SH1 = (float*)take(256 * 4);
  float* SCF = (float*)take(256 * 4);
  float* SHF = (float*)take(256 * 4);
  unsigned short* WQSA = (unsigned short*)take(32ull * 256 * 2);
  unsigned short* WQSB = (unsigned short*)take(32ull * 256 * 2);
  unsigned short* KWTA = (unsigned short*)take(256ull * 32 * 2);
  unsigned short* VWTA = (unsigned short*)take(256ull * 256 * 2);
  unsigned short* KWTB = (unsigned short*)take(256ull * 32 * 2);
  unsigned short* VWTB = (unsigned short*)take(256ull * 256 * 2);
  (void)ws_size; (void)in_sizes; (void)n_in; (void)out_size;

  zero_border_k<<<8 * 356, 128, 0, stream>>>(XPAD, 512);
  zero_border_k<<<8 * 356, 128, 0, stream>>>(FUSP, 576);
  zero_fustail_k<<<1936, 256, 0, stream>>>(FUSP);
  hipMemsetAsync(VBTA, 0, 2ull * 8 * 256 * 128 * 2, stream);

  bnprep_k<<<1, 256, 0, stream>>>(P[4], P[5], P[6], P[7], P[3],
                                  P[38], P[39], P[40], P[41], P[37],
                                  SC1, SH1, SCF, SHF);
  prep_xpad_k<<<7744, 256, 0, stream>>>(P[0], P[1], XPAD);
  prep_w1t_k<<<256, 256, 0, stream>>>(P[2], W1T);
  prep_wfus_k<<<256, 256, 0, stream>>>(P[36], WFT);
  prep_wsr_k<<<256, 256, 0, stream>>>(P[16], WSRA);
  prep_wsr_k<<<256, 256, 0, stream>>>(P[28], WSRB);
  wqprep_k<<<32, 256, 0, stream>>>(P[10], WQSA);
  wqprep_k<<<32, 256, 0, stream>>>(P[22], WQSB);
  tranw_k<<<8, 256, 0, stream>>>(P[12], KWTA, 32, 256);
  tranw_k<<<64, 256, 0, stream>>>(P[14], VWTA, 256, 256);
  tranw_k<<<8, 256, 0, stream>>>(P[24], KWTB, 32, 256);
  tranw_k<<<64, 256, 0, stream>>>(P[26], VWTB, 256, 256);

  // conv1 3x3 (512->256) + BN + ReLU -> h1 NHWC bf16   [256^2 8-phase, R9 schedule]
  GemmP g1{};
  g1.A = XPAD; g1.W = W1T; g1.ep_scale = SC1; g1.ep_shift = SH1; g1.out = H1;
  g1.img_px = 8100; g1.row_px = 90; g1.px_el = 512; g1.ch_off = 0; g1.y0 = 0; g1.x0 = 0;
  g1.tapw = 3; g1.stridepix = 1; g1.out_w = 88; g1.out_imgpx = 7744;
  g1.Cin = 512; g1.Mtot = 61952; g1.Mtiles = 242; g1.Ntiles = 1; g1.k_per = 4608;
  gemm256_k<0><<<242, 512, 0, stream>>>(g1);

  mask_k<<<242, 256, 0, stream>>>(H1, P[8], P[9], MASK, FUSP);
  fdm_k<<<7744, 256, 0, stream>>>(XPAD, MASK, FDM);

  // ---------------- merged SRA pipelines ----------------
  GemmP ga{};
  ga.A = FDM; ga.W = WSRA; ga.out = nullptr;
  ga.img_px = 7744; ga.row_px = 88; ga.px_el = 256; ga.ch_off = 0; ga.y0 = 0; ga.x0 = 0;
  ga.tapw = 8; ga.stridepix = 8; ga.out_w = 11; ga.out_imgpx = 121;
  ga.Cin = 256; ga.Mtot = 968; ga.Mtiles = 8; ga.Ntiles = 2; ga.k_per = 2048;
  GemmP gb = ga;
  gb.A = XPAD; gb.W = WSRB;
  gb.img_px = 8100; gb.row_px = 90; gb.px_el = 512; gb.y0 = 1; gb.x0 = 1;
  gemm_sr_k<<<256, 256, 0, stream>>>(ga, gb, PARTA, PARTB);

  lnkvr2_k<<<1936, 256, 0, stream>>>(PARTA, PARTB, P[17], P[29], P[18], P[30],
                                     P[19], P[31], KVRA, KVRB);
  vconv2_k<<<1936, 256, 0, stream>>>(KVRA, KVRB, VWTA, VWTB, P[15], P[27],
                                     KWTA, KWTB, P[13], P[25],
                                     VBTA, VBTB, KBA, KBB);

  AttnS s0{XPAD, WQSA, P[11], KBA, VBTA, P[20], P[21], P[34], 1, 0, 0};
  AttnS s1{FDM,  WQSB, P[23], KBB, VBTB, P[32], P[33], P[35], 0, 256, 256};
  attn2_k<<<976, 512, 0, stream>>>(s0, s1, XPAD, FUSP);

  // final fused conv 3x3 (576->256) + BN + ReLU -> d_out f32 NCHW   [256^2 8-phase, R9 schedule]
  GemmP gf{};
  gf.A = FUSP; gf.W = WFT; gf.ep_scale = SCF; gf.ep_shift = SHF; gf.out = d_out;
  gf.img_px = 8100; gf.row_px = 90; gf.px_el = 576; gf.ch_off = 0; gf.y0 = 0; gf.x0 = 0;
  gf.tapw = 3; gf.stridepix = 1; gf.out_w = 88; gf.out_imgpx = 7744;
  gf.Cin = 576; gf.Mtot = 61952; gf.Mtiles = 242; gf.Ntiles = 1; gf.k_per = 5184;
  gemm256_k<1><<<242, 512, 0, stream>>>(gf);
}